// Round 5
// baseline (2970.155 us; speedup 1.0000x reference)
//
#include <hip/hip_runtime.h>

#define Bb 8
#define Nn 2048
#define Kk 40
#define HS (128*Nn)   // h stride per batch (channel-major [b,128,2048])

// monotone float->uint transform: a > b  <=>  f2o(a) > f2o(b)
__device__ __forceinline__ unsigned f2o(float f){
  unsigned u = __float_as_uint(f);
  return (u & 0x80000000u) ? ~u : (u | 0x80000000u);
}

// Wave-cooperative exact top-40 of 2048, grouped rescan (4 groups of 8 slots).
// Lane owns m = slot*64+lane. Per round only the winner lane rescans its group;
// selection order identical to a full linear scan (value desc, index asc).
__device__ __forceinline__ void wave_top40(float* d, int lane, int* op){
  float gv[4]; int gs[4];
  #pragma unroll
  for (int g=0; g<4; ++g){
    float bv = d[g*8]; int bs = g*8;
    #pragma unroll
    for (int j=1;j<8;++j){
      float v = d[g*8+j];
      if (v > bv){ bv = v; bs = g*8+j; }
    }
    gv[g]=bv; gs[g]=bs;
  }
  for (int t=0; t<Kk; ++t){
    float bv = gv[0]; int bs = gs[0];
    if (gv[1] > bv){ bv=gv[1]; bs=gs[1]; }
    if (gv[2] > bv){ bv=gv[2]; bs=gs[2]; }
    if (gv[3] > bv){ bv=gv[3]; bs=gs[3]; }
    int bm = bs*64 + lane;
    unsigned long long key = ((unsigned long long)f2o(bv) << 32) | (unsigned)(~bm);
    #pragma unroll
    for (int s=32;s>0;s>>=1){
      unsigned long long o = __shfl_xor(key, s, 64);
      if (o > key) key = o;
    }
    int wm = (int)(~(unsigned)key);
    if (lane == 0) op[t] = wm;
    bool mine = ((wm & 63) == lane);
    int wsl = wm >> 6;
    if (mine){
      int G = wsl >> 3;
      #pragma unroll
      for (int g=0; g<4; ++g){
        if (g == G){
          float nv = -__builtin_inff(); int ns = g*8;
          #pragma unroll
          for (int j=0;j<8;++j){
            float v = d[g*8+j];
            if (g*8+j == wsl) v = -__builtin_inff();
            d[g*8+j] = v;
            if (v > nv){ nv=v; ns=g*8+j; }
          }
          gv[g]=nv; gs[g]=ns;
        }
      }
    }
  }
}

// Variant for mapping m = (s>>2)*256 + lane*4 + (s&3) (coalesced float4 ownership).
// Within a lane m is increasing in s, so the same grouped tie-break is exact.
__device__ __forceinline__ void wave_top40_g(float* d, int lane, int* op){
  float gv[4]; int gs[4];
  #pragma unroll
  for (int g=0; g<4; ++g){
    float bv = d[g*8]; int bs = g*8;
    #pragma unroll
    for (int j=1;j<8;++j){
      float v = d[g*8+j];
      if (v > bv){ bv = v; bs = g*8+j; }
    }
    gv[g]=bv; gs[g]=bs;
  }
  for (int t=0; t<Kk; ++t){
    float bv = gv[0]; int bs = gs[0];
    if (gv[1] > bv){ bv=gv[1]; bs=gs[1]; }
    if (gv[2] > bv){ bv=gv[2]; bs=gs[2]; }
    if (gv[3] > bv){ bv=gv[3]; bs=gs[3]; }
    int bm = ((bs>>2)<<8) + lane*4 + (bs&3);
    unsigned long long key = ((unsigned long long)f2o(bv) << 32) | (unsigned)(~bm);
    #pragma unroll
    for (int s=32;s>0;s>>=1){
      unsigned long long o = __shfl_xor(key, s, 64);
      if (o > key) key = o;
    }
    int wm = (int)(~(unsigned)key);
    if (lane == 0) op[t] = wm;
    bool mine = (((wm>>2) & 63) == lane);
    int wsl = ((wm>>8)<<2) | (wm & 3);
    if (mine){
      int G = wsl >> 3;
      #pragma unroll
      for (int g=0; g<4; ++g){
        if (g == G){
          float nv = -__builtin_inff(); int ns = g*8;
          #pragma unroll
          for (int j=0;j<8;++j){
            float v = d[g*8+j];
            if (g*8+j == wsl) v = -__builtin_inff();
            d[g*8+j] = v;
            if (v > nv){ nv=v; ns=g*8+j; }
          }
          gv[g]=nv; gs[g]=ns;
        }
      }
    }
  }
}

// ---------------- prep ----------------
__global__ __launch_bounds__(256) void k_xx1(const float* __restrict__ x, float* __restrict__ XX){
  int e = blockIdx.x*256 + threadIdx.x;
  if (e >= Bb*Nn) return;
  float p0 = x[e*3+0], p1 = x[e*3+1], p2 = x[e*3+2];
  XX[e] = __fadd_rn(__fadd_rn(__fmul_rn(p0,p0), __fmul_rn(p1,p1)), __fmul_rn(p2,p2));
}

__global__ __launch_bounds__(256) void k_prep_wt(const float* __restrict__ w1, const float* __restrict__ w2,
                                                 const float* __restrict__ w3, const float* __restrict__ w4,
                                                 const float* __restrict__ fw,
                                                 float* __restrict__ W1T, float* __restrict__ W2T,
                                                 float* __restrict__ W3T, float* __restrict__ W4T,
                                                 float* __restrict__ FWT){
  int e = blockIdx.x*256 + threadIdx.x;
  if (e < 384)   { int i=e/64,  c=e%64;  W1T[e] = w1[c*6+i];    return; } e -= 384;
  if (e < 4096)  { int i=e/64,  c=e%64;  W2T[e] = w2[c*64+i];   return; } e -= 4096;
  if (e < 8192)  { int i=e/64,  c=e%64;  W3T[e] = w3[c*128+i];  return; } e -= 8192;
  if (e < 4096)  { int i=e/64,  c=e%64;  W4T[e] = w4[c*64+i];   return; } e -= 4096;
  if (e < 131072){ int i=e/256, o=e%256; FWT[e] = fw[o*512+i];  return; }
}

// ---------------- knn on 3-D points: 1 wave / query, LDS-staged cloud ----------------
__global__ __launch_bounds__(256) void k_knn1(const float* __restrict__ P, const float* __restrict__ XX,
                                              int* __restrict__ IDX){
  int blk = blockIdx.x;
  int b = blk >> 9;
  int w = threadIdx.x >> 6, lane = threadIdx.x & 63;
  int n = (blk & 511)*4 + w;
  const float* Pb = P + b*Nn*3;
  const float* xb = XX + b*Nn;
  __shared__ float Pl[Nn*3];
  __shared__ float Xl[Nn];
  for (int e = threadIdx.x; e < Nn*3; e += 256) Pl[e] = Pb[e];
  for (int e = threadIdx.x; e < Nn; e += 256) Xl[e] = xb[e];
  __syncthreads();
  float c0 = Pl[n*3+0], c1 = Pl[n*3+1], c2 = Pl[n*3+2];
  float xn = Xl[n];
  float d[32];
  #pragma unroll
  for (int j=0;j<32;++j){
    int m = j*64 + lane;
    float a0 = Pl[m*3+0], a1 = Pl[m*3+1], a2 = Pl[m*3+2];
    float in_ = __fadd_rn(__fadd_rn(__fmul_rn(c0,a0), __fmul_rn(c1,a1)), __fmul_rn(c2,a2));
    d[j] = __fsub_rn(__fsub_rn(__fmul_rn(2.0f,in_), xn), Xl[m]);
  }
  wave_top40(d, lane, IDX + (b*Nn+n)*Kk);
}

// ---------------- edge conv 1+2 + maxpool (bit-exact _rn path) ----------------
__global__ __launch_bounds__(64) void k_ec1(const float* __restrict__ P, const int* __restrict__ IDX,
                                            const float* __restrict__ W1T, const float* __restrict__ W2T,
                                            const float* __restrict__ g1, const float* __restrict__ b1,
                                            const float* __restrict__ g2, const float* __restrict__ b2,
                                            float* __restrict__ X1T){
  int e = blockIdx.x;           // global point row 0..16383
  int b = e >> 11;
  int lane = threadIdx.x;
  __shared__ float dC[Kk*4];
  __shared__ __align__(16) float y1L[64*44];
  float c0 = P[e*3+0], c1 = P[e*3+1], c2 = P[e*3+2];
  if (lane < Kk) {
    int idx = IDX[e*Kk + lane] & (Nn-1);
    const float* pn = P + (b*Nn + idx)*3;
    dC[lane*4+0] = __fsub_rn(pn[0], c0);
    dC[lane*4+1] = __fsub_rn(pn[1], c1);
    dC[lane*4+2] = __fsub_rn(pn[2], c2);
  }
  __syncthreads();
  float w10 = W1T[0*64+lane], w11 = W1T[1*64+lane], w12 = W1T[2*64+lane];
  float w13 = W1T[3*64+lane], w14 = W1T[4*64+lane], w15 = W1T[5*64+lane];
  float p3 = __fmul_rn(w13,c0), p4 = __fmul_rn(w14,c1), p5 = __fmul_rn(w15,c2);
  float s1 = __fdiv_rn(g1[lane], __fsqrt_rn(1.0f + 1e-5f));
  float o1 = b1[lane];
  for (int k=0;k<Kk;++k){
    float t = __fmul_rn(w10, dC[k*4+0]);
    t = __fadd_rn(t, __fmul_rn(w11, dC[k*4+1]));
    t = __fadd_rn(t, __fmul_rn(w12, dC[k*4+2]));
    t = __fadd_rn(t, p3); t = __fadd_rn(t, p4); t = __fadd_rn(t, p5);
    float y = __fadd_rn(__fmul_rn(t, s1), o1);
    y = (y >= 0.0f) ? y : __fmul_rn(0.2f, y);
    y1L[lane*44+k] = y;
  }
  __syncthreads();
  float4 q[10];
  #pragma unroll
  for (int k4=0;k4<10;++k4) q[k4] = make_float4(0.f,0.f,0.f,0.f);
  for (int i=0;i<64;++i){
    float w = W2T[i*64+lane];
    const float4* yp = (const float4*)&y1L[i*44];
    #pragma unroll
    for (int k4=0;k4<10;++k4){
      float4 yv = yp[k4];
      q[k4].x = __fadd_rn(q[k4].x, __fmul_rn(w, yv.x));
      q[k4].y = __fadd_rn(q[k4].y, __fmul_rn(w, yv.y));
      q[k4].z = __fadd_rn(q[k4].z, __fmul_rn(w, yv.z));
      q[k4].w = __fadd_rn(q[k4].w, __fmul_rn(w, yv.w));
    }
  }
  float s2 = __fdiv_rn(g2[lane], __fsqrt_rn(1.0f + 1e-5f));
  float o2 = b2[lane];
  float mx = -__builtin_inff();
  #pragma unroll
  for (int k4=0;k4<10;++k4){
    float vs[4] = {q[k4].x, q[k4].y, q[k4].z, q[k4].w};
    #pragma unroll
    for (int j=0;j<4;++j){
      float y = __fadd_rn(__fmul_rn(vs[j], s2), o2);
      y = (y >= 0.0f) ? y : __fmul_rn(0.2f, y);
      mx = fmaxf(mx, y);
    }
  }
  X1T[e*64 + lane] = mx;
}

__global__ __launch_bounds__(256) void k_xx2(const float* __restrict__ X1T, float* __restrict__ XX2){
  int e = blockIdx.x*256 + threadIdx.x;
  const float* r = X1T + e*64;
  float a = 0.f;
  for (int c=0;c<64;++c) a = __fadd_rn(a, __fmul_rn(r[c], r[c]));
  XX2[e] = a;
}

// ---------------- knn on 64-D features ----------------
// v2: 4 queries/wave (16/block), point slab staged through LDS in 4-channel
// chunks. Each ds_read_b128 now feeds 16 MACs (was 4 per global load), unique
// global traffic drops 16x. Accumulation order (c = 0..63 sequential, _rn
// mul+add) and float4 point ownership (m = j*256 + lane*4 + e) are identical
// to v1, so wave_top40_g selection is bit-exact vs the passing kernel.
__global__ __launch_bounds__(256) void k_knn2(const float* __restrict__ X1C, const float* __restrict__ XX2,
                                              int* __restrict__ IDX){
  int blk = blockIdx.x;
  int b = blk >> 7;                 // 128 blocks per batch
  int n0 = (blk & 127) << 4;        // 16 queries per block
  int w = threadIdx.x >> 6, lane = threadIdx.x & 63;
  __shared__ __align__(16) float buf[4*2048];   // 4 channel rows (32 KB)
  __shared__ __align__(16) float qL[64*16];     // [c][q] query features (4 KB)
  for (int e=threadIdx.x; e<1024; e+=256){
    int c = e >> 4, t = e & 15;
    qL[e] = X1C[b*HS + c*Nn + n0 + t];
  }
  float4 acc[4][8];                 // 4 queries x 32 points/lane = 128 VGPR
  #pragma unroll
  for (int qi=0;qi<4;++qi){
    #pragma unroll
    for (int j=0;j<8;++j) acc[qi][j] = make_float4(0.f,0.f,0.f,0.f);
  }
  const float4* src4 = (const float4*)(X1C + b*HS);
  float4* buf4 = (float4*)buf;
#define KNN2_ACC(Q, QS) \
    acc[Q][j].x = __fadd_rn(acc[Q][j].x, __fmul_rn(QS, v.x)); \
    acc[Q][j].y = __fadd_rn(acc[Q][j].y, __fmul_rn(QS, v.y)); \
    acc[Q][j].z = __fadd_rn(acc[Q][j].z, __fmul_rn(QS, v.z)); \
    acc[Q][j].w = __fadd_rn(acc[Q][j].w, __fmul_rn(QS, v.w));
  for (int cc=0; cc<16; ++cc){
    __syncthreads();                // protect buf readers of previous chunk
    #pragma unroll
    for (int e=0;e<8;++e)
      buf4[e*256 + threadIdx.x] = src4[cc*2048 + e*256 + threadIdx.x];
    __syncthreads();
    #pragma unroll
    for (int c4=0;c4<4;++c4){
      float4 q = *(const float4*)&qL[(cc*4+c4)*16 + w*4];  // broadcast b128
      #pragma unroll
      for (int j=0;j<8;++j){
        float4 v = buf4[c4*512 + j*64 + lane];
        KNN2_ACC(0, q.x)
        KNN2_ACC(1, q.y)
        KNN2_ACC(2, q.z)
        KNN2_ACC(3, q.w)
      }
    }
  }
#undef KNN2_ACC
  const float* xb = XX2 + b*Nn;
  const float4* xb4 = (const float4*)xb;
  #pragma unroll
  for (int qi=0;qi<4;++qi){
    int n = n0 + w*4 + qi;
    float xn = xb[n];
    float d[32];
    #pragma unroll
    for (int j=0;j<8;++j){
      float4 xm = xb4[j*64 + lane];
      d[j*4+0] = __fsub_rn(__fsub_rn(__fmul_rn(2.0f, acc[qi][j].x), xn), xm.x);
      d[j*4+1] = __fsub_rn(__fsub_rn(__fmul_rn(2.0f, acc[qi][j].y), xn), xm.y);
      d[j*4+2] = __fsub_rn(__fsub_rn(__fmul_rn(2.0f, acc[qi][j].z), xn), xm.z);
      d[j*4+3] = __fsub_rn(__fsub_rn(__fmul_rn(2.0f, acc[qi][j].w), xn), xm.w);
    }
    wave_top40_g(d, lane, IDX + (b*Nn + n)*Kk);
  }
}

// ---------------- edge conv 3+4 + maxpool (fma ok) ----------------
__global__ __launch_bounds__(64) void k_ec2(const float* __restrict__ X1T, const int* __restrict__ IDX,
                                            const float* __restrict__ W3T, const float* __restrict__ W4T,
                                            const float* __restrict__ g3, const float* __restrict__ b3,
                                            const float* __restrict__ g4, const float* __restrict__ b4,
                                            float* __restrict__ X2T){
  int e = blockIdx.x; int b = e >> 11; int lane = threadIdx.x;
  __shared__ __align__(16) float dL[64*44];
  __shared__ float ctrL[64];
  float ctr = X1T[e*64 + lane];
  ctrL[lane] = ctr;
  __syncthreads();
  for (int k=0;k<Kk;++k){
    int idx = IDX[e*Kk + k] & (Nn-1);
    dL[lane*44 + k] = X1T[(b*Nn+idx)*64 + lane] - ctr;
  }
  __syncthreads();
  float base = 0.f;
  for (int i=0;i<64;++i) base = fmaf(W3T[(64+i)*64 + lane], ctrL[i], base);
  float4 q[10];
  #pragma unroll
  for (int k4=0;k4<10;++k4) q[k4] = make_float4(base,base,base,base);
  for (int i=0;i<64;++i){
    float w = W3T[i*64 + lane];
    const float4* dp = (const float4*)&dL[i*44];
    #pragma unroll
    for (int k4=0;k4<10;++k4){
      float4 d = dp[k4];
      q[k4].x = fmaf(w, d.x, q[k4].x);
      q[k4].y = fmaf(w, d.y, q[k4].y);
      q[k4].z = fmaf(w, d.z, q[k4].z);
      q[k4].w = fmaf(w, d.w, q[k4].w);
    }
  }
  float s3 = g3[lane] / sqrtf(1.0f+1e-5f);
  float o3 = b3[lane];
  __syncthreads();
  #pragma unroll
  for (int k4=0;k4<10;++k4){
    float4 y;
    y.x = q[k4].x*s3 + o3; y.x = (y.x>=0.f)?y.x:0.2f*y.x;
    y.y = q[k4].y*s3 + o3; y.y = (y.y>=0.f)?y.y:0.2f*y.y;
    y.z = q[k4].z*s3 + o3; y.z = (y.z>=0.f)?y.z:0.2f*y.z;
    y.w = q[k4].w*s3 + o3; y.w = (y.w>=0.f)?y.w:0.2f*y.w;
    *(float4*)&dL[lane*44 + k4*4] = y;
  }
  __syncthreads();
  float4 p[10];
  #pragma unroll
  for (int k4=0;k4<10;++k4) p[k4] = make_float4(0.f,0.f,0.f,0.f);
  for (int i=0;i<64;++i){
    float w = W4T[i*64 + lane];
    const float4* yp = (const float4*)&dL[i*44];
    #pragma unroll
    for (int k4=0;k4<10;++k4){
      float4 yv = yp[k4];
      p[k4].x = fmaf(w, yv.x, p[k4].x);
      p[k4].y = fmaf(w, yv.y, p[k4].y);
      p[k4].z = fmaf(w, yv.z, p[k4].z);
      p[k4].w = fmaf(w, yv.w, p[k4].w);
    }
  }
  float s4 = g4[lane] / sqrtf(1.0f+1e-5f);
  float o4 = b4[lane];
  float mx = -__builtin_inff();
  #pragma unroll
  for (int k4=0;k4<10;++k4){
    float vs[4] = {p[k4].x, p[k4].y, p[k4].z, p[k4].w};
    #pragma unroll
    for (int j=0;j<4;++j){
      float y = vs[j]*s4 + o4;
      y = (y>=0.f)?y:0.2f*y;
      mx = fmaxf(mx, y);
    }
  }
  X2T[e*64 + lane] = mx;
}

// (b,n,64) -> (b,c,n); dst pre-offset by channel base; dst batch stride = HS
__global__ __launch_bounds__(256) void k_tr(const float* __restrict__ src, float* __restrict__ dst){
  int b = blockIdx.x >> 5; int n0 = (blockIdx.x & 31) << 6;
  __shared__ float t[64*65];
  for (int e=threadIdx.x; e<4096; e+=256){
    int r = e >> 6, c = e & 63;
    t[r*65+c] = src[(b*Nn + n0 + r)*64 + c];
  }
  __syncthreads();
  for (int e=threadIdx.x; e<4096; e+=256){
    int c = e >> 6, r = e & 63;
    dst[b*HS + c*Nn + n0 + r] = t[r*65+c];
  }
}

// ---------------- SA layer ----------------
// grid 512 = b(8) x nt(32) x part(2); unified rows: r<32 -> QX row r, else XV row r-32.
__global__ __launch_bounds__(256) void k_sa_a(const float* __restrict__ IN,
                                              const float* __restrict__ QKw, const float* __restrict__ Vw,
                                              const float* __restrict__ Vb,
                                              float* __restrict__ QX, float* __restrict__ XV){
  int blk = blockIdx.x;
  int part = blk & 1; int nt = (blk >> 1) & 31; int b = blk >> 6;
  int n0 = nt << 6;
  int w = threadIdx.x >> 6, lane = threadIdx.x & 63;
  __shared__ float xl[128*64];
  for (int e=threadIdx.x; e<8192; e+=256){
    int c = e >> 6, j = e & 63;
    xl[e] = IN[b*HS + c*Nn + n0 + j];
  }
  __syncthreads();
  for (int i=0;i<20;++i){
    int r = part*80 + w*20 + i;
    const float4* wp4;
    if (r < 32) wp4 = (const float4*)(QKw + r*128);
    else        wp4 = (const float4*)(Vw + (r-32)*128);
    float a = 0.f;
    #pragma unroll
    for (int c4=0;c4<32;++c4){
      float4 wv = wp4[c4];
      a = fmaf(wv.x, xl[(c4*4+0)*64 + lane], a);
      a = fmaf(wv.y, xl[(c4*4+1)*64 + lane], a);
      a = fmaf(wv.z, xl[(c4*4+2)*64 + lane], a);
      a = fmaf(wv.w, xl[(c4*4+3)*64 + lane], a);
    }
    if (r < 32) QX[(b*32+r)*Nn + n0 + lane] = a;
    else { int o = r-32; XV[(b*128+o)*Nn + n0 + lane] = a + Vb[o]; }
  }
}

// m-split x8: grid 512 = b(8) x nc(8) x mc(8)
__global__ __launch_bounds__(256) void k_sa_b(const float* __restrict__ QX,
                                              float* __restrict__ RMP, float* __restrict__ RSP){
  int blk = blockIdx.x;
  int b = blk >> 6, sub = blk & 63;
  int ncn = sub >> 3, mcn = sub & 7;
  int n = ncn*256 + threadIdx.x;
  float q[32];
  #pragma unroll
  for (int o=0;o<32;++o) q[o] = QX[(b*32+o)*Nn + n];
  __shared__ float qt[32*128];
  float mr = -__builtin_inff(), lr = 0.f;
  int m0 = mcn*256;
  for (int t=0;t<2;++t){
    for (int e=threadIdx.x; e<4096; e+=256){
      int o = e >> 7, mm = e & 127;
      qt[e] = QX[(b*32+o)*Nn + m0 + t*128 + mm];
    }
    __syncthreads();
    for (int mm=0;mm<128;mm+=2){
      float e0=0.f, e1=0.f;
      #pragma unroll
      for (int o=0;o<32;++o){ float qo=q[o]; e0=fmaf(qo, qt[o*128+mm], e0); e1=fmaf(qo, qt[o*128+mm+1], e1); }
      if (e0 > mr){ lr = lr*expf(mr-e0) + 1.f; mr = e0; } else lr += expf(e0-mr);
      if (e1 > mr){ lr = lr*expf(mr-e1) + 1.f; mr = e1; } else lr += expf(e1-mr);
    }
    __syncthreads();
  }
  RMP[(b*Nn+n)*8 + mcn] = mr;
  RSP[(b*Nn+n)*8 + mcn] = lr;
}

__global__ __launch_bounds__(256) void k_sa_b2(const float* __restrict__ RMP, const float* __restrict__ RSP,
                                               float* __restrict__ RMX, float* __restrict__ RSM){
  int e = blockIdx.x*256 + threadIdx.x;
  float M = -__builtin_inff();
  #pragma unroll
  for (int i=0;i<8;++i) M = fmaxf(M, RMP[e*8+i]);
  float l = 0.f;
  #pragma unroll
  for (int i=0;i<8;++i) l += RSP[e*8+i]*expf(RMP[e*8+i]-M);
  RMX[e] = M; RSM[e] = l;
}

// LDS map (floats): QM[32o][32m]=1024 @0, QN[32o][32n]=1024 @1024,
// XVt[32n][132]=4224 @2048, SL[32n][32m]=1024 @6272, MX@7296, RL@7328.
#define SM_QM 0
#define SM_QN 1024
#define SM_XV 2048
#define SM_SL 6272
#define SM_MX 7296
#define SM_RL 7328

// main: grid 1024 = b(8) x mt(64) x part(2); n-range split in 2; writes PV and
// column-sum partials to PP/CSP.
__global__ __launch_bounds__(256) void k_sa_cm(const float* __restrict__ QX, const float* __restrict__ XV,
                                               const float* __restrict__ RMAX, const float* __restrict__ RSUM,
                                               float* __restrict__ PP, float* __restrict__ CSP){
  int blk = blockIdx.x;
  int part = blk & 1, mt = (blk >> 1) & 63, b = blk >> 7;
  int m0 = mt << 5;
  int tid = threadIdx.x;
  int nnp = tid >> 4, mmp = tid & 15;      // 2x2 S-microtile owner
  int tc = tid >> 3, tm8 = tid & 7;        // PV owner: c=tc*4+ci, m=tm8*4+mi
  __shared__ __align__(16) float sm[7360];
  for (int e=tid; e<1024; e+=256){
    int o = e >> 5, mm = e & 31;
    sm[SM_QM + e] = QX[(b*32+o)*Nn + m0 + mm];
  }
  float acc[4][4];
  #pragma unroll
  for (int ci=0;ci<4;++ci){
    #pragma unroll
    for (int mi=0;mi<4;++mi) acc[ci][mi] = 0.f;
  }
  float csr = 0.f;
  int it0 = part*32;
  for (int it=it0; it<it0+32; ++it){
    int nb = it*32;
    __syncthreads();
    for (int e=tid; e<1024; e+=256){ int o=e>>5, nn=e&31; sm[SM_QN+e] = QX[(b*32+o)*Nn + nb + nn]; }
    for (int e=tid; e<4096; e+=256){ int c=e>>5, nn=e&31; sm[SM_XV + nn*132 + c] = XV[(b*128+c)*Nn + nb + nn]; }
    if (tid < 32){ sm[SM_MX+tid] = RMAX[b*Nn + nb + tid]; sm[SM_RL+tid] = 1.0f / RSUM[b*Nn + nb + tid]; }
    __syncthreads();
    float e00=0.f, e01=0.f, e10=0.f, e11=0.f;
    #pragma unroll
    for (int o=0;o<32;++o){
      float2 qn = *(const float2*)&sm[SM_QN + o*32 + nnp*2];
      float2 qm = *(const float2*)&sm[SM_QM + o*32 + mmp*2];
      e00 = fmaf(qn.x, qm.x, e00);
      e01 = fmaf(qn.x, qm.y, e01);
      e10 = fmaf(qn.y, qm.x, e10);
      e11 = fmaf(qn.y, qm.y, e11);
    }
    float mx0 = sm[SM_MX + nnp*2],   rl0 = sm[SM_RL + nnp*2];
    float mx1 = sm[SM_MX + nnp*2+1], rl1 = sm[SM_RL + nnp*2+1];
    float2 s0; s0.x = expf(e00-mx0)*rl0; s0.y = expf(e01-mx0)*rl0;
    float2 s1; s1.x = expf(e10-mx1)*rl1; s1.y = expf(e11-mx1)*rl1;
    *(float2*)&sm[SM_SL + (nnp*2  )*32 + mmp*2] = s0;
    *(float2*)&sm[SM_SL + (nnp*2+1)*32 + mmp*2] = s1;
    __syncthreads();
    if (tid < 32){
      #pragma unroll
      for (int nn=0;nn<32;++nn) csr += sm[SM_SL + nn*32 + tid];
    }
    #pragma unroll 8
    for (int nn=0;nn<32;++nn){
      float4 xv4 = *(const float4*)&sm[SM_XV + nn*132 + tc*4];
      float4 s4  = *(const float4*)&sm[SM_SL + nn*32  + tm8*4];
      acc[0][0] = fmaf(xv4.x, s4.x, acc[0][0]);
      acc[0][1] = fmaf(xv4.x, s4.y, acc[0][1]);
      acc[0][2] = fmaf(xv4.x, s4.z, acc[0][2]);
      acc[0][3] = fmaf(xv4.x, s4.w, acc[0][3]);
      acc[1][0] = fmaf(xv4.y, s4.x, acc[1][0]);
      acc[1][1] = fmaf(xv4.y, s4.y, acc[1][1]);
      acc[1][2] = fmaf(xv4.y, s4.z, acc[1][2]);
      acc[1][3] = fmaf(xv4.y, s4.w, acc[1][3]);
      acc[2][0] = fmaf(xv4.z, s4.x, acc[2][0]);
      acc[2][1] = fmaf(xv4.z, s4.y, acc[2][1]);
      acc[2][2] = fmaf(xv4.z, s4.z, acc[2][2]);
      acc[2][3] = fmaf(xv4.z, s4.w, acc[2][3]);
      acc[3][0] = fmaf(xv4.w, s4.x, acc[3][0]);
      acc[3][1] = fmaf(xv4.w, s4.y, acc[3][1]);
      acc[3][2] = fmaf(xv4.w, s4.z, acc[3][2]);
      acc[3][3] = fmaf(xv4.w, s4.w, acc[3][3]);
    }
  }
  int slot = (b*64 + mt)*2 + part;
  #pragma unroll
  for (int ci=0;ci<4;++ci){
    int c = tc*4 + ci;
    *(float4*)&PP[slot*4096 + c*32 + tm8*4] =
      make_float4(acc[ci][0], acc[ci][1], acc[ci][2], acc[ci][3]);
  }
  if (tid < 32) CSP[slot*32 + tid] = csr;
}

// combine + transform epilogue: grid 512 = b(8) x mt(64). In-place on h.
__global__ __launch_bounds__(256) void k_sa_cc(const float* IN,
                                               const float* __restrict__ PP, const float* __restrict__ CSP,
                                               const float* __restrict__ Tw, const float* __restrict__ Tb,
                                               const float* __restrict__ Gs, const float* __restrict__ Bs,
                                               float* OUT){
  int blk = blockIdx.x;
  int mt = blk & 63, b = blk >> 6;
  int m0 = mt << 5;
  int tid = threadIdx.x;
  int tc = tid >> 3, tm8 = tid & 7;
  __shared__ __align__(16) float sm[4128];   // DL[128][32] @0, CS[32] @4096
  int s0 = (b*64 + mt)*2, s1 = s0 + 1;
  if (tid < 32) sm[4096 + tid] = CSP[s0*32 + tid] + CSP[s1*32 + tid];
  __syncthreads();
  #pragma unroll
  for (int ci=0;ci<4;++ci){
    int c = tc*4 + ci;
    float4 p0 = *(const float4*)&PP[s0*4096 + c*32 + tm8*4];
    float4 p1 = *(const float4*)&PP[s1*4096 + c*32 + tm8*4];
    float am[4] = {p0.x+p1.x, p0.y+p1.y, p0.z+p1.z, p0.w+p1.w};
    #pragma unroll
    for (int mi=0;mi<4;++mi){
      int ml = tm8*4 + mi;
      float cs = sm[4096 + ml];
      float xr = am[mi] / (1e-9f + cs);
      sm[c*32 + ml] = IN[b*HS + c*Nn + m0 + ml] - xr;
    }
  }
  __syncthreads();
  int hw = tid >> 5, m = tid & 31;
  float sroot = sqrtf(1.0f + 1e-5f);
  for (int oo=0; oo<16; ++oo){
    int o = oo*8 + hw;
    const float4* twp = (const float4*)(Tw + o*128);
    float a = 0.f;
    #pragma unroll
    for (int c4=0;c4<32;++c4){
      float4 wv = twp[c4];
      a = fmaf(wv.x, sm[(c4*4+0)*32 + m], a);
      a = fmaf(wv.y, sm[(c4*4+1)*32 + m], a);
      a = fmaf(wv.z, sm[(c4*4+2)*32 + m], a);
      a = fmaf(wv.w, sm[(c4*4+3)*32 + m], a);
    }
    a += Tb[o];
    float y = a * (Gs[o] / sroot) + Bs[o];
    y = fmaxf(y, 0.f);
    OUT[b*HS + o*Nn + m0 + m] = IN[b*HS + o*Nn + m0 + m] + y;
  }
}

// ---------------- progressive fuse: ACC += FW[:, l*128:(l+1)*128] * h_l ----------------
// grid 512 = b(8) x nt(32) x half(2); wave w covers o = hf*128 + w*32 + [0,32).
// fin: apply final BN + leaky-ReLU on the last layer's write (replaces k_fin).
__global__ __launch_bounds__(256) void k_fuse_part(const float* __restrict__ Hc, const float* __restrict__ FWT,
                                                   float* __restrict__ ACC, int l, int init, int fin,
                                                   const float* __restrict__ FGF, const float* __restrict__ FBF){
  int blk = blockIdx.x;
  int hf = blk & 1; int nt = (blk >> 1) & 31; int b = blk >> 6;
  int n0 = nt << 6;
  int w = threadIdx.x >> 6, lane = threadIdx.x & 63;
  __shared__ float xt[128*64];
  for (int e=threadIdx.x; e<8192; e+=256){
    int c = e >> 6, j = e & 63;
    xt[e] = Hc[(b*128 + c)*Nn + n0 + j];
  }
  __syncthreads();
  float4 a[8];
  #pragma unroll
  for (int j=0;j<8;++j) a[j] = make_float4(0.f,0.f,0.f,0.f);
  int ob = hf*128 + w*32;
  for (int c=0;c<128;++c){
    float xv = xt[c*64 + lane];
    const float4* wr = (const float4*)(FWT + (l*128+c)*256 + ob);
    #pragma unroll
    for (int j4=0;j4<8;++j4){
      float4 wv = wr[j4];
      a[j4].x = fmaf(wv.x, xv, a[j4].x);
      a[j4].y = fmaf(wv.y, xv, a[j4].y);
      a[j4].z = fmaf(wv.z, xv, a[j4].z);
      a[j4].w = fmaf(wv.w, xv, a[j4].w);
    }
  }
  float sroot = sqrtf(1.0f + 1e-5f);
  #pragma unroll
  for (int j4=0;j4<8;++j4){
    float vs[4] = {a[j4].x, a[j4].y, a[j4].z, a[j4].w};
    #pragma unroll
    for (int qq=0;qq<4;++qq){
      int o = ob + j4*4 + qq;
      int idx = (b*256 + o)*Nn + n0 + lane;
      float v = init ? vs[qq] : (ACC[idx] + vs[qq]);
      if (fin){
        float y = v * (FGF[o] / sroot) + FBF[o];
        y = (y >= 0.f) ? y : 0.2f*y;
        ACC[idx] = y;
      } else {
        ACC[idx] = v;
      }
    }
  }
}

extern "C" void kernel_launch(void* const* d_in, const int* in_sizes, int n_in,
                              void* d_out, int out_size, void* d_ws, size_t ws_size,
                              hipStream_t stream) {
  const float* X   = (const float*)d_in[0];
  const float* w1  = (const float*)d_in[1];
  const float* g1  = (const float*)d_in[2];
  const float* b1  = (const float*)d_in[3];
  const float* w2  = (const float*)d_in[4];
  const float* g2  = (const float*)d_in[5];
  const float* b2_ = (const float*)d_in[6];
  const float* w3  = (const float*)d_in[7];
  const float* g3  = (const float*)d_in[8];
  const float* b3  = (const float*)d_in[9];
  const float* w4  = (const float*)d_in[10];
  const float* g4  = (const float*)d_in[11];
  const float* b4  = (const float*)d_in[12];
  // d_in[13..15] = w5/g5/b5 : unused by reference
  const float* qk  = (const float*)d_in[16];
  const float* sv  = (const float*)d_in[17];
  const float* svb = (const float*)d_in[18];
  const float* st  = (const float*)d_in[19];
  const float* stb = (const float*)d_in[20];
  const float* sg  = (const float*)d_in[21];
  const float* sb  = (const float*)d_in[22];
  const float* fw  = (const float*)d_in[23];
  const float* fg  = (const float*)d_in[24];
  const float* fb  = (const float*)d_in[25];

  float* ws = (float*)d_ws;
  float* H    = ws + 0;          // 2,097,152
  float* QXb  = ws + 2097152;    //   524,288
  float* XVb  = ws + 2621440;    // 2,097,152 (ends 4,718,592)
  float* RMP  = ws + 4718592;    //   131,072
  float* RSP  = ws + 4849664;    //   131,072
  float* RMX  = ws + 4980736;    //    16,384
  float* RSM  = ws + 4997120;    //    16,384 (ends 5,013,504)
  // phase-1 overlay on [2,097,152 .. 4,915,200) — dead before SA phase:
  float* XX   = ws + 2146304;
  int*   IDX  = (int*)(ws + 2162688);
  float* X1T  = ws + 2818048;
  float* X2T  = ws + 3866624;    // ends 4,915,200
  float* C0   = ws + 5013504;
  float* W1T = C0 + 0;
  float* W2T = C0 + 384;
  float* W3T = C0 + 4480;
  float* W4T = C0 + 12672;
  float* FWT = C0 + 16768;       // C0 ends 5,161,344
  float* PP  = ws + 5161344;     // 4,194,304 (PV partials: 1024 slots x 4096)
  float* CSP = ws + 9355648;     //    32,768 — total 9,388,416 floats = 35.8 MiB
  float* ACC = (float*)d_out;

  k_xx1<<<64,256,0,stream>>>(X, XX);
  k_prep_wt<<<578,256,0,stream>>>(w1,w2,w3,w4,fw, W1T,W2T,W3T,W4T,FWT);
  k_knn1<<<4096,256,0,stream>>>(X, XX, IDX);
  k_ec1<<<16384,64,0,stream>>>(X, IDX, W1T, W2T, g1,b1,g2,b2_, X1T);
  k_xx2<<<64,256,0,stream>>>(X1T, XX);
  k_tr<<<256,256,0,stream>>>(X1T, H);                  // X1 -> channel-major (H ch 0..63), BEFORE knn2
  k_knn2<<<1024,256,0,stream>>>(H, XX, IDX);           // v2: 16 queries/block, LDS-staged slab
  k_ec2<<<16384,64,0,stream>>>(X1T, IDX, W3T, W4T, g3,b3,g4,b4, X2T);
  k_tr<<<256,256,0,stream>>>(X2T, H + 64*Nn);

  for (int l=0;l<4;++l){
    k_sa_a<<<512,256,0,stream>>>(H, qk + l*4096, sv + l*16384, svb + l*128, QXb, XVb);
    k_sa_b<<<512,256,0,stream>>>(QXb, RMP, RSP);
    k_sa_b2<<<64,256,0,stream>>>(RMP, RSP, RMX, RSM);
    k_sa_cm<<<1024,256,0,stream>>>(QXb, XVb, RMX, RSM, PP, CSP);
    k_sa_cc<<<512,256,0,stream>>>(H, PP, CSP,
                                  st + l*16384, stb + l*128, sg + l*128, sb + l*128, H);
    k_fuse_part<<<512,256,0,stream>>>(H, FWT, ACC, l, (l==0)?1:0, (l==3)?1:0, fg, fb);
  }
}

// Round 6
// 2622.893 us; speedup vs baseline: 1.1324x; 1.1324x over previous
//
#include <hip/hip_runtime.h>

#define Bb 8
#define Nn 2048
#define Kk 40
#define HS (128*Nn)   // h stride per batch (channel-major [b,128,2048])

// monotone float->uint transform: a > b  <=>  f2o(a) > f2o(b)
__device__ __forceinline__ unsigned f2o(float f){
  unsigned u = __float_as_uint(f);
  return (u & 0x80000000u) ? ~u : (u | 0x80000000u);
}

// Wave-cooperative exact top-40 of 2048, grouped rescan (4 groups of 8 slots).
// Lane owns m = slot*64+lane. Per round only the winner lane rescans its group;
// selection order identical to a full linear scan (value desc, index asc).
__device__ __forceinline__ void wave_top40(float* d, int lane, int* op){
  float gv[4]; int gs[4];
  #pragma unroll
  for (int g=0; g<4; ++g){
    float bv = d[g*8]; int bs = g*8;
    #pragma unroll
    for (int j=1;j<8;++j){
      float v = d[g*8+j];
      if (v > bv){ bv = v; bs = g*8+j; }
    }
    gv[g]=bv; gs[g]=bs;
  }
  for (int t=0; t<Kk; ++t){
    float bv = gv[0]; int bs = gs[0];
    if (gv[1] > bv){ bv=gv[1]; bs=gs[1]; }
    if (gv[2] > bv){ bv=gv[2]; bs=gs[2]; }
    if (gv[3] > bv){ bv=gv[3]; bs=gs[3]; }
    int bm = bs*64 + lane;
    unsigned long long key = ((unsigned long long)f2o(bv) << 32) | (unsigned)(~bm);
    #pragma unroll
    for (int s=32;s>0;s>>=1){
      unsigned long long o = __shfl_xor(key, s, 64);
      if (o > key) key = o;
    }
    int wm = (int)(~(unsigned)key);
    if (lane == 0) op[t] = wm;
    bool mine = ((wm & 63) == lane);
    int wsl = wm >> 6;
    if (mine){
      int G = wsl >> 3;
      #pragma unroll
      for (int g=0; g<4; ++g){
        if (g == G){
          float nv = -__builtin_inff(); int ns = g*8;
          #pragma unroll
          for (int j=0;j<8;++j){
            float v = d[g*8+j];
            if (g*8+j == wsl) v = -__builtin_inff();
            d[g*8+j] = v;
            if (v > nv){ nv=v; ns=g*8+j; }
          }
          gv[g]=nv; gs[g]=ns;
        }
      }
    }
  }
}

// Variant for mapping m = (s>>2)*256 + lane*4 + (s&3) (coalesced float4 ownership).
// Within a lane m is increasing in s, so the same grouped tie-break is exact.
__device__ __forceinline__ void wave_top40_g(float* d, int lane, int* op){
  float gv[4]; int gs[4];
  #pragma unroll
  for (int g=0; g<4; ++g){
    float bv = d[g*8]; int bs = g*8;
    #pragma unroll
    for (int j=1;j<8;++j){
      float v = d[g*8+j];
      if (v > bv){ bv = v; bs = g*8+j; }
    }
    gv[g]=bv; gs[g]=bs;
  }
  for (int t=0; t<Kk; ++t){
    float bv = gv[0]; int bs = gs[0];
    if (gv[1] > bv){ bv=gv[1]; bs=gs[1]; }
    if (gv[2] > bv){ bv=gv[2]; bs=gs[2]; }
    if (gv[3] > bv){ bv=gv[3]; bs=gs[3]; }
    int bm = ((bs>>2)<<8) + lane*4 + (bs&3);
    unsigned long long key = ((unsigned long long)f2o(bv) << 32) | (unsigned)(~bm);
    #pragma unroll
    for (int s=32;s>0;s>>=1){
      unsigned long long o = __shfl_xor(key, s, 64);
      if (o > key) key = o;
    }
    int wm = (int)(~(unsigned)key);
    if (lane == 0) op[t] = wm;
    bool mine = (((wm>>2) & 63) == lane);
    int wsl = ((wm>>8)<<2) | (wm & 3);
    if (mine){
      int G = wsl >> 3;
      #pragma unroll
      for (int g=0; g<4; ++g){
        if (g == G){
          float nv = -__builtin_inff(); int ns = g*8;
          #pragma unroll
          for (int j=0;j<8;++j){
            float v = d[g*8+j];
            if (g*8+j == wsl) v = -__builtin_inff();
            d[g*8+j] = v;
            if (v > nv){ nv=v; ns=g*8+j; }
          }
          gv[g]=nv; gs[g]=ns;
        }
      }
    }
  }
}

// ---------------- prep ----------------
__global__ __launch_bounds__(256) void k_xx1(const float* __restrict__ x, float* __restrict__ XX){
  int e = blockIdx.x*256 + threadIdx.x;
  if (e >= Bb*Nn) return;
  float p0 = x[e*3+0], p1 = x[e*3+1], p2 = x[e*3+2];
  XX[e] = __fadd_rn(__fadd_rn(__fmul_rn(p0,p0), __fmul_rn(p1,p1)), __fmul_rn(p2,p2));
}

__global__ __launch_bounds__(256) void k_prep_wt(const float* __restrict__ w1, const float* __restrict__ w2,
                                                 const float* __restrict__ w3, const float* __restrict__ w4,
                                                 const float* __restrict__ fw,
                                                 float* __restrict__ W1T, float* __restrict__ W2T,
                                                 float* __restrict__ W3T, float* __restrict__ W4T,
                                                 float* __restrict__ FWT){
  int e = blockIdx.x*256 + threadIdx.x;
  if (e < 384)   { int i=e/64,  c=e%64;  W1T[e] = w1[c*6+i];    return; } e -= 384;
  if (e < 4096)  { int i=e/64,  c=e%64;  W2T[e] = w2[c*64+i];   return; } e -= 4096;
  if (e < 8192)  { int i=e/64,  c=e%64;  W3T[e] = w3[c*128+i];  return; } e -= 8192;
  if (e < 4096)  { int i=e/64,  c=e%64;  W4T[e] = w4[c*64+i];   return; } e -= 4096;
  if (e < 131072){ int i=e/256, o=e%256; FWT[e] = fw[o*512+i];  return; }
}

// ---------------- knn on 3-D points: 1 wave / query, LDS-staged cloud ----------------
__global__ __launch_bounds__(256) void k_knn1(const float* __restrict__ P, const float* __restrict__ XX,
                                              int* __restrict__ IDX){
  int blk = blockIdx.x;
  int b = blk >> 9;
  int w = threadIdx.x >> 6, lane = threadIdx.x & 63;
  int n = (blk & 511)*4 + w;
  const float* Pb = P + b*Nn*3;
  const float* xb = XX + b*Nn;
  __shared__ float Pl[Nn*3];
  __shared__ float Xl[Nn];
  for (int e = threadIdx.x; e < Nn*3; e += 256) Pl[e] = Pb[e];
  for (int e = threadIdx.x; e < Nn; e += 256) Xl[e] = xb[e];
  __syncthreads();
  float c0 = Pl[n*3+0], c1 = Pl[n*3+1], c2 = Pl[n*3+2];
  float xn = Xl[n];
  float d[32];
  #pragma unroll
  for (int j=0;j<32;++j){
    int m = j*64 + lane;
    float a0 = Pl[m*3+0], a1 = Pl[m*3+1], a2 = Pl[m*3+2];
    float in_ = __fadd_rn(__fadd_rn(__fmul_rn(c0,a0), __fmul_rn(c1,a1)), __fmul_rn(c2,a2));
    d[j] = __fsub_rn(__fsub_rn(__fmul_rn(2.0f,in_), xn), Xl[m]);
  }
  wave_top40(d, lane, IDX + (b*Nn+n)*Kk);
}

// ---------------- edge conv 1+2 + maxpool (bit-exact _rn path) ----------------
__global__ __launch_bounds__(64) void k_ec1(const float* __restrict__ P, const int* __restrict__ IDX,
                                            const float* __restrict__ W1T, const float* __restrict__ W2T,
                                            const float* __restrict__ g1, const float* __restrict__ b1,
                                            const float* __restrict__ g2, const float* __restrict__ b2,
                                            float* __restrict__ X1T){
  int e = blockIdx.x;           // global point row 0..16383
  int b = e >> 11;
  int lane = threadIdx.x;
  __shared__ float dC[Kk*4];
  __shared__ __align__(16) float y1L[64*44];
  float c0 = P[e*3+0], c1 = P[e*3+1], c2 = P[e*3+2];
  if (lane < Kk) {
    int idx = IDX[e*Kk + lane] & (Nn-1);
    const float* pn = P + (b*Nn + idx)*3;
    dC[lane*4+0] = __fsub_rn(pn[0], c0);
    dC[lane*4+1] = __fsub_rn(pn[1], c1);
    dC[lane*4+2] = __fsub_rn(pn[2], c2);
  }
  __syncthreads();
  float w10 = W1T[0*64+lane], w11 = W1T[1*64+lane], w12 = W1T[2*64+lane];
  float w13 = W1T[3*64+lane], w14 = W1T[4*64+lane], w15 = W1T[5*64+lane];
  float p3 = __fmul_rn(w13,c0), p4 = __fmul_rn(w14,c1), p5 = __fmul_rn(w15,c2);
  float s1 = __fdiv_rn(g1[lane], __fsqrt_rn(1.0f + 1e-5f));
  float o1 = b1[lane];
  for (int k=0;k<Kk;++k){
    float t = __fmul_rn(w10, dC[k*4+0]);
    t = __fadd_rn(t, __fmul_rn(w11, dC[k*4+1]));
    t = __fadd_rn(t, __fmul_rn(w12, dC[k*4+2]));
    t = __fadd_rn(t, p3); t = __fadd_rn(t, p4); t = __fadd_rn(t, p5);
    float y = __fadd_rn(__fmul_rn(t, s1), o1);
    y = (y >= 0.0f) ? y : __fmul_rn(0.2f, y);
    y1L[lane*44+k] = y;
  }
  __syncthreads();
  float4 q[10];
  #pragma unroll
  for (int k4=0;k4<10;++k4) q[k4] = make_float4(0.f,0.f,0.f,0.f);
  for (int i=0;i<64;++i){
    float w = W2T[i*64+lane];
    const float4* yp = (const float4*)&y1L[i*44];
    #pragma unroll
    for (int k4=0;k4<10;++k4){
      float4 yv = yp[k4];
      q[k4].x = __fadd_rn(q[k4].x, __fmul_rn(w, yv.x));
      q[k4].y = __fadd_rn(q[k4].y, __fmul_rn(w, yv.y));
      q[k4].z = __fadd_rn(q[k4].z, __fmul_rn(w, yv.z));
      q[k4].w = __fadd_rn(q[k4].w, __fmul_rn(w, yv.w));
    }
  }
  float s2 = __fdiv_rn(g2[lane], __fsqrt_rn(1.0f + 1e-5f));
  float o2 = b2[lane];
  float mx = -__builtin_inff();
  #pragma unroll
  for (int k4=0;k4<10;++k4){
    float vs[4] = {q[k4].x, q[k4].y, q[k4].z, q[k4].w};
    #pragma unroll
    for (int j=0;j<4;++j){
      float y = __fadd_rn(__fmul_rn(vs[j], s2), o2);
      y = (y >= 0.0f) ? y : __fmul_rn(0.2f, y);
      mx = fmaxf(mx, y);
    }
  }
  X1T[e*64 + lane] = mx;
}

__global__ __launch_bounds__(256) void k_xx2(const float* __restrict__ X1T, float* __restrict__ XX2){
  int e = blockIdx.x*256 + threadIdx.x;
  const float* r = X1T + e*64;
  float a = 0.f;
  for (int c=0;c<64;++c) a = __fadd_rn(a, __fmul_rn(r[c], r[c]));
  XX2[e] = a;
}

// ---------------- knn on 64-D features ----------------
// v3: 2 queries/wave (8/block, grid 2048), direct-L2 float4 reads shared
// across both queries (halves L2 traffic vs v1: 8 MACs/load instead of 4),
// NO slab LDS staging and no per-chunk barriers (v2's occupancy collapse:
// 40.7%->11.8%, VALUBusy 23%, 602us). LDS = 2KB query features only.
// Per-query accumulation order (c = 0..63 ascending, _rn mul+add) and float4
// ownership (m = j*256 + lane*4 + comp) identical to v1 -> wave_top40_g
// selection is bit-exact vs the passing kernel.
__global__ __launch_bounds__(256) void k_knn2(const float* __restrict__ X1C, const float* __restrict__ XX2,
                                              int* __restrict__ IDX){
  int blk = blockIdx.x;
  int b = blk >> 8;                 // 256 blocks per batch
  int n0 = (blk & 255) << 3;        // 8 queries per block
  int w = threadIdx.x >> 6, lane = threadIdx.x & 63;
  __shared__ float qL[8*64];        // [q][c] query features (2 KB)
  for (int e=threadIdx.x; e<512; e+=256){
    int q = e >> 6, c = e & 63;
    qL[e] = X1C[b*HS + c*Nn + n0 + q];
  }
  __syncthreads();
  float4 a0[8], a1[8];
  #pragma unroll
  for (int j=0;j<8;++j){
    a0[j] = make_float4(0.f,0.f,0.f,0.f);
    a1[j] = make_float4(0.f,0.f,0.f,0.f);
  }
  for (int c=0;c<64;++c){
    const float4* row = (const float4*)(X1C + b*HS + c*Nn);
    float q0 = qL[(w*2+0)*64 + c];
    float q1 = qL[(w*2+1)*64 + c];
    #pragma unroll
    for (int j=0;j<8;++j){
      float4 v = row[j*64 + lane];
      a0[j].x = __fadd_rn(a0[j].x, __fmul_rn(q0, v.x));
      a0[j].y = __fadd_rn(a0[j].y, __fmul_rn(q0, v.y));
      a0[j].z = __fadd_rn(a0[j].z, __fmul_rn(q0, v.z));
      a0[j].w = __fadd_rn(a0[j].w, __fmul_rn(q0, v.w));
      a1[j].x = __fadd_rn(a1[j].x, __fmul_rn(q1, v.x));
      a1[j].y = __fadd_rn(a1[j].y, __fmul_rn(q1, v.y));
      a1[j].z = __fadd_rn(a1[j].z, __fmul_rn(q1, v.z));
      a1[j].w = __fadd_rn(a1[j].w, __fmul_rn(q1, v.w));
    }
  }
  const float* xb = XX2 + b*Nn;
  const float4* xb4 = (const float4*)xb;
  {
    int n = n0 + w*2 + 0;
    float xn = xb[n];
    float d[32];
    #pragma unroll
    for (int j=0;j<8;++j){
      float4 xm = xb4[j*64 + lane];
      d[j*4+0] = __fsub_rn(__fsub_rn(__fmul_rn(2.0f, a0[j].x), xn), xm.x);
      d[j*4+1] = __fsub_rn(__fsub_rn(__fmul_rn(2.0f, a0[j].y), xn), xm.y);
      d[j*4+2] = __fsub_rn(__fsub_rn(__fmul_rn(2.0f, a0[j].z), xn), xm.z);
      d[j*4+3] = __fsub_rn(__fsub_rn(__fmul_rn(2.0f, a0[j].w), xn), xm.w);
    }
    wave_top40_g(d, lane, IDX + (b*Nn + n)*Kk);
  }
  {
    int n = n0 + w*2 + 1;
    float xn = xb[n];
    float d[32];
    #pragma unroll
    for (int j=0;j<8;++j){
      float4 xm = xb4[j*64 + lane];
      d[j*4+0] = __fsub_rn(__fsub_rn(__fmul_rn(2.0f, a1[j].x), xn), xm.x);
      d[j*4+1] = __fsub_rn(__fsub_rn(__fmul_rn(2.0f, a1[j].y), xn), xm.y);
      d[j*4+2] = __fsub_rn(__fsub_rn(__fmul_rn(2.0f, a1[j].z), xn), xm.z);
      d[j*4+3] = __fsub_rn(__fsub_rn(__fmul_rn(2.0f, a1[j].w), xn), xm.w);
    }
    wave_top40_g(d, lane, IDX + (b*Nn + n)*Kk);
  }
}

// ---------------- edge conv 3+4 + maxpool (fma ok) ----------------
__global__ __launch_bounds__(64) void k_ec2(const float* __restrict__ X1T, const int* __restrict__ IDX,
                                            const float* __restrict__ W3T, const float* __restrict__ W4T,
                                            const float* __restrict__ g3, const float* __restrict__ b3,
                                            const float* __restrict__ g4, const float* __restrict__ b4,
                                            float* __restrict__ X2T){
  int e = blockIdx.x; int b = e >> 11; int lane = threadIdx.x;
  __shared__ __align__(16) float dL[64*44];
  __shared__ float ctrL[64];
  float ctr = X1T[e*64 + lane];
  ctrL[lane] = ctr;
  __syncthreads();
  for (int k=0;k<Kk;++k){
    int idx = IDX[e*Kk + k] & (Nn-1);
    dL[lane*44 + k] = X1T[(b*Nn+idx)*64 + lane] - ctr;
  }
  __syncthreads();
  float base = 0.f;
  for (int i=0;i<64;++i) base = fmaf(W3T[(64+i)*64 + lane], ctrL[i], base);
  float4 q[10];
  #pragma unroll
  for (int k4=0;k4<10;++k4) q[k4] = make_float4(base,base,base,base);
  for (int i=0;i<64;++i){
    float w = W3T[i*64 + lane];
    const float4* dp = (const float4*)&dL[i*44];
    #pragma unroll
    for (int k4=0;k4<10;++k4){
      float4 d = dp[k4];
      q[k4].x = fmaf(w, d.x, q[k4].x);
      q[k4].y = fmaf(w, d.y, q[k4].y);
      q[k4].z = fmaf(w, d.z, q[k4].z);
      q[k4].w = fmaf(w, d.w, q[k4].w);
    }
  }
  float s3 = g3[lane] / sqrtf(1.0f+1e-5f);
  float o3 = b3[lane];
  __syncthreads();
  #pragma unroll
  for (int k4=0;k4<10;++k4){
    float4 y;
    y.x = q[k4].x*s3 + o3; y.x = (y.x>=0.f)?y.x:0.2f*y.x;
    y.y = q[k4].y*s3 + o3; y.y = (y.y>=0.f)?y.y:0.2f*y.y;
    y.z = q[k4].z*s3 + o3; y.z = (y.z>=0.f)?y.z:0.2f*y.z;
    y.w = q[k4].w*s3 + o3; y.w = (y.w>=0.f)?y.w:0.2f*y.w;
    *(float4*)&dL[lane*44 + k4*4] = y;
  }
  __syncthreads();
  float4 p[10];
  #pragma unroll
  for (int k4=0;k4<10;++k4) p[k4] = make_float4(0.f,0.f,0.f,0.f);
  for (int i=0;i<64;++i){
    float w = W4T[i*64 + lane];
    const float4* yp = (const float4*)&dL[i*44];
    #pragma unroll
    for (int k4=0;k4<10;++k4){
      float4 yv = yp[k4];
      p[k4].x = fmaf(w, yv.x, p[k4].x);
      p[k4].y = fmaf(w, yv.y, p[k4].y);
      p[k4].z = fmaf(w, yv.z, p[k4].z);
      p[k4].w = fmaf(w, yv.w, p[k4].w);
    }
  }
  float s4 = g4[lane] / sqrtf(1.0f+1e-5f);
  float o4 = b4[lane];
  float mx = -__builtin_inff();
  #pragma unroll
  for (int k4=0;k4<10;++k4){
    float vs[4] = {p[k4].x, p[k4].y, p[k4].z, p[k4].w};
    #pragma unroll
    for (int j=0;j<4;++j){
      float y = vs[j]*s4 + o4;
      y = (y>=0.f)?y:0.2f*y;
      mx = fmaxf(mx, y);
    }
  }
  X2T[e*64 + lane] = mx;
}

// (b,n,64) -> (b,c,n); dst pre-offset by channel base; dst batch stride = HS
__global__ __launch_bounds__(256) void k_tr(const float* __restrict__ src, float* __restrict__ dst){
  int b = blockIdx.x >> 5; int n0 = (blockIdx.x & 31) << 6;
  __shared__ float t[64*65];
  for (int e=threadIdx.x; e<4096; e+=256){
    int r = e >> 6, c = e & 63;
    t[r*65+c] = src[(b*Nn + n0 + r)*64 + c];
  }
  __syncthreads();
  for (int e=threadIdx.x; e<4096; e+=256){
    int c = e >> 6, r = e & 63;
    dst[b*HS + c*Nn + n0 + r] = t[r*65+c];
  }
}

// ---------------- SA layer ----------------
// grid 512 = b(8) x nt(32) x part(2); unified rows: r<32 -> QX row r, else XV row r-32.
__global__ __launch_bounds__(256) void k_sa_a(const float* __restrict__ IN,
                                              const float* __restrict__ QKw, const float* __restrict__ Vw,
                                              const float* __restrict__ Vb,
                                              float* __restrict__ QX, float* __restrict__ XV){
  int blk = blockIdx.x;
  int part = blk & 1; int nt = (blk >> 1) & 31; int b = blk >> 6;
  int n0 = nt << 6;
  int w = threadIdx.x >> 6, lane = threadIdx.x & 63;
  __shared__ float xl[128*64];
  for (int e=threadIdx.x; e<8192; e+=256){
    int c = e >> 6, j = e & 63;
    xl[e] = IN[b*HS + c*Nn + n0 + j];
  }
  __syncthreads();
  for (int i=0;i<20;++i){
    int r = part*80 + w*20 + i;
    const float4* wp4;
    if (r < 32) wp4 = (const float4*)(QKw + r*128);
    else        wp4 = (const float4*)(Vw + (r-32)*128);
    float a = 0.f;
    #pragma unroll
    for (int c4=0;c4<32;++c4){
      float4 wv = wp4[c4];
      a = fmaf(wv.x, xl[(c4*4+0)*64 + lane], a);
      a = fmaf(wv.y, xl[(c4*4+1)*64 + lane], a);
      a = fmaf(wv.z, xl[(c4*4+2)*64 + lane], a);
      a = fmaf(wv.w, xl[(c4*4+3)*64 + lane], a);
    }
    if (r < 32) QX[(b*32+r)*Nn + n0 + lane] = a;
    else { int o = r-32; XV[(b*128+o)*Nn + n0 + lane] = a + Vb[o]; }
  }
}

// m-split x8: grid 512 = b(8) x nc(8) x mc(8)
__global__ __launch_bounds__(256) void k_sa_b(const float* __restrict__ QX,
                                              float* __restrict__ RMP, float* __restrict__ RSP){
  int blk = blockIdx.x;
  int b = blk >> 6, sub = blk & 63;
  int ncn = sub >> 3, mcn = sub & 7;
  int n = ncn*256 + threadIdx.x;
  float q[32];
  #pragma unroll
  for (int o=0;o<32;++o) q[o] = QX[(b*32+o)*Nn + n];
  __shared__ float qt[32*128];
  float mr = -__builtin_inff(), lr = 0.f;
  int m0 = mcn*256;
  for (int t=0;t<2;++t){
    for (int e=threadIdx.x; e<4096; e+=256){
      int o = e >> 7, mm = e & 127;
      qt[e] = QX[(b*32+o)*Nn + m0 + t*128 + mm];
    }
    __syncthreads();
    for (int mm=0;mm<128;mm+=2){
      float e0=0.f, e1=0.f;
      #pragma unroll
      for (int o=0;o<32;++o){ float qo=q[o]; e0=fmaf(qo, qt[o*128+mm], e0); e1=fmaf(qo, qt[o*128+mm+1], e1); }
      if (e0 > mr){ lr = lr*expf(mr-e0) + 1.f; mr = e0; } else lr += expf(e0-mr);
      if (e1 > mr){ lr = lr*expf(mr-e1) + 1.f; mr = e1; } else lr += expf(e1-mr);
    }
    __syncthreads();
  }
  RMP[(b*Nn+n)*8 + mcn] = mr;
  RSP[(b*Nn+n)*8 + mcn] = lr;
}

__global__ __launch_bounds__(256) void k_sa_b2(const float* __restrict__ RMP, const float* __restrict__ RSP,
                                               float* __restrict__ RMX, float* __restrict__ RSM){
  int e = blockIdx.x*256 + threadIdx.x;
  float M = -__builtin_inff();
  #pragma unroll
  for (int i=0;i<8;++i) M = fmaxf(M, RMP[e*8+i]);
  float l = 0.f;
  #pragma unroll
  for (int i=0;i<8;++i) l += RSP[e*8+i]*expf(RMP[e*8+i]-M);
  RMX[e] = M; RSM[e] = l;
}

// LDS map (floats): QM[32o][32m]=1024 @0, QN[32o][32n]=1024 @1024,
// XVt[32n][132]=4224 @2048, SL[32n][32m]=1024 @6272, MX@7296, RL@7328.
#define SM_QM 0
#define SM_QN 1024
#define SM_XV 2048
#define SM_SL 6272
#define SM_MX 7296
#define SM_RL 7328

// main: grid 1024 = b(8) x mt(64) x part(2); n-range split in 2; writes PV and
// column-sum partials to PP/CSP.
__global__ __launch_bounds__(256) void k_sa_cm(const float* __restrict__ QX, const float* __restrict__ XV,
                                               const float* __restrict__ RMAX, const float* __restrict__ RSUM,
                                               float* __restrict__ PP, float* __restrict__ CSP){
  int blk = blockIdx.x;
  int part = blk & 1, mt = (blk >> 1) & 63, b = blk >> 7;
  int m0 = mt << 5;
  int tid = threadIdx.x;
  int nnp = tid >> 4, mmp = tid & 15;      // 2x2 S-microtile owner
  int tc = tid >> 3, tm8 = tid & 7;        // PV owner: c=tc*4+ci, m=tm8*4+mi
  __shared__ __align__(16) float sm[7360];
  for (int e=tid; e<1024; e+=256){
    int o = e >> 5, mm = e & 31;
    sm[SM_QM + e] = QX[(b*32+o)*Nn + m0 + mm];
  }
  float acc[4][4];
  #pragma unroll
  for (int ci=0;ci<4;++ci){
    #pragma unroll
    for (int mi=0;mi<4;++mi) acc[ci][mi] = 0.f;
  }
  float csr = 0.f;
  int it0 = part*32;
  for (int it=it0; it<it0+32; ++it){
    int nb = it*32;
    __syncthreads();
    for (int e=tid; e<1024; e+=256){ int o=e>>5, nn=e&31; sm[SM_QN+e] = QX[(b*32+o)*Nn + nb + nn]; }
    for (int e=tid; e<4096; e+=256){ int c=e>>5, nn=e&31; sm[SM_XV + nn*132 + c] = XV[(b*128+c)*Nn + nb + nn]; }
    if (tid < 32){ sm[SM_MX+tid] = RMAX[b*Nn + nb + tid]; sm[SM_RL+tid] = 1.0f / RSUM[b*Nn + nb + tid]; }
    __syncthreads();
    float e00=0.f, e01=0.f, e10=0.f, e11=0.f;
    #pragma unroll
    for (int o=0;o<32;++o){
      float2 qn = *(const float2*)&sm[SM_QN + o*32 + nnp*2];
      float2 qm = *(const float2*)&sm[SM_QM + o*32 + mmp*2];
      e00 = fmaf(qn.x, qm.x, e00);
      e01 = fmaf(qn.x, qm.y, e01);
      e10 = fmaf(qn.y, qm.x, e10);
      e11 = fmaf(qn.y, qm.y, e11);
    }
    float mx0 = sm[SM_MX + nnp*2],   rl0 = sm[SM_RL + nnp*2];
    float mx1 = sm[SM_MX + nnp*2+1], rl1 = sm[SM_RL + nnp*2+1];
    float2 s0; s0.x = expf(e00-mx0)*rl0; s0.y = expf(e01-mx0)*rl0;
    float2 s1; s1.x = expf(e10-mx1)*rl1; s1.y = expf(e11-mx1)*rl1;
    *(float2*)&sm[SM_SL + (nnp*2  )*32 + mmp*2] = s0;
    *(float2*)&sm[SM_SL + (nnp*2+1)*32 + mmp*2] = s1;
    __syncthreads();
    if (tid < 32){
      #pragma unroll
      for (int nn=0;nn<32;++nn) csr += sm[SM_SL + nn*32 + tid];
    }
    #pragma unroll 8
    for (int nn=0;nn<32;++nn){
      float4 xv4 = *(const float4*)&sm[SM_XV + nn*132 + tc*4];
      float4 s4  = *(const float4*)&sm[SM_SL + nn*32  + tm8*4];
      acc[0][0] = fmaf(xv4.x, s4.x, acc[0][0]);
      acc[0][1] = fmaf(xv4.x, s4.y, acc[0][1]);
      acc[0][2] = fmaf(xv4.x, s4.z, acc[0][2]);
      acc[0][3] = fmaf(xv4.x, s4.w, acc[0][3]);
      acc[1][0] = fmaf(xv4.y, s4.x, acc[1][0]);
      acc[1][1] = fmaf(xv4.y, s4.y, acc[1][1]);
      acc[1][2] = fmaf(xv4.y, s4.z, acc[1][2]);
      acc[1][3] = fmaf(xv4.y, s4.w, acc[1][3]);
      acc[2][0] = fmaf(xv4.z, s4.x, acc[2][0]);
      acc[2][1] = fmaf(xv4.z, s4.y, acc[2][1]);
      acc[2][2] = fmaf(xv4.z, s4.z, acc[2][2]);
      acc[2][3] = fmaf(xv4.z, s4.w, acc[2][3]);
      acc[3][0] = fmaf(xv4.w, s4.x, acc[3][0]);
      acc[3][1] = fmaf(xv4.w, s4.y, acc[3][1]);
      acc[3][2] = fmaf(xv4.w, s4.z, acc[3][2]);
      acc[3][3] = fmaf(xv4.w, s4.w, acc[3][3]);
    }
  }
  int slot = (b*64 + mt)*2 + part;
  #pragma unroll
  for (int ci=0;ci<4;++ci){
    int c = tc*4 + ci;
    *(float4*)&PP[slot*4096 + c*32 + tm8*4] =
      make_float4(acc[ci][0], acc[ci][1], acc[ci][2], acc[ci][3]);
  }
  if (tid < 32) CSP[slot*32 + tid] = csr;
}

// combine + transform epilogue: grid 512 = b(8) x mt(64). In-place on h.
__global__ __launch_bounds__(256) void k_sa_cc(const float* IN,
                                               const float* __restrict__ PP, const float* __restrict__ CSP,
                                               const float* __restrict__ Tw, const float* __restrict__ Tb,
                                               const float* __restrict__ Gs, const float* __restrict__ Bs,
                                               float* OUT){
  int blk = blockIdx.x;
  int mt = blk & 63, b = blk >> 6;
  int m0 = mt << 5;
  int tid = threadIdx.x;
  int tc = tid >> 3, tm8 = tid & 7;
  __shared__ __align__(16) float sm[4128];   // DL[128][32] @0, CS[32] @4096
  int s0 = (b*64 + mt)*2, s1 = s0 + 1;
  if (tid < 32) sm[4096 + tid] = CSP[s0*32 + tid] + CSP[s1*32 + tid];
  __syncthreads();
  #pragma unroll
  for (int ci=0;ci<4;++ci){
    int c = tc*4 + ci;
    float4 p0 = *(const float4*)&PP[s0*4096 + c*32 + tm8*4];
    float4 p1 = *(const float4*)&PP[s1*4096 + c*32 + tm8*4];
    float am[4] = {p0.x+p1.x, p0.y+p1.y, p0.z+p1.z, p0.w+p1.w};
    #pragma unroll
    for (int mi=0;mi<4;++mi){
      int ml = tm8*4 + mi;
      float cs = sm[4096 + ml];
      float xr = am[mi] / (1e-9f + cs);
      sm[c*32 + ml] = IN[b*HS + c*Nn + m0 + ml] - xr;
    }
  }
  __syncthreads();
  int hw = tid >> 5, m = tid & 31;
  float sroot = sqrtf(1.0f + 1e-5f);
  for (int oo=0; oo<16; ++oo){
    int o = oo*8 + hw;
    const float4* twp = (const float4*)(Tw + o*128);
    float a = 0.f;
    #pragma unroll
    for (int c4=0;c4<32;++c4){
      float4 wv = twp[c4];
      a = fmaf(wv.x, sm[(c4*4+0)*32 + m], a);
      a = fmaf(wv.y, sm[(c4*4+1)*32 + m], a);
      a = fmaf(wv.z, sm[(c4*4+2)*32 + m], a);
      a = fmaf(wv.w, sm[(c4*4+3)*32 + m], a);
    }
    a += Tb[o];
    float y = a * (Gs[o] / sroot) + Bs[o];
    y = fmaxf(y, 0.f);
    OUT[b*HS + o*Nn + m0 + m] = IN[b*HS + o*Nn + m0 + m] + y;
  }
}

// ---------------- progressive fuse: ACC += FW[:, l*128:(l+1)*128] * h_l ----------------
// grid 512 = b(8) x nt(32) x half(2); wave w covers o = hf*128 + w*32 + [0,32).
// fin: apply final BN + leaky-ReLU on the last layer's write (replaces k_fin).
__global__ __launch_bounds__(256) void k_fuse_part(const float* __restrict__ Hc, const float* __restrict__ FWT,
                                                   float* __restrict__ ACC, int l, int init, int fin,
                                                   const float* __restrict__ FGF, const float* __restrict__ FBF){
  int blk = blockIdx.x;
  int hf = blk & 1; int nt = (blk >> 1) & 31; int b = blk >> 6;
  int n0 = nt << 6;
  int w = threadIdx.x >> 6, lane = threadIdx.x & 63;
  __shared__ float xt[128*64];
  for (int e=threadIdx.x; e<8192; e+=256){
    int c = e >> 6, j = e & 63;
    xt[e] = Hc[(b*128 + c)*Nn + n0 + j];
  }
  __syncthreads();
  float4 a[8];
  #pragma unroll
  for (int j=0;j<8;++j) a[j] = make_float4(0.f,0.f,0.f,0.f);
  int ob = hf*128 + w*32;
  for (int c=0;c<128;++c){
    float xv = xt[c*64 + lane];
    const float4* wr = (const float4*)(FWT + (l*128+c)*256 + ob);
    #pragma unroll
    for (int j4=0;j4<8;++j4){
      float4 wv = wr[j4];
      a[j4].x = fmaf(wv.x, xv, a[j4].x);
      a[j4].y = fmaf(wv.y, xv, a[j4].y);
      a[j4].z = fmaf(wv.z, xv, a[j4].z);
      a[j4].w = fmaf(wv.w, xv, a[j4].w);
    }
  }
  float sroot = sqrtf(1.0f + 1e-5f);
  #pragma unroll
  for (int j4=0;j4<8;++j4){
    float vs[4] = {a[j4].x, a[j4].y, a[j4].z, a[j4].w};
    #pragma unroll
    for (int qq=0;qq<4;++qq){
      int o = ob + j4*4 + qq;
      int idx = (b*256 + o)*Nn + n0 + lane;
      float v = init ? vs[qq] : (ACC[idx] + vs[qq]);
      if (fin){
        float y = v * (FGF[o] / sroot) + FBF[o];
        y = (y >= 0.f) ? y : 0.2f*y;
        ACC[idx] = y;
      } else {
        ACC[idx] = v;
      }
    }
  }
}

extern "C" void kernel_launch(void* const* d_in, const int* in_sizes, int n_in,
                              void* d_out, int out_size, void* d_ws, size_t ws_size,
                              hipStream_t stream) {
  const float* X   = (const float*)d_in[0];
  const float* w1  = (const float*)d_in[1];
  const float* g1  = (const float*)d_in[2];
  const float* b1  = (const float*)d_in[3];
  const float* w2  = (const float*)d_in[4];
  const float* g2  = (const float*)d_in[5];
  const float* b2_ = (const float*)d_in[6];
  const float* w3  = (const float*)d_in[7];
  const float* g3  = (const float*)d_in[8];
  const float* b3  = (const float*)d_in[9];
  const float* w4  = (const float*)d_in[10];
  const float* g4  = (const float*)d_in[11];
  const float* b4  = (const float*)d_in[12];
  // d_in[13..15] = w5/g5/b5 : unused by reference
  const float* qk  = (const float*)d_in[16];
  const float* sv  = (const float*)d_in[17];
  const float* svb = (const float*)d_in[18];
  const float* st  = (const float*)d_in[19];
  const float* stb = (const float*)d_in[20];
  const float* sg  = (const float*)d_in[21];
  const float* sb  = (const float*)d_in[22];
  const float* fw  = (const float*)d_in[23];
  const float* fg  = (const float*)d_in[24];
  const float* fb  = (const float*)d_in[25];

  float* ws = (float*)d_ws;
  float* H    = ws + 0;          // 2,097,152
  float* QXb  = ws + 2097152;    //   524,288
  float* XVb  = ws + 2621440;    // 2,097,152 (ends 4,718,592)
  float* RMP  = ws + 4718592;    //   131,072
  float* RSP  = ws + 4849664;    //   131,072
  float* RMX  = ws + 4980736;    //    16,384
  float* RSM  = ws + 4997120;    //    16,384 (ends 5,013,504)
  // phase-1 overlay on [2,097,152 .. 4,915,200) — dead before SA phase:
  float* XX   = ws + 2146304;
  int*   IDX  = (int*)(ws + 2162688);
  float* X1T  = ws + 2818048;
  float* X2T  = ws + 3866624;    // ends 4,915,200
  float* C0   = ws + 5013504;
  float* W1T = C0 + 0;
  float* W2T = C0 + 384;
  float* W3T = C0 + 4480;
  float* W4T = C0 + 12672;
  float* FWT = C0 + 16768;       // C0 ends 5,161,344
  float* PP  = ws + 5161344;     // 4,194,304 (PV partials: 1024 slots x 4096)
  float* CSP = ws + 9355648;     //    32,768 — total 9,388,416 floats = 35.8 MiB
  float* ACC = (float*)d_out;

  k_xx1<<<64,256,0,stream>>>(X, XX);
  k_prep_wt<<<578,256,0,stream>>>(w1,w2,w3,w4,fw, W1T,W2T,W3T,W4T,FWT);
  k_knn1<<<4096,256,0,stream>>>(X, XX, IDX);
  k_ec1<<<16384,64,0,stream>>>(X, IDX, W1T, W2T, g1,b1,g2,b2_, X1T);
  k_xx2<<<64,256,0,stream>>>(X1T, XX);
  k_tr<<<256,256,0,stream>>>(X1T, H);                  // X1 -> channel-major (H ch 0..63), BEFORE knn2
  k_knn2<<<2048,256,0,stream>>>(H, XX, IDX);           // v3: 2 q/wave, shared loads, no slab staging
  k_ec2<<<16384,64,0,stream>>>(X1T, IDX, W3T, W4T, g3,b3,g4,b4, X2T);
  k_tr<<<256,256,0,stream>>>(X2T, H + 64*Nn);

  for (int l=0;l<4;++l){
    k_sa_a<<<512,256,0,stream>>>(H, qk + l*4096, sv + l*16384, svb + l*128, QXb, XVb);
    k_sa_b<<<512,256,0,stream>>>(QXb, RMP, RSP);
    k_sa_b2<<<64,256,0,stream>>>(RMP, RSP, RMX, RSM);
    k_sa_cm<<<1024,256,0,stream>>>(QXb, XVb, RMX, RSM, PP, CSP);
    k_sa_cc<<<512,256,0,stream>>>(H, PP, CSP,
                                  st + l*16384, stb + l*128, sg + l*128, sb + l*128, H);
    k_fuse_part<<<512,256,0,stream>>>(H, FWT, ACC, l, (l==0)?1:0, (l==3)?1:0, fg, fb);
  }
}

// Round 8
// 2577.186 us; speedup vs baseline: 1.1525x; 1.0177x over previous
//
#include <hip/hip_runtime.h>

#define Bb 8
#define Nn 2048
#define Kk 40
#define HS (128*Nn)   // h stride per batch (channel-major [b,128,2048])

// monotone float->uint transform: a > b  <=>  f2o(a) > f2o(b)
__device__ __forceinline__ unsigned f2o(float f){
  unsigned u = __float_as_uint(f);
  return (u & 0x80000000u) ? ~u : (u | 0x80000000u);
}

// Wave-cooperative exact top-40 of 2048, grouped rescan (4 groups of 8 slots).
// Lane owns m = slot*64+lane. Per round only the winner lane rescans its group;
// selection order identical to a full linear scan (value desc, index asc).
__device__ __forceinline__ void wave_top40(float* d, int lane, int* op){
  float gv[4]; int gs[4];
  #pragma unroll
  for (int g=0; g<4; ++g){
    float bv = d[g*8]; int bs = g*8;
    #pragma unroll
    for (int j=1;j<8;++j){
      float v = d[g*8+j];
      if (v > bv){ bv = v; bs = g*8+j; }
    }
    gv[g]=bv; gs[g]=bs;
  }
  for (int t=0; t<Kk; ++t){
    float bv = gv[0]; int bs = gs[0];
    if (gv[1] > bv){ bv=gv[1]; bs=gs[1]; }
    if (gv[2] > bv){ bv=gv[2]; bs=gs[2]; }
    if (gv[3] > bv){ bv=gv[3]; bs=gs[3]; }
    int bm = bs*64 + lane;
    unsigned long long key = ((unsigned long long)f2o(bv) << 32) | (unsigned)(~bm);
    #pragma unroll
    for (int s=32;s>0;s>>=1){
      unsigned long long o = __shfl_xor(key, s, 64);
      if (o > key) key = o;
    }
    int wm = (int)(~(unsigned)key);
    if (lane == 0) op[t] = wm;
    bool mine = ((wm & 63) == lane);
    int wsl = wm >> 6;
    if (mine){
      int G = wsl >> 3;
      #pragma unroll
      for (int g=0; g<4; ++g){
        if (g == G){
          float nv = -__builtin_inff(); int ns = g*8;
          #pragma unroll
          for (int j=0;j<8;++j){
            float v = d[g*8+j];
            if (g*8+j == wsl) v = -__builtin_inff();
            d[g*8+j] = v;
            if (v > nv){ nv=v; ns=g*8+j; }
          }
          gv[g]=nv; gs[g]=ns;
        }
      }
    }
  }
}

// Variant for mapping m = (s>>2)*256 + lane*4 + (s&3) (coalesced float4 ownership).
// Within a lane m is increasing in s, so the same grouped tie-break is exact.
__device__ __forceinline__ void wave_top40_g(float* d, int lane, int* op){
  float gv[4]; int gs[4];
  #pragma unroll
  for (int g=0; g<4; ++g){
    float bv = d[g*8]; int bs = g*8;
    #pragma unroll
    for (int j=1;j<8;++j){
      float v = d[g*8+j];
      if (v > bv){ bv = v; bs = g*8+j; }
    }
    gv[g]=bv; gs[g]=bs;
  }
  for (int t=0; t<Kk; ++t){
    float bv = gv[0]; int bs = gs[0];
    if (gv[1] > bv){ bv=gv[1]; bs=gs[1]; }
    if (gv[2] > bv){ bv=gv[2]; bs=gs[2]; }
    if (gv[3] > bv){ bv=gv[3]; bs=gs[3]; }
    int bm = ((bs>>2)<<8) + lane*4 + (bs&3);
    unsigned long long key = ((unsigned long long)f2o(bv) << 32) | (unsigned)(~bm);
    #pragma unroll
    for (int s=32;s>0;s>>=1){
      unsigned long long o = __shfl_xor(key, s, 64);
      if (o > key) key = o;
    }
    int wm = (int)(~(unsigned)key);
    if (lane == 0) op[t] = wm;
    bool mine = (((wm>>2) & 63) == lane);
    int wsl = ((wm>>8)<<2) | (wm & 3);
    if (mine){
      int G = wsl >> 3;
      #pragma unroll
      for (int g=0; g<4; ++g){
        if (g == G){
          float nv = -__builtin_inff(); int ns = g*8;
          #pragma unroll
          for (int j=0;j<8;++j){
            float v = d[g*8+j];
            if (g*8+j == wsl) v = -__builtin_inff();
            d[g*8+j] = v;
            if (v > nv){ nv=v; ns=g*8+j; }
          }
          gv[g]=nv; gs[g]=ns;
        }
      }
    }
  }
}

// ---------------- prep ----------------
__global__ __launch_bounds__(256) void k_xx1(const float* __restrict__ x, float* __restrict__ XX){
  int e = blockIdx.x*256 + threadIdx.x;
  if (e >= Bb*Nn) return;
  float p0 = x[e*3+0], p1 = x[e*3+1], p2 = x[e*3+2];
  XX[e] = __fadd_rn(__fadd_rn(__fmul_rn(p0,p0), __fmul_rn(p1,p1)), __fmul_rn(p2,p2));
}

__global__ __launch_bounds__(256) void k_prep_wt(const float* __restrict__ w1, const float* __restrict__ w2,
                                                 const float* __restrict__ w3, const float* __restrict__ w4,
                                                 const float* __restrict__ fw,
                                                 float* __restrict__ W1T, float* __restrict__ W2T,
                                                 float* __restrict__ W3T, float* __restrict__ W4T,
                                                 float* __restrict__ FWT){
  int e = blockIdx.x*256 + threadIdx.x;
  if (e < 384)   { int i=e/64,  c=e%64;  W1T[e] = w1[c*6+i];    return; } e -= 384;
  if (e < 4096)  { int i=e/64,  c=e%64;  W2T[e] = w2[c*64+i];   return; } e -= 4096;
  if (e < 8192)  { int i=e/64,  c=e%64;  W3T[e] = w3[c*128+i];  return; } e -= 8192;
  if (e < 4096)  { int i=e/64,  c=e%64;  W4T[e] = w4[c*64+i];   return; } e -= 4096;
  if (e < 131072){ int i=e/256, o=e%256; FWT[e] = fw[o*512+i];  return; }
}

// ---------------- knn on 3-D points: 1 wave / query, LDS-staged cloud ----------------
__global__ __launch_bounds__(256) void k_knn1(const float* __restrict__ P, const float* __restrict__ XX,
                                              int* __restrict__ IDX){
  int blk = blockIdx.x;
  int b = blk >> 9;
  int w = threadIdx.x >> 6, lane = threadIdx.x & 63;
  int n = (blk & 511)*4 + w;
  const float* Pb = P + b*Nn*3;
  const float* xb = XX + b*Nn;
  __shared__ float Pl[Nn*3];
  __shared__ float Xl[Nn];
  for (int e = threadIdx.x; e < Nn*3; e += 256) Pl[e] = Pb[e];
  for (int e = threadIdx.x; e < Nn; e += 256) Xl[e] = xb[e];
  __syncthreads();
  float c0 = Pl[n*3+0], c1 = Pl[n*3+1], c2 = Pl[n*3+2];
  float xn = Xl[n];
  float d[32];
  #pragma unroll
  for (int j=0;j<32;++j){
    int m = j*64 + lane;
    float a0 = Pl[m*3+0], a1 = Pl[m*3+1], a2 = Pl[m*3+2];
    float in_ = __fadd_rn(__fadd_rn(__fmul_rn(c0,a0), __fmul_rn(c1,a1)), __fmul_rn(c2,a2));
    d[j] = __fsub_rn(__fsub_rn(__fmul_rn(2.0f,in_), xn), Xl[m]);
  }
  wave_top40(d, lane, IDX + (b*Nn+n)*Kk);
}

// ---------------- edge conv 1+2 + maxpool (bit-exact _rn path) ----------------
__global__ __launch_bounds__(64) void k_ec1(const float* __restrict__ P, const int* __restrict__ IDX,
                                            const float* __restrict__ W1T, const float* __restrict__ W2T,
                                            const float* __restrict__ g1, const float* __restrict__ b1,
                                            const float* __restrict__ g2, const float* __restrict__ b2,
                                            float* __restrict__ X1T){
  int e = blockIdx.x;           // global point row 0..16383
  int b = e >> 11;
  int lane = threadIdx.x;
  __shared__ float dC[Kk*4];
  __shared__ __align__(16) float y1L[64*44];
  float c0 = P[e*3+0], c1 = P[e*3+1], c2 = P[e*3+2];
  if (lane < Kk) {
    int idx = IDX[e*Kk + lane] & (Nn-1);
    const float* pn = P + (b*Nn + idx)*3;
    dC[lane*4+0] = __fsub_rn(pn[0], c0);
    dC[lane*4+1] = __fsub_rn(pn[1], c1);
    dC[lane*4+2] = __fsub_rn(pn[2], c2);
  }
  __syncthreads();
  float w10 = W1T[0*64+lane], w11 = W1T[1*64+lane], w12 = W1T[2*64+lane];
  float w13 = W1T[3*64+lane], w14 = W1T[4*64+lane], w15 = W1T[5*64+lane];
  float p3 = __fmul_rn(w13,c0), p4 = __fmul_rn(w14,c1), p5 = __fmul_rn(w15,c2);
  float s1 = __fdiv_rn(g1[lane], __fsqrt_rn(1.0f + 1e-5f));
  float o1 = b1[lane];
  for (int k=0;k<Kk;++k){
    float t = __fmul_rn(w10, dC[k*4+0]);
    t = __fadd_rn(t, __fmul_rn(w11, dC[k*4+1]));
    t = __fadd_rn(t, __fmul_rn(w12, dC[k*4+2]));
    t = __fadd_rn(t, p3); t = __fadd_rn(t, p4); t = __fadd_rn(t, p5);
    float y = __fadd_rn(__fmul_rn(t, s1), o1);
    y = (y >= 0.0f) ? y : __fmul_rn(0.2f, y);
    y1L[lane*44+k] = y;
  }
  __syncthreads();
  float4 q[10];
  #pragma unroll
  for (int k4=0;k4<10;++k4) q[k4] = make_float4(0.f,0.f,0.f,0.f);
  for (int i=0;i<64;++i){
    float w = W2T[i*64+lane];
    const float4* yp = (const float4*)&y1L[i*44];
    #pragma unroll
    for (int k4=0;k4<10;++k4){
      float4 yv = yp[k4];
      q[k4].x = __fadd_rn(q[k4].x, __fmul_rn(w, yv.x));
      q[k4].y = __fadd_rn(q[k4].y, __fmul_rn(w, yv.y));
      q[k4].z = __fadd_rn(q[k4].z, __fmul_rn(w, yv.z));
      q[k4].w = __fadd_rn(q[k4].w, __fmul_rn(w, yv.w));
    }
  }
  float s2 = __fdiv_rn(g2[lane], __fsqrt_rn(1.0f + 1e-5f));
  float o2 = b2[lane];
  float mx = -__builtin_inff();
  #pragma unroll
  for (int k4=0;k4<10;++k4){
    float vs[4] = {q[k4].x, q[k4].y, q[k4].z, q[k4].w};
    #pragma unroll
    for (int j=0;j<4;++j){
      float y = __fadd_rn(__fmul_rn(vs[j], s2), o2);
      y = (y >= 0.0f) ? y : __fmul_rn(0.2f, y);
      mx = fmaxf(mx, y);
    }
  }
  X1T[e*64 + lane] = mx;
}

__global__ __launch_bounds__(256) void k_xx2(const float* __restrict__ X1T, float* __restrict__ XX2){
  int e = blockIdx.x*256 + threadIdx.x;
  const float* r = X1T + e*64;
  float a = 0.f;
  for (int c=0;c<64;++c) a = __fadd_rn(a, __fmul_rn(r[c], r[c]));
  XX2[e] = a;
}

// ---------------- knn on 64-D features ----------------
// v4: 4 queries/wave (16/block, grid 1024), direct-L2 float4 reads shared
// across all 4 queries (16 MACs/load vs v3's 8; L2 traffic 4.3GB -> 2.1GB).
// This is v2's register blocking WITHOUT the LDS slab staging/barriers that
// collapsed occupancy (v2: 11.8%, 602us). LDS = 4KB query features only.
// Per-query accumulation order (c = 0..63 ascending, _rn mul+add) and float4
// ownership (m = j*256 + lane*4 + comp) identical to v1/v3 -> wave_top40_g
// selection is bit-exact vs the passing kernel.
__global__ __launch_bounds__(256) void k_knn2(const float* __restrict__ X1C, const float* __restrict__ XX2,
                                              int* __restrict__ IDX){
  int blk = blockIdx.x;
  int b = blk >> 7;                 // 128 blocks per batch
  int n0 = (blk & 127) << 4;        // 16 queries per block
  int w = threadIdx.x >> 6, lane = threadIdx.x & 63;
  __shared__ __align__(16) float qL[64*16];   // [c][q] query features (4 KB)
  for (int e=threadIdx.x; e<1024; e+=256){
    int c = e >> 4, t = e & 15;
    qL[e] = X1C[b*HS + c*Nn + n0 + t];
  }
  __syncthreads();
  float4 acc[4][8];                 // 4 queries x 32 points/lane = 128 VGPR
  #pragma unroll
  for (int qi=0;qi<4;++qi){
    #pragma unroll
    for (int j=0;j<8;++j) acc[qi][j] = make_float4(0.f,0.f,0.f,0.f);
  }
#define KNN2_ACC(Q, QS) \
    acc[Q][j].x = __fadd_rn(acc[Q][j].x, __fmul_rn(QS, v.x)); \
    acc[Q][j].y = __fadd_rn(acc[Q][j].y, __fmul_rn(QS, v.y)); \
    acc[Q][j].z = __fadd_rn(acc[Q][j].z, __fmul_rn(QS, v.z)); \
    acc[Q][j].w = __fadd_rn(acc[Q][j].w, __fmul_rn(QS, v.w));
  for (int c=0;c<64;++c){
    const float4* row = (const float4*)(X1C + b*HS + c*Nn);
    float4 q = *(const float4*)&qL[c*16 + w*4];
    #pragma unroll
    for (int j=0;j<8;++j){
      float4 v = row[j*64 + lane];
      KNN2_ACC(0, q.x)
      KNN2_ACC(1, q.y)
      KNN2_ACC(2, q.z)
      KNN2_ACC(3, q.w)
    }
  }
#undef KNN2_ACC
  const float* xb = XX2 + b*Nn;
  const float4* xb4 = (const float4*)xb;
  #pragma unroll
  for (int qi=0;qi<4;++qi){
    int n = n0 + w*4 + qi;
    float xn = xb[n];
    float d[32];
    #pragma unroll
    for (int j=0;j<8;++j){
      float4 xm = xb4[j*64 + lane];
      d[j*4+0] = __fsub_rn(__fsub_rn(__fmul_rn(2.0f, acc[qi][j].x), xn), xm.x);
      d[j*4+1] = __fsub_rn(__fsub_rn(__fmul_rn(2.0f, acc[qi][j].y), xn), xm.y);
      d[j*4+2] = __fsub_rn(__fsub_rn(__fmul_rn(2.0f, acc[qi][j].z), xn), xm.z);
      d[j*4+3] = __fsub_rn(__fsub_rn(__fmul_rn(2.0f, acc[qi][j].w), xn), xm.w);
    }
    wave_top40_g(d, lane, IDX + (b*Nn + n)*Kk);
  }
}

// ---------------- edge conv 3+4 + maxpool (fma ok) ----------------
__global__ __launch_bounds__(64) void k_ec2(const float* __restrict__ X1T, const int* __restrict__ IDX,
                                            const float* __restrict__ W3T, const float* __restrict__ W4T,
                                            const float* __restrict__ g3, const float* __restrict__ b3,
                                            const float* __restrict__ g4, const float* __restrict__ b4,
                                            float* __restrict__ X2T){
  int e = blockIdx.x; int b = e >> 11; int lane = threadIdx.x;
  __shared__ __align__(16) float dL[64*44];
  __shared__ float ctrL[64];
  float ctr = X1T[e*64 + lane];
  ctrL[lane] = ctr;
  __syncthreads();
  for (int k=0;k<Kk;++k){
    int idx = IDX[e*Kk + k] & (Nn-1);
    dL[lane*44 + k] = X1T[(b*Nn+idx)*64 + lane] - ctr;
  }
  __syncthreads();
  float base = 0.f;
  for (int i=0;i<64;++i) base = fmaf(W3T[(64+i)*64 + lane], ctrL[i], base);
  float4 q[10];
  #pragma unroll
  for (int k4=0;k4<10;++k4) q[k4] = make_float4(base,base,base,base);
  for (int i=0;i<64;++i){
    float w = W3T[i*64 + lane];
    const float4* dp = (const float4*)&dL[i*44];
    #pragma unroll
    for (int k4=0;k4<10;++k4){
      float4 d = dp[k4];
      q[k4].x = fmaf(w, d.x, q[k4].x);
      q[k4].y = fmaf(w, d.y, q[k4].y);
      q[k4].z = fmaf(w, d.z, q[k4].z);
      q[k4].w = fmaf(w, d.w, q[k4].w);
    }
  }
  float s3 = g3[lane] / sqrtf(1.0f+1e-5f);
  float o3 = b3[lane];
  __syncthreads();
  #pragma unroll
  for (int k4=0;k4<10;++k4){
    float4 y;
    y.x = q[k4].x*s3 + o3; y.x = (y.x>=0.f)?y.x:0.2f*y.x;
    y.y = q[k4].y*s3 + o3; y.y = (y.y>=0.f)?y.y:0.2f*y.y;
    y.z = q[k4].z*s3 + o3; y.z = (y.z>=0.f)?y.z:0.2f*y.z;
    y.w = q[k4].w*s3 + o3; y.w = (y.w>=0.f)?y.w:0.2f*y.w;
    *(float4*)&dL[lane*44 + k4*4] = y;
  }
  __syncthreads();
  float4 p[10];
  #pragma unroll
  for (int k4=0;k4<10;++k4) p[k4] = make_float4(0.f,0.f,0.f,0.f);
  for (int i=0;i<64;++i){
    float w = W4T[i*64 + lane];
    const float4* yp = (const float4*)&dL[i*44];
    #pragma unroll
    for (int k4=0;k4<10;++k4){
      float4 yv = yp[k4];
      p[k4].x = fmaf(w, yv.x, p[k4].x);
      p[k4].y = fmaf(w, yv.y, p[k4].y);
      p[k4].z = fmaf(w, yv.z, p[k4].z);
      p[k4].w = fmaf(w, yv.w, p[k4].w);
    }
  }
  float s4 = g4[lane] / sqrtf(1.0f+1e-5f);
  float o4 = b4[lane];
  float mx = -__builtin_inff();
  #pragma unroll
  for (int k4=0;k4<10;++k4){
    float vs[4] = {p[k4].x, p[k4].y, p[k4].z, p[k4].w};
    #pragma unroll
    for (int j=0;j<4;++j){
      float y = vs[j]*s4 + o4;
      y = (y>=0.f)?y:0.2f*y;
      mx = fmaxf(mx, y);
    }
  }
  X2T[e*64 + lane] = mx;
}

// (b,n,64) -> (b,c,n); dst pre-offset by channel base; dst batch stride = HS
__global__ __launch_bounds__(256) void k_tr(const float* __restrict__ src, float* __restrict__ dst){
  int b = blockIdx.x >> 5; int n0 = (blockIdx.x & 31) << 6;
  __shared__ float t[64*65];
  for (int e=threadIdx.x; e<4096; e+=256){
    int r = e >> 6, c = e & 63;
    t[r*65+c] = src[(b*Nn + n0 + r)*64 + c];
  }
  __syncthreads();
  for (int e=threadIdx.x; e<4096; e+=256){
    int c = e >> 6, r = e & 63;
    dst[b*HS + c*Nn + n0 + r] = t[r*65+c];
  }
}

// ---------------- SA layer ----------------
// grid 512 = b(8) x nt(32) x part(2); unified rows: r<32 -> QX row r, else XV row r-32.
__global__ __launch_bounds__(256) void k_sa_a(const float* __restrict__ IN,
                                              const float* __restrict__ QKw, const float* __restrict__ Vw,
                                              const float* __restrict__ Vb,
                                              float* __restrict__ QX, float* __restrict__ XV){
  int blk = blockIdx.x;
  int part = blk & 1; int nt = (blk >> 1) & 31; int b = blk >> 6;
  int n0 = nt << 6;
  int w = threadIdx.x >> 6, lane = threadIdx.x & 63;
  __shared__ float xl[128*64];
  for (int e=threadIdx.x; e<8192; e+=256){
    int c = e >> 6, j = e & 63;
    xl[e] = IN[b*HS + c*Nn + n0 + j];
  }
  __syncthreads();
  for (int i=0;i<20;++i){
    int r = part*80 + w*20 + i;
    const float4* wp4;
    if (r < 32) wp4 = (const float4*)(QKw + r*128);
    else        wp4 = (const float4*)(Vw + (r-32)*128);
    float a = 0.f;
    #pragma unroll
    for (int c4=0;c4<32;++c4){
      float4 wv = wp4[c4];
      a = fmaf(wv.x, xl[(c4*4+0)*64 + lane], a);
      a = fmaf(wv.y, xl[(c4*4+1)*64 + lane], a);
      a = fmaf(wv.z, xl[(c4*4+2)*64 + lane], a);
      a = fmaf(wv.w, xl[(c4*4+3)*64 + lane], a);
    }
    if (r < 32) QX[(b*32+r)*Nn + n0 + lane] = a;
    else { int o = r-32; XV[(b*128+o)*Nn + n0 + lane] = a + Vb[o]; }
  }
}

// m-split x8: grid 512 = b(8) x nc(8) x mc(8)
// v2: qt read as broadcast float4 (4 m per inner iter, was 2 x b32/b64) --
// sa_b is LDS-issue-bound, this halves LDS wave-instructions. Bit-exact:
// same per-e fmaf order over o, same ascending-m online update sequence.
__global__ __launch_bounds__(256) void k_sa_b(const float* __restrict__ QX,
                                              float* __restrict__ RMP, float* __restrict__ RSP){
  int blk = blockIdx.x;
  int b = blk >> 6, sub = blk & 63;
  int ncn = sub >> 3, mcn = sub & 7;
  int n = ncn*256 + threadIdx.x;
  float q[32];
  #pragma unroll
  for (int o=0;o<32;++o) q[o] = QX[(b*32+o)*Nn + n];
  __shared__ __align__(16) float qt[32*128];
  float mr = -__builtin_inff(), lr = 0.f;
  int m0 = mcn*256;
  for (int t=0;t<2;++t){
    for (int e=threadIdx.x; e<4096; e+=256){
      int o = e >> 7, mm = e & 127;
      qt[e] = QX[(b*32+o)*Nn + m0 + t*128 + mm];
    }
    __syncthreads();
    for (int mm=0;mm<128;mm+=4){
      float e0=0.f, e1=0.f, e2=0.f, e3=0.f;
      #pragma unroll
      for (int o=0;o<32;++o){
        float qo=q[o];
        float4 qv = *(const float4*)&qt[o*128+mm];
        e0 = fmaf(qo, qv.x, e0);
        e1 = fmaf(qo, qv.y, e1);
        e2 = fmaf(qo, qv.z, e2);
        e3 = fmaf(qo, qv.w, e3);
      }
      if (e0 > mr){ lr = lr*expf(mr-e0) + 1.f; mr = e0; } else lr += expf(e0-mr);
      if (e1 > mr){ lr = lr*expf(mr-e1) + 1.f; mr = e1; } else lr += expf(e1-mr);
      if (e2 > mr){ lr = lr*expf(mr-e2) + 1.f; mr = e2; } else lr += expf(e2-mr);
      if (e3 > mr){ lr = lr*expf(mr-e3) + 1.f; mr = e3; } else lr += expf(e3-mr);
    }
    __syncthreads();
  }
  RMP[(b*Nn+n)*8 + mcn] = mr;
  RSP[(b*Nn+n)*8 + mcn] = lr;
}

__global__ __launch_bounds__(256) void k_sa_b2(const float* __restrict__ RMP, const float* __restrict__ RSP,
                                               float* __restrict__ RMX, float* __restrict__ RSM){
  int e = blockIdx.x*256 + threadIdx.x;
  float M = -__builtin_inff();
  #pragma unroll
  for (int i=0;i<8;++i) M = fmaxf(M, RMP[e*8+i]);
  float l = 0.f;
  #pragma unroll
  for (int i=0;i<8;++i) l += RSP[e*8+i]*expf(RMP[e*8+i]-M);
  RMX[e] = M; RSM[e] = l;
}

// LDS map (floats): QM[32o][32m]=1024 @0, QN[32o][32n]=1024 @1024,
// XVt[32n][132]=4224 @2048, SL[32n][32m]=1024 @6272, MX@7296, RL@7328.
#define SM_QM 0
#define SM_QN 1024
#define SM_XV 2048
#define SM_SL 6272
#define SM_MX 7296
#define SM_RL 7328

// main: grid 1024 = b(8) x mt(64) x part(2); n-range split in 2; writes PV and
// column-sum partials to PP/CSP.
__global__ __launch_bounds__(256) void k_sa_cm(const float* __restrict__ QX, const float* __restrict__ XV,
                                               const float* __restrict__ RMAX, const float* __restrict__ RSUM,
                                               float* __restrict__ PP, float* __restrict__ CSP){
  int blk = blockIdx.x;
  int part = blk & 1, mt = (blk >> 1) & 63, b = blk >> 7;
  int m0 = mt << 5;
  int tid = threadIdx.x;
  int nnp = tid >> 4, mmp = tid & 15;      // 2x2 S-microtile owner
  int tc = tid >> 3, tm8 = tid & 7;        // PV owner: c=tc*4+ci, m=tm8*4+mi
  __shared__ __align__(16) float sm[7360];
  for (int e=tid; e<1024; e+=256){
    int o = e >> 5, mm = e & 31;
    sm[SM_QM + e] = QX[(b*32+o)*Nn + m0 + mm];
  }
  float acc[4][4];
  #pragma unroll
  for (int ci=0;ci<4;++ci){
    #pragma unroll
    for (int mi=0;mi<4;++mi) acc[ci][mi] = 0.f;
  }
  float csr = 0.f;
  int it0 = part*32;
  for (int it=it0; it<it0+32; ++it){
    int nb = it*32;
    __syncthreads();
    for (int e=tid; e<1024; e+=256){ int o=e>>5, nn=e&31; sm[SM_QN+e] = QX[(b*32+o)*Nn + nb + nn]; }
    for (int e=tid; e<4096; e+=256){ int c=e>>5, nn=e&31; sm[SM_XV + nn*132 + c] = XV[(b*128+c)*Nn + nb + nn]; }
    if (tid < 32){ sm[SM_MX+tid] = RMAX[b*Nn + nb + tid]; sm[SM_RL+tid] = 1.0f / RSUM[b*Nn + nb + tid]; }
    __syncthreads();
    float e00=0.f, e01=0.f, e10=0.f, e11=0.f;
    #pragma unroll
    for (int o=0;o<32;++o){
      float2 qn = *(const float2*)&sm[SM_QN + o*32 + nnp*2];
      float2 qm = *(const float2*)&sm[SM_QM + o*32 + mmp*2];
      e00 = fmaf(qn.x, qm.x, e00);
      e01 = fmaf(qn.x, qm.y, e01);
      e10 = fmaf(qn.y, qm.x, e10);
      e11 = fmaf(qn.y, qm.y, e11);
    }
    float mx0 = sm[SM_MX + nnp*2],   rl0 = sm[SM_RL + nnp*2];
    float mx1 = sm[SM_MX + nnp*2+1], rl1 = sm[SM_RL + nnp*2+1];
    float2 s0; s0.x = expf(e00-mx0)*rl0; s0.y = expf(e01-mx0)*rl0;
    float2 s1; s1.x = expf(e10-mx1)*rl1; s1.y = expf(e11-mx1)*rl1;
    *(float2*)&sm[SM_SL + (nnp*2  )*32 + mmp*2] = s0;
    *(float2*)&sm[SM_SL + (nnp*2+1)*32 + mmp*2] = s1;
    __syncthreads();
    if (tid < 32){
      #pragma unroll
      for (int nn=0;nn<32;++nn) csr += sm[SM_SL + nn*32 + tid];
    }
    #pragma unroll 8
    for (int nn=0;nn<32;++nn){
      float4 xv4 = *(const float4*)&sm[SM_XV + nn*132 + tc*4];
      float4 s4  = *(const float4*)&sm[SM_SL + nn*32  + tm8*4];
      acc[0][0] = fmaf(xv4.x, s4.x, acc[0][0]);
      acc[0][1] = fmaf(xv4.x, s4.y, acc[0][1]);
      acc[0][2] = fmaf(xv4.x, s4.z, acc[0][2]);
      acc[0][3] = fmaf(xv4.x, s4.w, acc[0][3]);
      acc[1][0] = fmaf(xv4.y, s4.x, acc[1][0]);
      acc[1][1] = fmaf(xv4.y, s4.y, acc[1][1]);
      acc[1][2] = fmaf(xv4.y, s4.z, acc[1][2]);
      acc[1][3] = fmaf(xv4.y, s4.w, acc[1][3]);
      acc[2][0] = fmaf(xv4.z, s4.x, acc[2][0]);
      acc[2][1] = fmaf(xv4.z, s4.y, acc[2][1]);
      acc[2][2] = fmaf(xv4.z, s4.z, acc[2][2]);
      acc[2][3] = fmaf(xv4.z, s4.w, acc[2][3]);
      acc[3][0] = fmaf(xv4.w, s4.x, acc[3][0]);
      acc[3][1] = fmaf(xv4.w, s4.y, acc[3][1]);
      acc[3][2] = fmaf(xv4.w, s4.z, acc[3][2]);
      acc[3][3] = fmaf(xv4.w, s4.w, acc[3][3]);
    }
  }
  int slot = (b*64 + mt)*2 + part;
  #pragma unroll
  for (int ci=0;ci<4;++ci){
    int c = tc*4 + ci;
    *(float4*)&PP[slot*4096 + c*32 + tm8*4] =
      make_float4(acc[ci][0], acc[ci][1], acc[ci][2], acc[ci][3]);
  }
  if (tid < 32) CSP[slot*32 + tid] = csr;
}

// combine + transform epilogue: grid 512 = b(8) x mt(64). In-place on h.
__global__ __launch_bounds__(256) void k_sa_cc(const float* IN,
                                               const float* __restrict__ PP, const float* __restrict__ CSP,
                                               const float* __restrict__ Tw, const float* __restrict__ Tb,
                                               const float* __restrict__ Gs, const float* __restrict__ Bs,
                                               float* OUT){
  int blk = blockIdx.x;
  int mt = blk & 63, b = blk >> 6;
  int m0 = mt << 5;
  int tid = threadIdx.x;
  int tc = tid >> 3, tm8 = tid & 7;
  __shared__ __align__(16) float sm[4128];   // DL[128][32] @0, CS[32] @4096
  int s0 = (b*64 + mt)*2, s1 = s0 + 1;
  if (tid < 32) sm[4096 + tid] = CSP[s0*32 + tid] + CSP[s1*32 + tid];
  __syncthreads();
  #pragma unroll
  for (int ci=0;ci<4;++ci){
    int c = tc*4 + ci;
    float4 p0 = *(const float4*)&PP[s0*4096 + c*32 + tm8*4];
    float4 p1 = *(const float4*)&PP[s1*4096 + c*32 + tm8*4];
    float am[4] = {p0.x+p1.x, p0.y+p1.y, p0.z+p1.z, p0.w+p1.w};
    #pragma unroll
    for (int mi=0;mi<4;++mi){
      int ml = tm8*4 + mi;
      float cs = sm[4096 + ml];
      float xr = am[mi] / (1e-9f + cs);
      sm[c*32 + ml] = IN[b*HS + c*Nn + m0 + ml] - xr;
    }
  }
  __syncthreads();
  int hw = tid >> 5, m = tid & 31;
  float sroot = sqrtf(1.0f + 1e-5f);
  for (int oo=0; oo<16; ++oo){
    int o = oo*8 + hw;
    const float4* twp = (const float4*)(Tw + o*128);
    float a = 0.f;
    #pragma unroll
    for (int c4=0;c4<32;++c4){
      float4 wv = twp[c4];
      a = fmaf(wv.x, sm[(c4*4+0)*32 + m], a);
      a = fmaf(wv.y, sm[(c4*4+1)*32 + m], a);
      a = fmaf(wv.z, sm[(c4*4+2)*32 + m], a);
      a = fmaf(wv.w, sm[(c4*4+3)*32 + m], a);
    }
    a += Tb[o];
    float y = a * (Gs[o] / sroot) + Bs[o];
    y = fmaxf(y, 0.f);
    OUT[b*HS + o*Nn + m0 + m] = IN[b*HS + o*Nn + m0 + m] + y;
  }
}

// ---------------- progressive fuse: ACC += FW[:, l*128:(l+1)*128] * h_l ----------------
// grid 512 = b(8) x nt(32) x half(2); wave w covers o = hf*128 + w*32 + [0,32).
// fin: apply final BN + leaky-ReLU on the last layer's write (replaces k_fin).
__global__ __launch_bounds__(256) void k_fuse_part(const float* __restrict__ Hc, const float* __restrict__ FWT,
                                                   float* __restrict__ ACC, int l, int init, int fin,
                                                   const float* __restrict__ FGF, const float* __restrict__ FBF){
  int blk = blockIdx.x;
  int hf = blk & 1; int nt = (blk >> 1) & 31; int b = blk >> 6;
  int n0 = nt << 6;
  int w = threadIdx.x >> 6, lane = threadIdx.x & 63;
  __shared__ float xt[128*64];
  for (int e=threadIdx.x; e<8192; e+=256){
    int c = e >> 6, j = e & 63;
    xt[e] = Hc[(b*128 + c)*Nn + n0 + j];
  }
  __syncthreads();
  float4 a[8];
  #pragma unroll
  for (int j=0;j<8;++j) a[j] = make_float4(0.f,0.f,0.f,0.f);
  int ob = hf*128 + w*32;
  for (int c=0;c<128;++c){
    float xv = xt[c*64 + lane];
    const float4* wr = (const float4*)(FWT + (l*128+c)*256 + ob);
    #pragma unroll
    for (int j4=0;j4<8;++j4){
      float4 wv = wr[j4];
      a[j4].x = fmaf(wv.x, xv, a[j4].x);
      a[j4].y = fmaf(wv.y, xv, a[j4].y);
      a[j4].z = fmaf(wv.z, xv, a[j4].z);
      a[j4].w = fmaf(wv.w, xv, a[j4].w);
    }
  }
  float sroot = sqrtf(1.0f + 1e-5f);
  #pragma unroll
  for (int j4=0;j4<8;++j4){
    float vs[4] = {a[j4].x, a[j4].y, a[j4].z, a[j4].w};
    #pragma unroll
    for (int qq=0;qq<4;++qq){
      int o = ob + j4*4 + qq;
      int idx = (b*256 + o)*Nn + n0 + lane;
      float v = init ? vs[qq] : (ACC[idx] + vs[qq]);
      if (fin){
        float y = v * (FGF[o] / sroot) + FBF[o];
        y = (y >= 0.f) ? y : 0.2f*y;
        ACC[idx] = y;
      } else {
        ACC[idx] = v;
      }
    }
  }
}

extern "C" void kernel_launch(void* const* d_in, const int* in_sizes, int n_in,
                              void* d_out, int out_size, void* d_ws, size_t ws_size,
                              hipStream_t stream) {
  const float* X   = (const float*)d_in[0];
  const float* w1  = (const float*)d_in[1];
  const float* g1  = (const float*)d_in[2];
  const float* b1  = (const float*)d_in[3];
  const float* w2  = (const float*)d_in[4];
  const float* g2  = (const float*)d_in[5];
  const float* b2_ = (const float*)d_in[6];
  const float* w3  = (const float*)d_in[7];
  const float* g3  = (const float*)d_in[8];
  const float* b3  = (const float*)d_in[9];
  const float* w4  = (const float*)d_in[10];
  const float* g4  = (const float*)d_in[11];
  const float* b4  = (const float*)d_in[12];
  // d_in[13..15] = w5/g5/b5 : unused by reference
  const float* qk  = (const float*)d_in[16];
  const float* sv  = (const float*)d_in[17];
  const float* svb = (const float*)d_in[18];
  const float* st  = (const float*)d_in[19];
  const float* stb = (const float*)d_in[20];
  const float* sg  = (const float*)d_in[21];
  const float* sb  = (const float*)d_in[22];
  const float* fw  = (const float*)d_in[23];
  const float* fg  = (const float*)d_in[24];
  const float* fb  = (const float*)d_in[25];

  float* ws = (float*)d_ws;
  float* H    = ws + 0;          // 2,097,152
  float* QXb  = ws + 2097152;    //   524,288
  float* XVb  = ws + 2621440;    // 2,097,152 (ends 4,718,592)
  float* RMP  = ws + 4718592;    //   131,072
  float* RSP  = ws + 4849664;    //   131,072
  float* RMX  = ws + 4980736;    //    16,384
  float* RSM  = ws + 4997120;    //    16,384 (ends 5,013,504)
  // phase-1 overlay on [2,097,152 .. 4,915,200) — dead before SA phase:
  float* XX   = ws + 2146304;
  int*   IDX  = (int*)(ws + 2162688);
  float* X1T  = ws + 2818048;
  float* X2T  = ws + 3866624;    // ends 4,915,200
  float* C0   = ws + 5013504;
  float* W1T = C0 + 0;
  float* W2T = C0 + 384;
  float* W3T = C0 + 4480;
  float* W4T = C0 + 12672;
  float* FWT = C0 + 16768;       // C0 ends 5,161,344
  float* PP  = ws + 5161344;     // 4,194,304 (PV partials: 1024 slots x 4096)
  float* CSP = ws + 9355648;     //    32,768 — total 9,388,416 floats = 35.8 MiB
  float* ACC = (float*)d_out;

  k_xx1<<<64,256,0,stream>>>(X, XX);
  k_prep_wt<<<578,256,0,stream>>>(w1,w2,w3,w4,fw, W1T,W2T,W3T,W4T,FWT);
  k_knn1<<<4096,256,0,stream>>>(X, XX, IDX);
  k_ec1<<<16384,64,0,stream>>>(X, IDX, W1T, W2T, g1,b1,g2,b2_, X1T);
  k_xx2<<<64,256,0,stream>>>(X1T, XX);
  k_tr<<<256,256,0,stream>>>(X1T, H);                  // X1 -> channel-major (H ch 0..63), BEFORE knn2
  k_knn2<<<1024,256,0,stream>>>(H, XX, IDX);           // v4: 4 q/wave, shared direct-L2 loads
  k_ec2<<<16384,64,0,stream>>>(X1T, IDX, W3T, W4T, g3,b3,g4,b4, X2T);
  k_tr<<<256,256,0,stream>>>(X2T, H + 64*Nn);

  for (int l=0;l<4;++l){
    k_sa_a<<<512,256,0,stream>>>(H, qk + l*4096, sv + l*16384, svb + l*128, QXb, XVb);
    k_sa_b<<<512,256,0,stream>>>(QXb, RMP, RSP);
    k_sa_b2<<<64,256,0,stream>>>(RMP, RSP, RMX, RSM);
    k_sa_cm<<<1024,256,0,stream>>>(QXb, XVb, RMX, RSM, PP, CSP);
    k_sa_cc<<<512,256,0,stream>>>(H, PP, CSP,
                                  st + l*16384, stb + l*128, sg + l*128, sb + l*128, H);
    k_fuse_part<<<512,256,0,stream>>>(H, FWT, ACC, l, (l==0)?1:0, (l==3)?1:0, fg, fb);
  }
}

// Round 9
// 2540.918 us; speedup vs baseline: 1.1689x; 1.0143x over previous
//
#include <hip/hip_runtime.h>

#define Bb 8
#define Nn 2048
#define Kk 40
#define HS (128*Nn)   // h stride per batch (channel-major [b,128,2048])

// monotone float->uint transform: a > b  <=>  f2o(a) > f2o(b)
__device__ __forceinline__ unsigned f2o(float f){
  unsigned u = __float_as_uint(f);
  return (u & 0x80000000u) ? ~u : (u | 0x80000000u);
}

// Wave-cooperative exact top-40 of 2048, grouped rescan (4 groups of 8 slots).
// Lane owns m = slot*64+lane. Per round only the winner lane rescans its group;
// selection order identical to a full linear scan (value desc, index asc).
__device__ __forceinline__ void wave_top40(float* d, int lane, int* op){
  float gv[4]; int gs[4];
  #pragma unroll
  for (int g=0; g<4; ++g){
    float bv = d[g*8]; int bs = g*8;
    #pragma unroll
    for (int j=1;j<8;++j){
      float v = d[g*8+j];
      if (v > bv){ bv = v; bs = g*8+j; }
    }
    gv[g]=bv; gs[g]=bs;
  }
  for (int t=0; t<Kk; ++t){
    float bv = gv[0]; int bs = gs[0];
    if (gv[1] > bv){ bv=gv[1]; bs=gs[1]; }
    if (gv[2] > bv){ bv=gv[2]; bs=gs[2]; }
    if (gv[3] > bv){ bv=gv[3]; bs=gs[3]; }
    int bm = bs*64 + lane;
    unsigned long long key = ((unsigned long long)f2o(bv) << 32) | (unsigned)(~bm);
    #pragma unroll
    for (int s=32;s>0;s>>=1){
      unsigned long long o = __shfl_xor(key, s, 64);
      if (o > key) key = o;
    }
    int wm = (int)(~(unsigned)key);
    if (lane == 0) op[t] = wm;
    bool mine = ((wm & 63) == lane);
    int wsl = wm >> 6;
    if (mine){
      int G = wsl >> 3;
      #pragma unroll
      for (int g=0; g<4; ++g){
        if (g == G){
          float nv = -__builtin_inff(); int ns = g*8;
          #pragma unroll
          for (int j=0;j<8;++j){
            float v = d[g*8+j];
            if (g*8+j == wsl) v = -__builtin_inff();
            d[g*8+j] = v;
            if (v > nv){ nv=v; ns=g*8+j; }
          }
          gv[g]=nv; gs[g]=ns;
        }
      }
    }
  }
}

// Variant for mapping m = (s>>2)*256 + lane*4 + (s&3) (coalesced float4 ownership).
// Within a lane m is increasing in s, so the same grouped tie-break is exact.
__device__ __forceinline__ void wave_top40_g(float* d, int lane, int* op){
  float gv[4]; int gs[4];
  #pragma unroll
  for (int g=0; g<4; ++g){
    float bv = d[g*8]; int bs = g*8;
    #pragma unroll
    for (int j=1;j<8;++j){
      float v = d[g*8+j];
      if (v > bv){ bv = v; bs = g*8+j; }
    }
    gv[g]=bv; gs[g]=bs;
  }
  for (int t=0; t<Kk; ++t){
    float bv = gv[0]; int bs = gs[0];
    if (gv[1] > bv){ bv=gv[1]; bs=gs[1]; }
    if (gv[2] > bv){ bv=gv[2]; bs=gs[2]; }
    if (gv[3] > bv){ bv=gv[3]; bs=gs[3]; }
    int bm = ((bs>>2)<<8) + lane*4 + (bs&3);
    unsigned long long key = ((unsigned long long)f2o(bv) << 32) | (unsigned)(~bm);
    #pragma unroll
    for (int s=32;s>0;s>>=1){
      unsigned long long o = __shfl_xor(key, s, 64);
      if (o > key) key = o;
    }
    int wm = (int)(~(unsigned)key);
    if (lane == 0) op[t] = wm;
    bool mine = (((wm>>2) & 63) == lane);
    int wsl = ((wm>>8)<<2) | (wm & 3);
    if (mine){
      int G = wsl >> 3;
      #pragma unroll
      for (int g=0; g<4; ++g){
        if (g == G){
          float nv = -__builtin_inff(); int ns = g*8;
          #pragma unroll
          for (int j=0;j<8;++j){
            float v = d[g*8+j];
            if (g*8+j == wsl) v = -__builtin_inff();
            d[g*8+j] = v;
            if (v > nv){ nv=v; ns=g*8+j; }
          }
          gv[g]=nv; gs[g]=ns;
        }
      }
    }
  }
}

// ---------------- prep ----------------
__global__ __launch_bounds__(256) void k_xx1(const float* __restrict__ x, float* __restrict__ XX){
  int e = blockIdx.x*256 + threadIdx.x;
  if (e >= Bb*Nn) return;
  float p0 = x[e*3+0], p1 = x[e*3+1], p2 = x[e*3+2];
  XX[e] = __fadd_rn(__fadd_rn(__fmul_rn(p0,p0), __fmul_rn(p1,p1)), __fmul_rn(p2,p2));
}

__global__ __launch_bounds__(256) void k_prep_wt(const float* __restrict__ w1, const float* __restrict__ w2,
                                                 const float* __restrict__ w3, const float* __restrict__ w4,
                                                 const float* __restrict__ fw,
                                                 float* __restrict__ W1T, float* __restrict__ W2T,
                                                 float* __restrict__ W3T, float* __restrict__ W4T,
                                                 float* __restrict__ FWT){
  int e = blockIdx.x*256 + threadIdx.x;
  if (e < 384)   { int i=e/64,  c=e%64;  W1T[e] = w1[c*6+i];    return; } e -= 384;
  if (e < 4096)  { int i=e/64,  c=e%64;  W2T[e] = w2[c*64+i];   return; } e -= 4096;
  if (e < 8192)  { int i=e/64,  c=e%64;  W3T[e] = w3[c*128+i];  return; } e -= 8192;
  if (e < 4096)  { int i=e/64,  c=e%64;  W4T[e] = w4[c*64+i];   return; } e -= 4096;
  if (e < 131072){ int i=e/256, o=e%256; FWT[e] = fw[o*512+i];  return; }
}

// ---------------- knn on 3-D points: 1 wave / query, LDS-staged cloud ----------------
__global__ __launch_bounds__(256) void k_knn1(const float* __restrict__ P, const float* __restrict__ XX,
                                              int* __restrict__ IDX){
  int blk = blockIdx.x;
  int b = blk >> 9;
  int w = threadIdx.x >> 6, lane = threadIdx.x & 63;
  int n = (blk & 511)*4 + w;
  const float* Pb = P + b*Nn*3;
  const float* xb = XX + b*Nn;
  __shared__ float Pl[Nn*3];
  __shared__ float Xl[Nn];
  for (int e = threadIdx.x; e < Nn*3; e += 256) Pl[e] = Pb[e];
  for (int e = threadIdx.x; e < Nn; e += 256) Xl[e] = xb[e];
  __syncthreads();
  float c0 = Pl[n*3+0], c1 = Pl[n*3+1], c2 = Pl[n*3+2];
  float xn = Xl[n];
  float d[32];
  #pragma unroll
  for (int j=0;j<32;++j){
    int m = j*64 + lane;
    float a0 = Pl[m*3+0], a1 = Pl[m*3+1], a2 = Pl[m*3+2];
    float in_ = __fadd_rn(__fadd_rn(__fmul_rn(c0,a0), __fmul_rn(c1,a1)), __fmul_rn(c2,a2));
    d[j] = __fsub_rn(__fsub_rn(__fmul_rn(2.0f,in_), xn), Xl[m]);
  }
  wave_top40(d, lane, IDX + (b*Nn+n)*Kk);
}

// ---------------- edge conv 1+2 + maxpool (bit-exact _rn path) ----------------
__global__ __launch_bounds__(64) void k_ec1(const float* __restrict__ P, const int* __restrict__ IDX,
                                            const float* __restrict__ W1T, const float* __restrict__ W2T,
                                            const float* __restrict__ g1, const float* __restrict__ b1,
                                            const float* __restrict__ g2, const float* __restrict__ b2,
                                            float* __restrict__ X1T){
  int e = blockIdx.x;           // global point row 0..16383
  int b = e >> 11;
  int lane = threadIdx.x;
  __shared__ float dC[Kk*4];
  __shared__ __align__(16) float y1L[64*44];
  float c0 = P[e*3+0], c1 = P[e*3+1], c2 = P[e*3+2];
  if (lane < Kk) {
    int idx = IDX[e*Kk + lane] & (Nn-1);
    const float* pn = P + (b*Nn + idx)*3;
    dC[lane*4+0] = __fsub_rn(pn[0], c0);
    dC[lane*4+1] = __fsub_rn(pn[1], c1);
    dC[lane*4+2] = __fsub_rn(pn[2], c2);
  }
  __syncthreads();
  float w10 = W1T[0*64+lane], w11 = W1T[1*64+lane], w12 = W1T[2*64+lane];
  float w13 = W1T[3*64+lane], w14 = W1T[4*64+lane], w15 = W1T[5*64+lane];
  float p3 = __fmul_rn(w13,c0), p4 = __fmul_rn(w14,c1), p5 = __fmul_rn(w15,c2);
  float s1 = __fdiv_rn(g1[lane], __fsqrt_rn(1.0f + 1e-5f));
  float o1 = b1[lane];
  for (int k=0;k<Kk;++k){
    float t = __fmul_rn(w10, dC[k*4+0]);
    t = __fadd_rn(t, __fmul_rn(w11, dC[k*4+1]));
    t = __fadd_rn(t, __fmul_rn(w12, dC[k*4+2]));
    t = __fadd_rn(t, p3); t = __fadd_rn(t, p4); t = __fadd_rn(t, p5);
    float y = __fadd_rn(__fmul_rn(t, s1), o1);
    y = (y >= 0.0f) ? y : __fmul_rn(0.2f, y);
    y1L[lane*44+k] = y;
  }
  __syncthreads();
  float4 q[10];
  #pragma unroll
  for (int k4=0;k4<10;++k4) q[k4] = make_float4(0.f,0.f,0.f,0.f);
  for (int i=0;i<64;++i){
    float w = W2T[i*64+lane];
    const float4* yp = (const float4*)&y1L[i*44];
    #pragma unroll
    for (int k4=0;k4<10;++k4){
      float4 yv = yp[k4];
      q[k4].x = __fadd_rn(q[k4].x, __fmul_rn(w, yv.x));
      q[k4].y = __fadd_rn(q[k4].y, __fmul_rn(w, yv.y));
      q[k4].z = __fadd_rn(q[k4].z, __fmul_rn(w, yv.z));
      q[k4].w = __fadd_rn(q[k4].w, __fmul_rn(w, yv.w));
    }
  }
  float s2 = __fdiv_rn(g2[lane], __fsqrt_rn(1.0f + 1e-5f));
  float o2 = b2[lane];
  float mx = -__builtin_inff();
  #pragma unroll
  for (int k4=0;k4<10;++k4){
    float vs[4] = {q[k4].x, q[k4].y, q[k4].z, q[k4].w};
    #pragma unroll
    for (int j=0;j<4;++j){
      float y = __fadd_rn(__fmul_rn(vs[j], s2), o2);
      y = (y >= 0.0f) ? y : __fmul_rn(0.2f, y);
      mx = fmaxf(mx, y);
    }
  }
  X1T[e*64 + lane] = mx;
}

__global__ __launch_bounds__(256) void k_xx2(const float* __restrict__ X1T, float* __restrict__ XX2){
  int e = blockIdx.x*256 + threadIdx.x;
  const float* r = X1T + e*64;
  float a = 0.f;
  for (int c=0;c<64;++c) a = __fadd_rn(a, __fmul_rn(r[c], r[c]));
  XX2[e] = a;
}

// ---------------- knn on 64-D features ----------------
// v3 (verified 262us @ R6): 2 queries/wave (8/block, grid 2048), direct-L2
// float4 reads shared across both queries. v4 (4 q/wave, grid 1024) REGRESSED
// to 295us: occupancy 39->22%, VALUBusy 61->48% -- grid 2048 / 2q-per-wave is
// the traffic-vs-TLP sweet spot for this kernel. LDS = 2KB query features.
// Per-query accumulation order (c = 0..63 ascending, _rn mul+add) and float4
// ownership (m = j*256 + lane*4 + comp) identical to v1 -> wave_top40_g
// selection is bit-exact vs the passing kernel.
__global__ __launch_bounds__(256) void k_knn2(const float* __restrict__ X1C, const float* __restrict__ XX2,
                                              int* __restrict__ IDX){
  int blk = blockIdx.x;
  int b = blk >> 8;                 // 256 blocks per batch
  int n0 = (blk & 255) << 3;        // 8 queries per block
  int w = threadIdx.x >> 6, lane = threadIdx.x & 63;
  __shared__ float qL[8*64];        // [q][c] query features (2 KB)
  for (int e=threadIdx.x; e<512; e+=256){
    int q = e >> 6, c = e & 63;
    qL[e] = X1C[b*HS + c*Nn + n0 + q];
  }
  __syncthreads();
  float4 a0[8], a1[8];
  #pragma unroll
  for (int j=0;j<8;++j){
    a0[j] = make_float4(0.f,0.f,0.f,0.f);
    a1[j] = make_float4(0.f,0.f,0.f,0.f);
  }
  for (int c=0;c<64;++c){
    const float4* row = (const float4*)(X1C + b*HS + c*Nn);
    float q0 = qL[(w*2+0)*64 + c];
    float q1 = qL[(w*2+1)*64 + c];
    #pragma unroll
    for (int j=0;j<8;++j){
      float4 v = row[j*64 + lane];
      a0[j].x = __fadd_rn(a0[j].x, __fmul_rn(q0, v.x));
      a0[j].y = __fadd_rn(a0[j].y, __fmul_rn(q0, v.y));
      a0[j].z = __fadd_rn(a0[j].z, __fmul_rn(q0, v.z));
      a0[j].w = __fadd_rn(a0[j].w, __fmul_rn(q0, v.w));
      a1[j].x = __fadd_rn(a1[j].x, __fmul_rn(q1, v.x));
      a1[j].y = __fadd_rn(a1[j].y, __fmul_rn(q1, v.y));
      a1[j].z = __fadd_rn(a1[j].z, __fmul_rn(q1, v.z));
      a1[j].w = __fadd_rn(a1[j].w, __fmul_rn(q1, v.w));
    }
  }
  const float* xb = XX2 + b*Nn;
  const float4* xb4 = (const float4*)xb;
  {
    int n = n0 + w*2 + 0;
    float xn = xb[n];
    float d[32];
    #pragma unroll
    for (int j=0;j<8;++j){
      float4 xm = xb4[j*64 + lane];
      d[j*4+0] = __fsub_rn(__fsub_rn(__fmul_rn(2.0f, a0[j].x), xn), xm.x);
      d[j*4+1] = __fsub_rn(__fsub_rn(__fmul_rn(2.0f, a0[j].y), xn), xm.y);
      d[j*4+2] = __fsub_rn(__fsub_rn(__fmul_rn(2.0f, a0[j].z), xn), xm.z);
      d[j*4+3] = __fsub_rn(__fsub_rn(__fmul_rn(2.0f, a0[j].w), xn), xm.w);
    }
    wave_top40_g(d, lane, IDX + (b*Nn + n)*Kk);
  }
  {
    int n = n0 + w*2 + 1;
    float xn = xb[n];
    float d[32];
    #pragma unroll
    for (int j=0;j<8;++j){
      float4 xm = xb4[j*64 + lane];
      d[j*4+0] = __fsub_rn(__fsub_rn(__fmul_rn(2.0f, a1[j].x), xn), xm.x);
      d[j*4+1] = __fsub_rn(__fsub_rn(__fmul_rn(2.0f, a1[j].y), xn), xm.y);
      d[j*4+2] = __fsub_rn(__fsub_rn(__fmul_rn(2.0f, a1[j].z), xn), xm.z);
      d[j*4+3] = __fsub_rn(__fsub_rn(__fmul_rn(2.0f, a1[j].w), xn), xm.w);
    }
    wave_top40_g(d, lane, IDX + (b*Nn + n)*Kk);
  }
}

// ---------------- edge conv 3+4 + maxpool (fma ok) ----------------
__global__ __launch_bounds__(64) void k_ec2(const float* __restrict__ X1T, const int* __restrict__ IDX,
                                            const float* __restrict__ W3T, const float* __restrict__ W4T,
                                            const float* __restrict__ g3, const float* __restrict__ b3,
                                            const float* __restrict__ g4, const float* __restrict__ b4,
                                            float* __restrict__ X2T){
  int e = blockIdx.x; int b = e >> 11; int lane = threadIdx.x;
  __shared__ __align__(16) float dL[64*44];
  __shared__ float ctrL[64];
  float ctr = X1T[e*64 + lane];
  ctrL[lane] = ctr;
  __syncthreads();
  for (int k=0;k<Kk;++k){
    int idx = IDX[e*Kk + k] & (Nn-1);
    dL[lane*44 + k] = X1T[(b*Nn+idx)*64 + lane] - ctr;
  }
  __syncthreads();
  float base = 0.f;
  for (int i=0;i<64;++i) base = fmaf(W3T[(64+i)*64 + lane], ctrL[i], base);
  float4 q[10];
  #pragma unroll
  for (int k4=0;k4<10;++k4) q[k4] = make_float4(base,base,base,base);
  for (int i=0;i<64;++i){
    float w = W3T[i*64 + lane];
    const float4* dp = (const float4*)&dL[i*44];
    #pragma unroll
    for (int k4=0;k4<10;++k4){
      float4 d = dp[k4];
      q[k4].x = fmaf(w, d.x, q[k4].x);
      q[k4].y = fmaf(w, d.y, q[k4].y);
      q[k4].z = fmaf(w, d.z, q[k4].z);
      q[k4].w = fmaf(w, d.w, q[k4].w);
    }
  }
  float s3 = g3[lane] / sqrtf(1.0f+1e-5f);
  float o3 = b3[lane];
  __syncthreads();
  #pragma unroll
  for (int k4=0;k4<10;++k4){
    float4 y;
    y.x = q[k4].x*s3 + o3; y.x = (y.x>=0.f)?y.x:0.2f*y.x;
    y.y = q[k4].y*s3 + o3; y.y = (y.y>=0.f)?y.y:0.2f*y.y;
    y.z = q[k4].z*s3 + o3; y.z = (y.z>=0.f)?y.z:0.2f*y.z;
    y.w = q[k4].w*s3 + o3; y.w = (y.w>=0.f)?y.w:0.2f*y.w;
    *(float4*)&dL[lane*44 + k4*4] = y;
  }
  __syncthreads();
  float4 p[10];
  #pragma unroll
  for (int k4=0;k4<10;++k4) p[k4] = make_float4(0.f,0.f,0.f,0.f);
  for (int i=0;i<64;++i){
    float w = W4T[i*64 + lane];
    const float4* yp = (const float4*)&dL[i*44];
    #pragma unroll
    for (int k4=0;k4<10;++k4){
      float4 yv = yp[k4];
      p[k4].x = fmaf(w, yv.x, p[k4].x);
      p[k4].y = fmaf(w, yv.y, p[k4].y);
      p[k4].z = fmaf(w, yv.z, p[k4].z);
      p[k4].w = fmaf(w, yv.w, p[k4].w);
    }
  }
  float s4 = g4[lane] / sqrtf(1.0f+1e-5f);
  float o4 = b4[lane];
  float mx = -__builtin_inff();
  #pragma unroll
  for (int k4=0;k4<10;++k4){
    float vs[4] = {p[k4].x, p[k4].y, p[k4].z, p[k4].w};
    #pragma unroll
    for (int j=0;j<4;++j){
      float y = vs[j]*s4 + o4;
      y = (y>=0.f)?y:0.2f*y;
      mx = fmaxf(mx, y);
    }
  }
  X2T[e*64 + lane] = mx;
}

// (b,n,64) -> (b,c,n); dst pre-offset by channel base; dst batch stride = HS
__global__ __launch_bounds__(256) void k_tr(const float* __restrict__ src, float* __restrict__ dst){
  int b = blockIdx.x >> 5; int n0 = (blockIdx.x & 31) << 6;
  __shared__ float t[64*65];
  for (int e=threadIdx.x; e<4096; e+=256){
    int r = e >> 6, c = e & 63;
    t[r*65+c] = src[(b*Nn + n0 + r)*64 + c];
  }
  __syncthreads();
  for (int e=threadIdx.x; e<4096; e+=256){
    int c = e >> 6, r = e & 63;
    dst[b*HS + c*Nn + n0 + r] = t[r*65+c];
  }
}

// ---------------- SA layer ----------------
// grid 512 = b(8) x nt(32) x part(2); unified rows: r<32 -> QX row r, else XV row r-32.
__global__ __launch_bounds__(256) void k_sa_a(const float* __restrict__ IN,
                                              const float* __restrict__ QKw, const float* __restrict__ Vw,
                                              const float* __restrict__ Vb,
                                              float* __restrict__ QX, float* __restrict__ XV){
  int blk = blockIdx.x;
  int part = blk & 1; int nt = (blk >> 1) & 31; int b = blk >> 6;
  int n0 = nt << 6;
  int w = threadIdx.x >> 6, lane = threadIdx.x & 63;
  __shared__ float xl[128*64];
  for (int e=threadIdx.x; e<8192; e+=256){
    int c = e >> 6, j = e & 63;
    xl[e] = IN[b*HS + c*Nn + n0 + j];
  }
  __syncthreads();
  for (int i=0;i<20;++i){
    int r = part*80 + w*20 + i;
    const float4* wp4;
    if (r < 32) wp4 = (const float4*)(QKw + r*128);
    else        wp4 = (const float4*)(Vw + (r-32)*128);
    float a = 0.f;
    #pragma unroll
    for (int c4=0;c4<32;++c4){
      float4 wv = wp4[c4];
      a = fmaf(wv.x, xl[(c4*4+0)*64 + lane], a);
      a = fmaf(wv.y, xl[(c4*4+1)*64 + lane], a);
      a = fmaf(wv.z, xl[(c4*4+2)*64 + lane], a);
      a = fmaf(wv.w, xl[(c4*4+3)*64 + lane], a);
    }
    if (r < 32) QX[(b*32+r)*Nn + n0 + lane] = a;
    else { int o = r-32; XV[(b*128+o)*Nn + n0 + lane] = a + Vb[o]; }
  }
}

// m-split x8: grid 512 = b(8) x nc(8) x mc(8)
// v2: qt read as broadcast float4 (4 m per inner iter, was 2 x b32/b64) --
// sa_b is LDS-issue-bound, this halves LDS wave-instructions. Bit-exact:
// same per-e fmaf order over o, same ascending-m online update sequence.
// Measured R8: ~-79us total across 4 dispatches vs scalar qt reads.
__global__ __launch_bounds__(256) void k_sa_b(const float* __restrict__ QX,
                                              float* __restrict__ RMP, float* __restrict__ RSP){
  int blk = blockIdx.x;
  int b = blk >> 6, sub = blk & 63;
  int ncn = sub >> 3, mcn = sub & 7;
  int n = ncn*256 + threadIdx.x;
  float q[32];
  #pragma unroll
  for (int o=0;o<32;++o) q[o] = QX[(b*32+o)*Nn + n];
  __shared__ __align__(16) float qt[32*128];
  float mr = -__builtin_inff(), lr = 0.f;
  int m0 = mcn*256;
  for (int t=0;t<2;++t){
    for (int e=threadIdx.x; e<4096; e+=256){
      int o = e >> 7, mm = e & 127;
      qt[e] = QX[(b*32+o)*Nn + m0 + t*128 + mm];
    }
    __syncthreads();
    for (int mm=0;mm<128;mm+=4){
      float e0=0.f, e1=0.f, e2=0.f, e3=0.f;
      #pragma unroll
      for (int o=0;o<32;++o){
        float qo=q[o];
        float4 qv = *(const float4*)&qt[o*128+mm];
        e0 = fmaf(qo, qv.x, e0);
        e1 = fmaf(qo, qv.y, e1);
        e2 = fmaf(qo, qv.z, e2);
        e3 = fmaf(qo, qv.w, e3);
      }
      if (e0 > mr){ lr = lr*expf(mr-e0) + 1.f; mr = e0; } else lr += expf(e0-mr);
      if (e1 > mr){ lr = lr*expf(mr-e1) + 1.f; mr = e1; } else lr += expf(e1-mr);
      if (e2 > mr){ lr = lr*expf(mr-e2) + 1.f; mr = e2; } else lr += expf(e2-mr);
      if (e3 > mr){ lr = lr*expf(mr-e3) + 1.f; mr = e3; } else lr += expf(e3-mr);
    }
    __syncthreads();
  }
  RMP[(b*Nn+n)*8 + mcn] = mr;
  RSP[(b*Nn+n)*8 + mcn] = lr;
}

__global__ __launch_bounds__(256) void k_sa_b2(const float* __restrict__ RMP, const float* __restrict__ RSP,
                                               float* __restrict__ RMX, float* __restrict__ RSM){
  int e = blockIdx.x*256 + threadIdx.x;
  float M = -__builtin_inff();
  #pragma unroll
  for (int i=0;i<8;++i) M = fmaxf(M, RMP[e*8+i]);
  float l = 0.f;
  #pragma unroll
  for (int i=0;i<8;++i) l += RSP[e*8+i]*expf(RMP[e*8+i]-M);
  RMX[e] = M; RSM[e] = l;
}

// LDS map (floats): QM[32o][32m]=1024 @0, QN[32o][32n]=1024 @1024,
// XVt[32n][132]=4224 @2048, SL[32n][32m]=1024 @6272, MX@7296, RL@7328.
#define SM_QM 0
#define SM_QN 1024
#define SM_XV 2048
#define SM_SL 6272
#define SM_MX 7296
#define SM_RL 7328

// main: grid 1024 = b(8) x mt(64) x part(2); n-range split in 2; writes PV and
// column-sum partials to PP/CSP.
__global__ __launch_bounds__(256) void k_sa_cm(const float* __restrict__ QX, const float* __restrict__ XV,
                                               const float* __restrict__ RMAX, const float* __restrict__ RSUM,
                                               float* __restrict__ PP, float* __restrict__ CSP){
  int blk = blockIdx.x;
  int part = blk & 1, mt = (blk >> 1) & 63, b = blk >> 7;
  int m0 = mt << 5;
  int tid = threadIdx.x;
  int nnp = tid >> 4, mmp = tid & 15;      // 2x2 S-microtile owner
  int tc = tid >> 3, tm8 = tid & 7;        // PV owner: c=tc*4+ci, m=tm8*4+mi
  __shared__ __align__(16) float sm[7360];
  for (int e=tid; e<1024; e+=256){
    int o = e >> 5, mm = e & 31;
    sm[SM_QM + e] = QX[(b*32+o)*Nn + m0 + mm];
  }
  float acc[4][4];
  #pragma unroll
  for (int ci=0;ci<4;++ci){
    #pragma unroll
    for (int mi=0;mi<4;++mi) acc[ci][mi] = 0.f;
  }
  float csr = 0.f;
  int it0 = part*32;
  for (int it=it0; it<it0+32; ++it){
    int nb = it*32;
    __syncthreads();
    for (int e=tid; e<1024; e+=256){ int o=e>>5, nn=e&31; sm[SM_QN+e] = QX[(b*32+o)*Nn + nb + nn]; }
    for (int e=tid; e<4096; e+=256){ int c=e>>5, nn=e&31; sm[SM_XV + nn*132 + c] = XV[(b*128+c)*Nn + nb + nn]; }
    if (tid < 32){ sm[SM_MX+tid] = RMAX[b*Nn + nb + tid]; sm[SM_RL+tid] = 1.0f / RSUM[b*Nn + nb + tid]; }
    __syncthreads();
    float e00=0.f, e01=0.f, e10=0.f, e11=0.f;
    #pragma unroll
    for (int o=0;o<32;++o){
      float2 qn = *(const float2*)&sm[SM_QN + o*32 + nnp*2];
      float2 qm = *(const float2*)&sm[SM_QM + o*32 + mmp*2];
      e00 = fmaf(qn.x, qm.x, e00);
      e01 = fmaf(qn.x, qm.y, e01);
      e10 = fmaf(qn.y, qm.x, e10);
      e11 = fmaf(qn.y, qm.y, e11);
    }
    float mx0 = sm[SM_MX + nnp*2],   rl0 = sm[SM_RL + nnp*2];
    float mx1 = sm[SM_MX + nnp*2+1], rl1 = sm[SM_RL + nnp*2+1];
    float2 s0; s0.x = expf(e00-mx0)*rl0; s0.y = expf(e01-mx0)*rl0;
    float2 s1; s1.x = expf(e10-mx1)*rl1; s1.y = expf(e11-mx1)*rl1;
    *(float2*)&sm[SM_SL + (nnp*2  )*32 + mmp*2] = s0;
    *(float2*)&sm[SM_SL + (nnp*2+1)*32 + mmp*2] = s1;
    __syncthreads();
    if (tid < 32){
      #pragma unroll
      for (int nn=0;nn<32;++nn) csr += sm[SM_SL + nn*32 + tid];
    }
    #pragma unroll 8
    for (int nn=0;nn<32;++nn){
      float4 xv4 = *(const float4*)&sm[SM_XV + nn*132 + tc*4];
      float4 s4  = *(const float4*)&sm[SM_SL + nn*32  + tm8*4];
      acc[0][0] = fmaf(xv4.x, s4.x, acc[0][0]);
      acc[0][1] = fmaf(xv4.x, s4.y, acc[0][1]);
      acc[0][2] = fmaf(xv4.x, s4.z, acc[0][2]);
      acc[0][3] = fmaf(xv4.x, s4.w, acc[0][3]);
      acc[1][0] = fmaf(xv4.y, s4.x, acc[1][0]);
      acc[1][1] = fmaf(xv4.y, s4.y, acc[1][1]);
      acc[1][2] = fmaf(xv4.y, s4.z, acc[1][2]);
      acc[1][3] = fmaf(xv4.y, s4.w, acc[1][3]);
      acc[2][0] = fmaf(xv4.z, s4.x, acc[2][0]);
      acc[2][1] = fmaf(xv4.z, s4.y, acc[2][1]);
      acc[2][2] = fmaf(xv4.z, s4.z, acc[2][2]);
      acc[2][3] = fmaf(xv4.z, s4.w, acc[2][3]);
      acc[3][0] = fmaf(xv4.w, s4.x, acc[3][0]);
      acc[3][1] = fmaf(xv4.w, s4.y, acc[3][1]);
      acc[3][2] = fmaf(xv4.w, s4.z, acc[3][2]);
      acc[3][3] = fmaf(xv4.w, s4.w, acc[3][3]);
    }
  }
  int slot = (b*64 + mt)*2 + part;
  #pragma unroll
  for (int ci=0;ci<4;++ci){
    int c = tc*4 + ci;
    *(float4*)&PP[slot*4096 + c*32 + tm8*4] =
      make_float4(acc[ci][0], acc[ci][1], acc[ci][2], acc[ci][3]);
  }
  if (tid < 32) CSP[slot*32 + tid] = csr;
}

// combine + transform epilogue: grid 512 = b(8) x mt(64). In-place on h.
__global__ __launch_bounds__(256) void k_sa_cc(const float* IN,
                                               const float* __restrict__ PP, const float* __restrict__ CSP,
                                               const float* __restrict__ Tw, const float* __restrict__ Tb,
                                               const float* __restrict__ Gs, const float* __restrict__ Bs,
                                               float* OUT){
  int blk = blockIdx.x;
  int mt = blk & 63, b = blk >> 6;
  int m0 = mt << 5;
  int tid = threadIdx.x;
  int tc = tid >> 3, tm8 = tid & 7;
  __shared__ __align__(16) float sm[4128];   // DL[128][32] @0, CS[32] @4096
  int s0 = (b*64 + mt)*2, s1 = s0 + 1;
  if (tid < 32) sm[4096 + tid] = CSP[s0*32 + tid] + CSP[s1*32 + tid];
  __syncthreads();
  #pragma unroll
  for (int ci=0;ci<4;++ci){
    int c = tc*4 + ci;
    float4 p0 = *(const float4*)&PP[s0*4096 + c*32 + tm8*4];
    float4 p1 = *(const float4*)&PP[s1*4096 + c*32 + tm8*4];
    float am[4] = {p0.x+p1.x, p0.y+p1.y, p0.z+p1.z, p0.w+p1.w};
    #pragma unroll
    for (int mi=0;mi<4;++mi){
      int ml = tm8*4 + mi;
      float cs = sm[4096 + ml];
      float xr = am[mi] / (1e-9f + cs);
      sm[c*32 + ml] = IN[b*HS + c*Nn + m0 + ml] - xr;
    }
  }
  __syncthreads();
  int hw = tid >> 5, m = tid & 31;
  float sroot = sqrtf(1.0f + 1e-5f);
  for (int oo=0; oo<16; ++oo){
    int o = oo*8 + hw;
    const float4* twp = (const float4*)(Tw + o*128);
    float a = 0.f;
    #pragma unroll
    for (int c4=0;c4<32;++c4){
      float4 wv = twp[c4];
      a = fmaf(wv.x, sm[(c4*4+0)*32 + m], a);
      a = fmaf(wv.y, sm[(c4*4+1)*32 + m], a);
      a = fmaf(wv.z, sm[(c4*4+2)*32 + m], a);
      a = fmaf(wv.w, sm[(c4*4+3)*32 + m], a);
    }
    a += Tb[o];
    float y = a * (Gs[o] / sroot) + Bs[o];
    y = fmaxf(y, 0.f);
    OUT[b*HS + o*Nn + m0 + m] = IN[b*HS + o*Nn + m0 + m] + y;
  }
}

// ---------------- progressive fuse: ACC += FW[:, l*128:(l+1)*128] * h_l ----------------
// grid 512 = b(8) x nt(32) x half(2); wave w covers o = hf*128 + w*32 + [0,32).
// fin: apply final BN + leaky-ReLU on the last layer's write (replaces k_fin).
__global__ __launch_bounds__(256) void k_fuse_part(const float* __restrict__ Hc, const float* __restrict__ FWT,
                                                   float* __restrict__ ACC, int l, int init, int fin,
                                                   const float* __restrict__ FGF, const float* __restrict__ FBF){
  int blk = blockIdx.x;
  int hf = blk & 1; int nt = (blk >> 1) & 31; int b = blk >> 6;
  int n0 = nt << 6;
  int w = threadIdx.x >> 6, lane = threadIdx.x & 63;
  __shared__ float xt[128*64];
  for (int e=threadIdx.x; e<8192; e+=256){
    int c = e >> 6, j = e & 63;
    xt[e] = Hc[(b*128 + c)*Nn + n0 + j];
  }
  __syncthreads();
  float4 a[8];
  #pragma unroll
  for (int j=0;j<8;++j) a[j] = make_float4(0.f,0.f,0.f,0.f);
  int ob = hf*128 + w*32;
  for (int c=0;c<128;++c){
    float xv = xt[c*64 + lane];
    const float4* wr = (const float4*)(FWT + (l*128+c)*256 + ob);
    #pragma unroll
    for (int j4=0;j4<8;++j4){
      float4 wv = wr[j4];
      a[j4].x = fmaf(wv.x, xv, a[j4].x);
      a[j4].y = fmaf(wv.y, xv, a[j4].y);
      a[j4].z = fmaf(wv.z, xv, a[j4].z);
      a[j4].w = fmaf(wv.w, xv, a[j4].w);
    }
  }
  float sroot = sqrtf(1.0f + 1e-5f);
  #pragma unroll
  for (int j4=0;j4<8;++j4){
    float vs[4] = {a[j4].x, a[j4].y, a[j4].z, a[j4].w};
    #pragma unroll
    for (int qq=0;qq<4;++qq){
      int o = ob + j4*4 + qq;
      int idx = (b*256 + o)*Nn + n0 + lane;
      float v = init ? vs[qq] : (ACC[idx] + vs[qq]);
      if (fin){
        float y = v * (FGF[o] / sroot) + FBF[o];
        y = (y >= 0.f) ? y : 0.2f*y;
        ACC[idx] = y;
      } else {
        ACC[idx] = v;
      }
    }
  }
}

extern "C" void kernel_launch(void* const* d_in, const int* in_sizes, int n_in,
                              void* d_out, int out_size, void* d_ws, size_t ws_size,
                              hipStream_t stream) {
  const float* X   = (const float*)d_in[0];
  const float* w1  = (const float*)d_in[1];
  const float* g1  = (const float*)d_in[2];
  const float* b1  = (const float*)d_in[3];
  const float* w2  = (const float*)d_in[4];
  const float* g2  = (const float*)d_in[5];
  const float* b2_ = (const float*)d_in[6];
  const float* w3  = (const float*)d_in[7];
  const float* g3  = (const float*)d_in[8];
  const float* b3  = (const float*)d_in[9];
  const float* w4  = (const float*)d_in[10];
  const float* g4  = (const float*)d_in[11];
  const float* b4  = (const float*)d_in[12];
  // d_in[13..15] = w5/g5/b5 : unused by reference
  const float* qk  = (const float*)d_in[16];
  const float* sv  = (const float*)d_in[17];
  const float* svb = (const float*)d_in[18];
  const float* st  = (const float*)d_in[19];
  const float* stb = (const float*)d_in[20];
  const float* sg  = (const float*)d_in[21];
  const float* sb  = (const float*)d_in[22];
  const float* fw  = (const float*)d_in[23];
  const float* fg  = (const float*)d_in[24];
  const float* fb  = (const float*)d_in[25];

  float* ws = (float*)d_ws;
  float* H    = ws + 0;          // 2,097,152
  float* QXb  = ws + 2097152;    //   524,288
  float* XVb  = ws + 2621440;    // 2,097,152 (ends 4,718,592)
  float* RMP  = ws + 4718592;    //   131,072
  float* RSP  = ws + 4849664;    //   131,072
  float* RMX  = ws + 4980736;    //    16,384
  float* RSM  = ws + 4997120;    //    16,384 (ends 5,013,504)
  // phase-1 overlay on [2,097,152 .. 4,915,200) — dead before SA phase:
  float* XX   = ws + 2146304;
  int*   IDX  = (int*)(ws + 2162688);
  float* X1T  = ws + 2818048;
  float* X2T  = ws + 3866624;    // ends 4,915,200
  float* C0   = ws + 5013504;
  float* W1T = C0 + 0;
  float* W2T = C0 + 384;
  float* W3T = C0 + 4480;
  float* W4T = C0 + 12672;
  float* FWT = C0 + 16768;       // C0 ends 5,161,344
  float* PP  = ws + 5161344;     // 4,194,304 (PV partials: 1024 slots x 4096)
  float* CSP = ws + 9355648;     //    32,768 — total 9,388,416 floats = 35.8 MiB
  float* ACC = (float*)d_out;

  k_xx1<<<64,256,0,stream>>>(X, XX);
  k_prep_wt<<<578,256,0,stream>>>(w1,w2,w3,w4,fw, W1T,W2T,W3T,W4T,FWT);
  k_knn1<<<4096,256,0,stream>>>(X, XX, IDX);
  k_ec1<<<16384,64,0,stream>>>(X, IDX, W1T, W2T, g1,b1,g2,b2_, X1T);
  k_xx2<<<64,256,0,stream>>>(X1T, XX);
  k_tr<<<256,256,0,stream>>>(X1T, H);                  // X1 -> channel-major (H ch 0..63), BEFORE knn2
  k_knn2<<<2048,256,0,stream>>>(H, XX, IDX);           // v3: 2 q/wave, shared loads (verified 262us)
  k_ec2<<<16384,64,0,stream>>>(X1T, IDX, W3T, W4T, g3,b3,g4,b4, X2T);
  k_tr<<<256,256,0,stream>>>(X2T, H + 64*Nn);

  for (int l=0;l<4;++l){
    k_sa_a<<<512,256,0,stream>>>(H, qk + l*4096, sv + l*16384, svb + l*128, QXb, XVb);
    k_sa_b<<<512,256,0,stream>>>(QXb, RMP, RSP);
    k_sa_b2<<<64,256,0,stream>>>(RMP, RSP, RMX, RSM);
    k_sa_cm<<<1024,256,0,stream>>>(QXb, XVb, RMX, RSM, PP, CSP);
    k_sa_cc<<<512,256,0,stream>>>(H, PP, CSP,
                                  st + l*16384, stb + l*128, sg + l*128, sb + l*128, H);
    k_fuse_part<<<512,256,0,stream>>>(H, FWT, ACC, l, (l==0)?1:0, (l==3)?1:0, fg, fb);
  }
}

// Round 12
// 2460.882 us; speedup vs baseline: 1.2069x; 1.0325x over previous
//
#include <hip/hip_runtime.h>

#define Bb 8
#define Nn 2048
#define Kk 40
#define HS (128*Nn)   // h stride per batch (channel-major [b,128,2048])

// monotone float->uint transform: a > b  <=>  f2o(a) > f2o(b)
__device__ __forceinline__ unsigned f2o(float f){
  unsigned u = __float_as_uint(f);
  return (u & 0x80000000u) ? ~u : (u | 0x80000000u);
}

// Wave-cooperative exact top-40 of 2048, grouped rescan (4 groups of 8 slots).
// Lane owns m = slot*64+lane. Per round only the winner lane rescans its group;
// selection order identical to a full linear scan (value desc, index asc).
__device__ __forceinline__ void wave_top40(float* d, int lane, int* op){
  float gv[4]; int gs[4];
  #pragma unroll
  for (int g=0; g<4; ++g){
    float bv = d[g*8]; int bs = g*8;
    #pragma unroll
    for (int j=1;j<8;++j){
      float v = d[g*8+j];
      if (v > bv){ bv = v; bs = g*8+j; }
    }
    gv[g]=bv; gs[g]=bs;
  }
  for (int t=0; t<Kk; ++t){
    float bv = gv[0]; int bs = gs[0];
    if (gv[1] > bv){ bv=gv[1]; bs=gs[1]; }
    if (gv[2] > bv){ bv=gv[2]; bs=gs[2]; }
    if (gv[3] > bv){ bv=gv[3]; bs=gs[3]; }
    int bm = bs*64 + lane;
    unsigned long long key = ((unsigned long long)f2o(bv) << 32) | (unsigned)(~bm);
    #pragma unroll
    for (int s=32;s>0;s>>=1){
      unsigned long long o = __shfl_xor(key, s, 64);
      if (o > key) key = o;
    }
    int wm = (int)(~(unsigned)key);
    if (lane == 0) op[t] = wm;
    bool mine = ((wm & 63) == lane);
    int wsl = wm >> 6;
    if (mine){
      int G = wsl >> 3;
      #pragma unroll
      for (int g=0; g<4; ++g){
        if (g == G){
          float nv = -__builtin_inff(); int ns = g*8;
          #pragma unroll
          for (int j=0;j<8;++j){
            float v = d[g*8+j];
            if (g*8+j == wsl) v = -__builtin_inff();
            d[g*8+j] = v;
            if (v > nv){ nv=v; ns=g*8+j; }
          }
          gv[g]=nv; gs[g]=ns;
        }
      }
    }
  }
}

// Variant for mapping m = (s>>2)*256 + lane*4 + (s&3) (coalesced float4 ownership).
// Within a lane m is increasing in s, so the same grouped tie-break is exact.
__device__ __forceinline__ void wave_top40_g(float* d, int lane, int* op){
  float gv[4]; int gs[4];
  #pragma unroll
  for (int g=0; g<4; ++g){
    float bv = d[g*8]; int bs = g*8;
    #pragma unroll
    for (int j=1;j<8;++j){
      float v = d[g*8+j];
      if (v > bv){ bv = v; bs = g*8+j; }
    }
    gv[g]=bv; gs[g]=bs;
  }
  for (int t=0; t<Kk; ++t){
    float bv = gv[0]; int bs = gs[0];
    if (gv[1] > bv){ bv=gv[1]; bs=gs[1]; }
    if (gv[2] > bv){ bv=gv[2]; bs=gs[2]; }
    if (gv[3] > bv){ bv=gv[3]; bs=gs[3]; }
    int bm = ((bs>>2)<<8) + lane*4 + (bs&3);
    unsigned long long key = ((unsigned long long)f2o(bv) << 32) | (unsigned)(~bm);
    #pragma unroll
    for (int s=32;s>0;s>>=1){
      unsigned long long o = __shfl_xor(key, s, 64);
      if (o > key) key = o;
    }
    int wm = (int)(~(unsigned)key);
    if (lane == 0) op[t] = wm;
    bool mine = (((wm>>2) & 63) == lane);
    int wsl = ((wm>>8)<<2) | (wm & 3);
    if (mine){
      int G = wsl >> 3;
      #pragma unroll
      for (int g=0; g<4; ++g){
        if (g == G){
          float nv = -__builtin_inff(); int ns = g*8;
          #pragma unroll
          for (int j=0;j<8;++j){
            float v = d[g*8+j];
            if (g*8+j == wsl) v = -__builtin_inff();
            d[g*8+j] = v;
            if (v > nv){ nv=v; ns=g*8+j; }
          }
          gv[g]=nv; gs[g]=ns;
        }
      }
    }
  }
}

// ---------------- prep ----------------
__global__ __launch_bounds__(256) void k_xx1(const float* __restrict__ x, float* __restrict__ XX){
  int e = blockIdx.x*256 + threadIdx.x;
  if (e >= Bb*Nn) return;
  float p0 = x[e*3+0], p1 = x[e*3+1], p2 = x[e*3+2];
  XX[e] = __fadd_rn(__fadd_rn(__fmul_rn(p0,p0), __fmul_rn(p1,p1)), __fmul_rn(p2,p2));
}

__global__ __launch_bounds__(256) void k_prep_wt(const float* __restrict__ w1, const float* __restrict__ w2,
                                                 const float* __restrict__ w3, const float* __restrict__ w4,
                                                 const float* __restrict__ fw,
                                                 float* __restrict__ W1T, float* __restrict__ W2T,
                                                 float* __restrict__ W3T, float* __restrict__ W4T,
                                                 float* __restrict__ FWT){
  int e = blockIdx.x*256 + threadIdx.x;
  if (e < 384)   { int i=e/64,  c=e%64;  W1T[e] = w1[c*6+i];    return; } e -= 384;
  if (e < 4096)  { int i=e/64,  c=e%64;  W2T[e] = w2[c*64+i];   return; } e -= 4096;
  if (e < 8192)  { int i=e/64,  c=e%64;  W3T[e] = w3[c*128+i];  return; } e -= 8192;
  if (e < 4096)  { int i=e/64,  c=e%64;  W4T[e] = w4[c*64+i];   return; } e -= 4096;
  if (e < 131072){ int i=e/256, o=e%256; FWT[e] = fw[o*512+i];  return; }
}

// ---------------- knn on 3-D points: 1 wave / query, LDS-staged cloud ----------------
__global__ __launch_bounds__(256) void k_knn1(const float* __restrict__ P, const float* __restrict__ XX,
                                              int* __restrict__ IDX){
  int blk = blockIdx.x;
  int b = blk >> 9;
  int w = threadIdx.x >> 6, lane = threadIdx.x & 63;
  int n = (blk & 511)*4 + w;
  const float* Pb = P + b*Nn*3;
  const float* xb = XX + b*Nn;
  __shared__ float Pl[Nn*3];
  __shared__ float Xl[Nn];
  for (int e = threadIdx.x; e < Nn*3; e += 256) Pl[e] = Pb[e];
  for (int e = threadIdx.x; e < Nn; e += 256) Xl[e] = xb[e];
  __syncthreads();
  float c0 = Pl[n*3+0], c1 = Pl[n*3+1], c2 = Pl[n*3+2];
  float xn = Xl[n];
  float d[32];
  #pragma unroll
  for (int j=0;j<32;++j){
    int m = j*64 + lane;
    float a0 = Pl[m*3+0], a1 = Pl[m*3+1], a2 = Pl[m*3+2];
    float in_ = __fadd_rn(__fadd_rn(__fmul_rn(c0,a0), __fmul_rn(c1,a1)), __fmul_rn(c2,a2));
    d[j] = __fsub_rn(__fsub_rn(__fmul_rn(2.0f,in_), xn), Xl[m]);
  }
  wave_top40(d, lane, IDX + (b*Nn+n)*Kk);
}

// ---------------- edge conv 1+2 + maxpool (bit-exact _rn path) ----------------
__global__ __launch_bounds__(64) void k_ec1(const float* __restrict__ P, const int* __restrict__ IDX,
                                            const float* __restrict__ W1T, const float* __restrict__ W2T,
                                            const float* __restrict__ g1, const float* __restrict__ b1,
                                            const float* __restrict__ g2, const float* __restrict__ b2,
                                            float* __restrict__ X1T){
  int e = blockIdx.x;           // global point row 0..16383
  int b = e >> 11;
  int lane = threadIdx.x;
  __shared__ float dC[Kk*4];
  __shared__ __align__(16) float y1L[64*44];
  float c0 = P[e*3+0], c1 = P[e*3+1], c2 = P[e*3+2];
  if (lane < Kk) {
    int idx = IDX[e*Kk + lane] & (Nn-1);
    const float* pn = P + (b*Nn + idx)*3;
    dC[lane*4+0] = __fsub_rn(pn[0], c0);
    dC[lane*4+1] = __fsub_rn(pn[1], c1);
    dC[lane*4+2] = __fsub_rn(pn[2], c2);
  }
  __syncthreads();
  float w10 = W1T[0*64+lane], w11 = W1T[1*64+lane], w12 = W1T[2*64+lane];
  float w13 = W1T[3*64+lane], w14 = W1T[4*64+lane], w15 = W1T[5*64+lane];
  float p3 = __fmul_rn(w13,c0), p4 = __fmul_rn(w14,c1), p5 = __fmul_rn(w15,c2);
  float s1 = __fdiv_rn(g1[lane], __fsqrt_rn(1.0f + 1e-5f));
  float o1 = b1[lane];
  for (int k=0;k<Kk;++k){
    float t = __fmul_rn(w10, dC[k*4+0]);
    t = __fadd_rn(t, __fmul_rn(w11, dC[k*4+1]));
    t = __fadd_rn(t, __fmul_rn(w12, dC[k*4+2]));
    t = __fadd_rn(t, p3); t = __fadd_rn(t, p4); t = __fadd_rn(t, p5);
    float y = __fadd_rn(__fmul_rn(t, s1), o1);
    y = (y >= 0.0f) ? y : __fmul_rn(0.2f, y);
    y1L[lane*44+k] = y;
  }
  __syncthreads();
  float4 q[10];
  #pragma unroll
  for (int k4=0;k4<10;++k4) q[k4] = make_float4(0.f,0.f,0.f,0.f);
  for (int i=0;i<64;++i){
    float w = W2T[i*64+lane];
    const float4* yp = (const float4*)&y1L[i*44];
    #pragma unroll
    for (int k4=0;k4<10;++k4){
      float4 yv = yp[k4];
      q[k4].x = __fadd_rn(q[k4].x, __fmul_rn(w, yv.x));
      q[k4].y = __fadd_rn(q[k4].y, __fmul_rn(w, yv.y));
      q[k4].z = __fadd_rn(q[k4].z, __fmul_rn(w, yv.z));
      q[k4].w = __fadd_rn(q[k4].w, __fmul_rn(w, yv.w));
    }
  }
  float s2 = __fdiv_rn(g2[lane], __fsqrt_rn(1.0f + 1e-5f));
  float o2 = b2[lane];
  float mx = -__builtin_inff();
  #pragma unroll
  for (int k4=0;k4<10;++k4){
    float vs[4] = {q[k4].x, q[k4].y, q[k4].z, q[k4].w};
    #pragma unroll
    for (int j=0;j<4;++j){
      float y = __fadd_rn(__fmul_rn(vs[j], s2), o2);
      y = (y >= 0.0f) ? y : __fmul_rn(0.2f, y);
      mx = fmaxf(mx, y);
    }
  }
  X1T[e*64 + lane] = mx;
}

__global__ __launch_bounds__(256) void k_xx2(const float* __restrict__ X1T, float* __restrict__ XX2){
  int e = blockIdx.x*256 + threadIdx.x;
  const float* r = X1T + e*64;
  float a = 0.f;
  for (int c=0;c<64;++c) a = __fadd_rn(a, __fmul_rn(r[c], r[c]));
  XX2[e] = a;
}

// ---------------- knn on 64-D features ----------------
// v3 (verified 262us @ R6/R9): 2 queries/wave (8/block, grid 2048), direct-L2
// float4 reads shared across both queries. v4 (4 q/wave) regressed (occupancy
// 39->22%). grid 2048 / 2q-per-wave is the traffic-vs-TLP sweet spot.
__global__ __launch_bounds__(256) void k_knn2(const float* __restrict__ X1C, const float* __restrict__ XX2,
                                              int* __restrict__ IDX){
  int blk = blockIdx.x;
  int b = blk >> 8;                 // 256 blocks per batch
  int n0 = (blk & 255) << 3;        // 8 queries per block
  int w = threadIdx.x >> 6, lane = threadIdx.x & 63;
  __shared__ float qL[8*64];        // [q][c] query features (2 KB)
  for (int e=threadIdx.x; e<512; e+=256){
    int q = e >> 6, c = e & 63;
    qL[e] = X1C[b*HS + c*Nn + n0 + q];
  }
  __syncthreads();
  float4 a0[8], a1[8];
  #pragma unroll
  for (int j=0;j<8;++j){
    a0[j] = make_float4(0.f,0.f,0.f,0.f);
    a1[j] = make_float4(0.f,0.f,0.f,0.f);
  }
  for (int c=0;c<64;++c){
    const float4* row = (const float4*)(X1C + b*HS + c*Nn);
    float q0 = qL[(w*2+0)*64 + c];
    float q1 = qL[(w*2+1)*64 + c];
    #pragma unroll
    for (int j=0;j<8;++j){
      float4 v = row[j*64 + lane];
      a0[j].x = __fadd_rn(a0[j].x, __fmul_rn(q0, v.x));
      a0[j].y = __fadd_rn(a0[j].y, __fmul_rn(q0, v.y));
      a0[j].z = __fadd_rn(a0[j].z, __fmul_rn(q0, v.z));
      a0[j].w = __fadd_rn(a0[j].w, __fmul_rn(q0, v.w));
      a1[j].x = __fadd_rn(a1[j].x, __fmul_rn(q1, v.x));
      a1[j].y = __fadd_rn(a1[j].y, __fmul_rn(q1, v.y));
      a1[j].z = __fadd_rn(a1[j].z, __fmul_rn(q1, v.z));
      a1[j].w = __fadd_rn(a1[j].w, __fmul_rn(q1, v.w));
    }
  }
  const float* xb = XX2 + b*Nn;
  const float4* xb4 = (const float4*)xb;
  {
    int n = n0 + w*2 + 0;
    float xn = xb[n];
    float d[32];
    #pragma unroll
    for (int j=0;j<8;++j){
      float4 xm = xb4[j*64 + lane];
      d[j*4+0] = __fsub_rn(__fsub_rn(__fmul_rn(2.0f, a0[j].x), xn), xm.x);
      d[j*4+1] = __fsub_rn(__fsub_rn(__fmul_rn(2.0f, a0[j].y), xn), xm.y);
      d[j*4+2] = __fsub_rn(__fsub_rn(__fmul_rn(2.0f, a0[j].z), xn), xm.z);
      d[j*4+3] = __fsub_rn(__fsub_rn(__fmul_rn(2.0f, a0[j].w), xn), xm.w);
    }
    wave_top40_g(d, lane, IDX + (b*Nn + n)*Kk);
  }
  {
    int n = n0 + w*2 + 1;
    float xn = xb[n];
    float d[32];
    #pragma unroll
    for (int j=0;j<8;++j){
      float4 xm = xb4[j*64 + lane];
      d[j*4+0] = __fsub_rn(__fsub_rn(__fmul_rn(2.0f, a1[j].x), xn), xm.x);
      d[j*4+1] = __fsub_rn(__fsub_rn(__fmul_rn(2.0f, a1[j].y), xn), xm.y);
      d[j*4+2] = __fsub_rn(__fsub_rn(__fmul_rn(2.0f, a1[j].z), xn), xm.z);
      d[j*4+3] = __fsub_rn(__fsub_rn(__fmul_rn(2.0f, a1[j].w), xn), xm.w);
    }
    wave_top40_g(d, lane, IDX + (b*Nn + n)*Kk);
  }
}

// ---------------- edge conv 3+4 + maxpool (fma ok) ----------------
__global__ __launch_bounds__(64) void k_ec2(const float* __restrict__ X1T, const int* __restrict__ IDX,
                                            const float* __restrict__ W3T, const float* __restrict__ W4T,
                                            const float* __restrict__ g3, const float* __restrict__ b3,
                                            const float* __restrict__ g4, const float* __restrict__ b4,
                                            float* __restrict__ X2T){
  int e = blockIdx.x; int b = e >> 11; int lane = threadIdx.x;
  __shared__ __align__(16) float dL[64*44];
  __shared__ float ctrL[64];
  float ctr = X1T[e*64 + lane];
  ctrL[lane] = ctr;
  __syncthreads();
  for (int k=0;k<Kk;++k){
    int idx = IDX[e*Kk + k] & (Nn-1);
    dL[lane*44 + k] = X1T[(b*Nn+idx)*64 + lane] - ctr;
  }
  __syncthreads();
  float base = 0.f;
  for (int i=0;i<64;++i) base = fmaf(W3T[(64+i)*64 + lane], ctrL[i], base);
  float4 q[10];
  #pragma unroll
  for (int k4=0;k4<10;++k4) q[k4] = make_float4(base,base,base,base);
  for (int i=0;i<64;++i){
    float w = W3T[i*64 + lane];
    const float4* dp = (const float4*)&dL[i*44];
    #pragma unroll
    for (int k4=0;k4<10;++k4){
      float4 d = dp[k4];
      q[k4].x = fmaf(w, d.x, q[k4].x);
      q[k4].y = fmaf(w, d.y, q[k4].y);
      q[k4].z = fmaf(w, d.z, q[k4].z);
      q[k4].w = fmaf(w, d.w, q[k4].w);
    }
  }
  float s3 = g3[lane] / sqrtf(1.0f+1e-5f);
  float o3 = b3[lane];
  __syncthreads();
  #pragma unroll
  for (int k4=0;k4<10;++k4){
    float4 y;
    y.x = q[k4].x*s3 + o3; y.x = (y.x>=0.f)?y.x:0.2f*y.x;
    y.y = q[k4].y*s3 + o3; y.y = (y.y>=0.f)?y.y:0.2f*y.y;
    y.z = q[k4].z*s3 + o3; y.z = (y.z>=0.f)?y.z:0.2f*y.z;
    y.w = q[k4].w*s3 + o3; y.w = (y.w>=0.f)?y.w:0.2f*y.w;
    *(float4*)&dL[lane*44 + k4*4] = y;
  }
  __syncthreads();
  float4 p[10];
  #pragma unroll
  for (int k4=0;k4<10;++k4) p[k4] = make_float4(0.f,0.f,0.f,0.f);
  for (int i=0;i<64;++i){
    float w = W4T[i*64 + lane];
    const float4* yp = (const float4*)&dL[i*44];
    #pragma unroll
    for (int k4=0;k4<10;++k4){
      float4 yv = yp[k4];
      p[k4].x = fmaf(w, yv.x, p[k4].x);
      p[k4].y = fmaf(w, yv.y, p[k4].y);
      p[k4].z = fmaf(w, yv.z, p[k4].z);
      p[k4].w = fmaf(w, yv.w, p[k4].w);
    }
  }
  float s4 = g4[lane] / sqrtf(1.0f+1e-5f);
  float o4 = b4[lane];
  float mx = -__builtin_inff();
  #pragma unroll
  for (int k4=0;k4<10;++k4){
    float vs[4] = {p[k4].x, p[k4].y, p[k4].z, p[k4].w};
    #pragma unroll
    for (int j=0;j<4;++j){
      float y = vs[j]*s4 + o4;
      y = (y>=0.f)?y:0.2f*y;
      mx = fmaxf(mx, y);
    }
  }
  X2T[e*64 + lane] = mx;
}

// (b,n,64) -> (b,c,n); dst pre-offset by channel base; dst batch stride = HS
__global__ __launch_bounds__(256) void k_tr(const float* __restrict__ src, float* __restrict__ dst){
  int b = blockIdx.x >> 5; int n0 = (blockIdx.x & 31) << 6;
  __shared__ float t[64*65];
  for (int e=threadIdx.x; e<4096; e+=256){
    int r = e >> 6, c = e & 63;
    t[r*65+c] = src[(b*Nn + n0 + r)*64 + c];
  }
  __syncthreads();
  for (int e=threadIdx.x; e<4096; e+=256){
    int c = e >> 6, r = e & 63;
    dst[b*HS + c*Nn + n0 + r] = t[r*65+c];
  }
}

// ---------------- SA layer ----------------
// grid 512 = b(8) x nt(32) x part(2); unified rows: r<32 -> QX row r, else XV row r-32.
// v2: xl staging via float4 (8 b128 loads + 8 b128 LDS writes per thread, was
// 32 b32 each). Same values, same slots -> bit-exact.
__global__ __launch_bounds__(256) void k_sa_a(const float* __restrict__ IN,
                                              const float* __restrict__ QKw, const float* __restrict__ Vw,
                                              const float* __restrict__ Vb,
                                              float* __restrict__ QX, float* __restrict__ XV){
  int blk = blockIdx.x;
  int part = blk & 1; int nt = (blk >> 1) & 31; int b = blk >> 6;
  int n0 = nt << 6;
  int w = threadIdx.x >> 6, lane = threadIdx.x & 63;
  __shared__ __align__(16) float xl[128*64];
  for (int e=threadIdx.x; e<2048; e+=256){
    int c = e >> 4, j4 = (e & 15) << 2;
    *(float4*)&xl[(c<<6) + j4] = *(const float4*)&IN[b*HS + c*Nn + n0 + j4];
  }
  __syncthreads();
  for (int i=0;i<20;++i){
    int r = part*80 + w*20 + i;
    const float4* wp4;
    if (r < 32) wp4 = (const float4*)(QKw + r*128);
    else        wp4 = (const float4*)(Vw + (r-32)*128);
    float a = 0.f;
    #pragma unroll
    for (int c4=0;c4<32;++c4){
      float4 wv = wp4[c4];
      a = fmaf(wv.x, xl[(c4*4+0)*64 + lane], a);
      a = fmaf(wv.y, xl[(c4*4+1)*64 + lane], a);
      a = fmaf(wv.z, xl[(c4*4+2)*64 + lane], a);
      a = fmaf(wv.w, xl[(c4*4+3)*64 + lane], a);
    }
    if (r < 32) QX[(b*32+r)*Nn + n0 + lane] = a;
    else { int o = r-32; XV[(b*128+o)*Nn + n0 + lane] = a + Vb[o]; }
  }
}

// m-split x8: grid 512 = b(8) x nc(8) x mc(8)
// v3: qt staged via float4 global loads + b128 LDS writes (4 iters/thread,
// was 16 b32); inner loop reads qt as broadcast float4 (R8: -79us total).
// Bit-exact: same per-e fmaf order over o, same ascending-m online updates.
__global__ __launch_bounds__(256) void k_sa_b(const float* __restrict__ QX,
                                              float* __restrict__ RMP, float* __restrict__ RSP){
  int blk = blockIdx.x;
  int b = blk >> 6, sub = blk & 63;
  int ncn = sub >> 3, mcn = sub & 7;
  int n = ncn*256 + threadIdx.x;
  float q[32];
  #pragma unroll
  for (int o=0;o<32;++o) q[o] = QX[(b*32+o)*Nn + n];
  __shared__ __align__(16) float qt[32*128];
  float mr = -__builtin_inff(), lr = 0.f;
  int m0 = mcn*256;
  for (int t=0;t<2;++t){
    for (int e=threadIdx.x; e<1024; e+=256){
      int o = e >> 5, mm4 = (e & 31) << 2;
      *(float4*)&qt[(o<<7) + mm4] = *(const float4*)&QX[(b*32+o)*Nn + m0 + t*128 + mm4];
    }
    __syncthreads();
    for (int mm=0;mm<128;mm+=4){
      float e0=0.f, e1=0.f, e2=0.f, e3=0.f;
      #pragma unroll
      for (int o=0;o<32;++o){
        float qo=q[o];
        float4 qv = *(const float4*)&qt[o*128+mm];
        e0 = fmaf(qo, qv.x, e0);
        e1 = fmaf(qo, qv.y, e1);
        e2 = fmaf(qo, qv.z, e2);
        e3 = fmaf(qo, qv.w, e3);
      }
      if (e0 > mr){ lr = lr*expf(mr-e0) + 1.f; mr = e0; } else lr += expf(e0-mr);
      if (e1 > mr){ lr = lr*expf(mr-e1) + 1.f; mr = e1; } else lr += expf(e1-mr);
      if (e2 > mr){ lr = lr*expf(mr-e2) + 1.f; mr = e2; } else lr += expf(e2-mr);
      if (e3 > mr){ lr = lr*expf(mr-e3) + 1.f; mr = e3; } else lr += expf(e3-mr);
    }
    __syncthreads();
  }
  RMP[(b*Nn+n)*8 + mcn] = mr;
  RSP[(b*Nn+n)*8 + mcn] = lr;
}

__global__ __launch_bounds__(256) void k_sa_b2(const float* __restrict__ RMP, const float* __restrict__ RSP,
                                               float* __restrict__ RMX, float* __restrict__ RSM){
  int e = blockIdx.x*256 + threadIdx.x;
  float M = -__builtin_inff();
  #pragma unroll
  for (int i=0;i<8;++i) M = fmaxf(M, RMP[e*8+i]);
  float l = 0.f;
  #pragma unroll
  for (int i=0;i<8;++i) l += RSP[e*8+i]*expf(RMP[e*8+i]-M);
  RMX[e] = M; RSM[e] = l;
}

// LDS map (floats): QM[32o][32m]=1024 @0, QN[32o][32n]=1024 @1024,
// XVt[32n][132]=4224 @2048, SL[32n][32m]=1024 @6272, MX@7296, RL@7328.
#define SM_QM 0
#define SM_QN 1024
#define SM_XV 2048
#define SM_SL 6272
#define SM_MX 7296
#define SM_RL 7328

// main: grid 1024 = b(8) x mt(64) x part(2); n-range split in 2; writes PV and
// column-sum partials to PP/CSP. v2: QM/QN staged via b128+b128 (1 float4 per
// thread each), XV via float4 global + 4x b32 LDS scatter (4 iters/thread,
// was 16 b32 loads). Same values/slots -> bit-exact.
__global__ __launch_bounds__(256) void k_sa_cm(const float* __restrict__ QX, const float* __restrict__ XV,
                                               const float* __restrict__ RMAX, const float* __restrict__ RSUM,
                                               float* __restrict__ PP, float* __restrict__ CSP){
  int blk = blockIdx.x;
  int part = blk & 1, mt = (blk >> 1) & 63, b = blk >> 7;
  int m0 = mt << 5;
  int tid = threadIdx.x;
  int nnp = tid >> 4, mmp = tid & 15;      // 2x2 S-microtile owner
  int tc = tid >> 3, tm8 = tid & 7;        // PV owner: c=tc*4+ci, m=tm8*4+mi
  __shared__ __align__(16) float sm[7360];
  {
    int o = tid >> 3, mm4 = (tid & 7) << 2;
    *(float4*)&sm[SM_QM + (o<<5) + mm4] = *(const float4*)&QX[(b*32+o)*Nn + m0 + mm4];
  }
  float acc[4][4];
  #pragma unroll
  for (int ci=0;ci<4;++ci){
    #pragma unroll
    for (int mi=0;mi<4;++mi) acc[ci][mi] = 0.f;
  }
  float csr = 0.f;
  int it0 = part*32;
  for (int it=it0; it<it0+32; ++it){
    int nb = it*32;
    __syncthreads();
    {
      int o = tid >> 3, nn4 = (tid & 7) << 2;
      *(float4*)&sm[SM_QN + (o<<5) + nn4] = *(const float4*)&QX[(b*32+o)*Nn + nb + nn4];
    }
    for (int e=tid; e<1024; e+=256){
      int c = e >> 3, nn4 = (e & 7) << 2;
      float4 v = *(const float4*)&XV[(b*128+c)*Nn + nb + nn4];
      sm[SM_XV + (nn4+0)*132 + c] = v.x;
      sm[SM_XV + (nn4+1)*132 + c] = v.y;
      sm[SM_XV + (nn4+2)*132 + c] = v.z;
      sm[SM_XV + (nn4+3)*132 + c] = v.w;
    }
    if (tid < 32){ sm[SM_MX+tid] = RMAX[b*Nn + nb + tid]; sm[SM_RL+tid] = 1.0f / RSUM[b*Nn + nb + tid]; }
    __syncthreads();
    float e00=0.f, e01=0.f, e10=0.f, e11=0.f;
    #pragma unroll
    for (int o=0;o<32;++o){
      float2 qn = *(const float2*)&sm[SM_QN + o*32 + nnp*2];
      float2 qm = *(const float2*)&sm[SM_QM + o*32 + mmp*2];
      e00 = fmaf(qn.x, qm.x, e00);
      e01 = fmaf(qn.x, qm.y, e01);
      e10 = fmaf(qn.y, qm.x, e10);
      e11 = fmaf(qn.y, qm.y, e11);
    }
    float mx0 = sm[SM_MX + nnp*2],   rl0 = sm[SM_RL + nnp*2];
    float mx1 = sm[SM_MX + nnp*2+1], rl1 = sm[SM_RL + nnp*2+1];
    float2 s0; s0.x = expf(e00-mx0)*rl0; s0.y = expf(e01-mx0)*rl0;
    float2 s1; s1.x = expf(e10-mx1)*rl1; s1.y = expf(e11-mx1)*rl1;
    *(float2*)&sm[SM_SL + (nnp*2  )*32 + mmp*2] = s0;
    *(float2*)&sm[SM_SL + (nnp*2+1)*32 + mmp*2] = s1;
    __syncthreads();
    if (tid < 32){
      #pragma unroll
      for (int nn=0;nn<32;++nn) csr += sm[SM_SL + nn*32 + tid];
    }
    #pragma unroll 8
    for (int nn=0;nn<32;++nn){
      float4 xv4 = *(const float4*)&sm[SM_XV + nn*132 + tc*4];
      float4 s4  = *(const float4*)&sm[SM_SL + nn*32  + tm8*4];
      acc[0][0] = fmaf(xv4.x, s4.x, acc[0][0]);
      acc[0][1] = fmaf(xv4.x, s4.y, acc[0][1]);
      acc[0][2] = fmaf(xv4.x, s4.z, acc[0][2]);
      acc[0][3] = fmaf(xv4.x, s4.w, acc[0][3]);
      acc[1][0] = fmaf(xv4.y, s4.x, acc[1][0]);
      acc[1][1] = fmaf(xv4.y, s4.y, acc[1][1]);
      acc[1][2] = fmaf(xv4.y, s4.z, acc[1][2]);
      acc[1][3] = fmaf(xv4.y, s4.w, acc[1][3]);
      acc[2][0] = fmaf(xv4.z, s4.x, acc[2][0]);
      acc[2][1] = fmaf(xv4.z, s4.y, acc[2][1]);
      acc[2][2] = fmaf(xv4.z, s4.z, acc[2][2]);
      acc[2][3] = fmaf(xv4.z, s4.w, acc[2][3]);
      acc[3][0] = fmaf(xv4.w, s4.x, acc[3][0]);
      acc[3][1] = fmaf(xv4.w, s4.y, acc[3][1]);
      acc[3][2] = fmaf(xv4.w, s4.z, acc[3][2]);
      acc[3][3] = fmaf(xv4.w, s4.w, acc[3][3]);
    }
  }
  int slot = (b*64 + mt)*2 + part;
  #pragma unroll
  for (int ci=0;ci<4;++ci){
    int c = tc*4 + ci;
    *(float4*)&PP[slot*4096 + c*32 + tm8*4] =
      make_float4(acc[ci][0], acc[ci][1], acc[ci][2], acc[ci][3]);
  }
  if (tid < 32) CSP[slot*32 + tid] = csr;
}

// combine + transform epilogue: grid 512 = b(8) x mt(64). In-place on h.
// v2: IN read in the residual-build phase via float4 (4 b128, was 16 b32).
__global__ __launch_bounds__(256) void k_sa_cc(const float* IN,
                                               const float* __restrict__ PP, const float* __restrict__ CSP,
                                               const float* __restrict__ Tw, const float* __restrict__ Tb,
                                               const float* __restrict__ Gs, const float* __restrict__ Bs,
                                               float* OUT){
  int blk = blockIdx.x;
  int mt = blk & 63, b = blk >> 6;
  int m0 = mt << 5;
  int tid = threadIdx.x;
  int tc = tid >> 3, tm8 = tid & 7;
  __shared__ __align__(16) float sm[4128];   // DL[128][32] @0, CS[32] @4096
  int s0 = (b*64 + mt)*2, s1 = s0 + 1;
  if (tid < 32) sm[4096 + tid] = CSP[s0*32 + tid] + CSP[s1*32 + tid];
  __syncthreads();
  #pragma unroll
  for (int ci=0;ci<4;++ci){
    int c = tc*4 + ci;
    float4 p0 = *(const float4*)&PP[s0*4096 + c*32 + tm8*4];
    float4 p1 = *(const float4*)&PP[s1*4096 + c*32 + tm8*4];
    float4 inv = *(const float4*)&IN[b*HS + c*Nn + m0 + tm8*4];
    float am[4] = {p0.x+p1.x, p0.y+p1.y, p0.z+p1.z, p0.w+p1.w};
    float ivs[4] = {inv.x, inv.y, inv.z, inv.w};
    #pragma unroll
    for (int mi=0;mi<4;++mi){
      int ml = tm8*4 + mi;
      float cs = sm[4096 + ml];
      float xr = am[mi] / (1e-9f + cs);
      sm[c*32 + ml] = ivs[mi] - xr;
    }
  }
  __syncthreads();
  int hw = tid >> 5, m = tid & 31;
  float sroot = sqrtf(1.0f + 1e-5f);
  for (int oo=0; oo<16; ++oo){
    int o = oo*8 + hw;
    const float4* twp = (const float4*)(Tw + o*128);
    float a = 0.f;
    #pragma unroll
    for (int c4=0;c4<32;++c4){
      float4 wv = twp[c4];
      a = fmaf(wv.x, sm[(c4*4+0)*32 + m], a);
      a = fmaf(wv.y, sm[(c4*4+1)*32 + m], a);
      a = fmaf(wv.z, sm[(c4*4+2)*32 + m], a);
      a = fmaf(wv.w, sm[(c4*4+3)*32 + m], a);
    }
    a += Tb[o];
    float y = a * (Gs[o] / sroot) + Bs[o];
    y = fmaxf(y, 0.f);
    OUT[b*HS + o*Nn + m0 + m] = IN[b*HS + o*Nn + m0 + m] + y;
  }
}

// ---------------- progressive fuse: ACC += FW[:, l*128:(l+1)*128] * h_l ----------------
// grid 512 = b(8) x nt(32) x half(2); wave w covers o = hf*128 + w*32 + [0,32).
// fin: apply final BN + leaky-ReLU on the last layer's write (replaces k_fin).
// v2: xt staging via float4 (8 b128 loads + 8 b128 LDS writes, was 32 b32).
__global__ __launch_bounds__(256) void k_fuse_part(const float* __restrict__ Hc, const float* __restrict__ FWT,
                                                   float* __restrict__ ACC, int l, int init, int fin,
                                                   const float* __restrict__ FGF, const float* __restrict__ FBF){
  int blk = blockIdx.x;
  int hf = blk & 1; int nt = (blk >> 1) & 31; int b = blk >> 6;
  int n0 = nt << 6;
  int w = threadIdx.x >> 6, lane = threadIdx.x & 63;
  __shared__ __align__(16) float xt[128*64];
  for (int e=threadIdx.x; e<2048; e+=256){
    int c = e >> 4, j4 = (e & 15) << 2;
    *(float4*)&xt[(c<<6) + j4] = *(const float4*)&Hc[(b*128 + c)*Nn + n0 + j4];
  }
  __syncthreads();
  float4 a[8];
  #pragma unroll
  for (int j=0;j<8;++j) a[j] = make_float4(0.f,0.f,0.f,0.f);
  int ob = hf*128 + w*32;
  for (int c=0;c<128;++c){
    float xv = xt[c*64 + lane];
    const float4* wr = (const float4*)(FWT + (l*128+c)*256 + ob);
    #pragma unroll
    for (int j4=0;j4<8;++j4){
      float4 wv = wr[j4];
      a[j4].x = fmaf(wv.x, xv, a[j4].x);
      a[j4].y = fmaf(wv.y, xv, a[j4].y);
      a[j4].z = fmaf(wv.z, xv, a[j4].z);
      a[j4].w = fmaf(wv.w, xv, a[j4].w);
    }
  }
  float sroot = sqrtf(1.0f + 1e-5f);
  #pragma unroll
  for (int j4=0;j4<8;++j4){
    float vs[4] = {a[j4].x, a[j4].y, a[j4].z, a[j4].w};
    #pragma unroll
    for (int qq=0;qq<4;++qq){
      int o = ob + j4*4 + qq;
      int idx = (b*256 + o)*Nn + n0 + lane;
      float v = init ? vs[qq] : (ACC[idx] + vs[qq]);
      if (fin){
        float y = v * (FGF[o] / sroot) + FBF[o];
        y = (y >= 0.f) ? y : 0.2f*y;
        ACC[idx] = y;
      } else {
        ACC[idx] = v;
      }
    }
  }
}

extern "C" void kernel_launch(void* const* d_in, const int* in_sizes, int n_in,
                              void* d_out, int out_size, void* d_ws, size_t ws_size,
                              hipStream_t stream) {
  const float* X   = (const float*)d_in[0];
  const float* w1  = (const float*)d_in[1];
  const float* g1  = (const float*)d_in[2];
  const float* b1  = (const float*)d_in[3];
  const float* w2  = (const float*)d_in[4];
  const float* g2  = (const float*)d_in[5];
  const float* b2_ = (const float*)d_in[6];
  const float* w3  = (const float*)d_in[7];
  const float* g3  = (const float*)d_in[8];
  const float* b3  = (const float*)d_in[9];
  const float* w4  = (const float*)d_in[10];
  const float* g4  = (const float*)d_in[11];
  const float* b4  = (const float*)d_in[12];
  // d_in[13..15] = w5/g5/b5 : unused by reference
  const float* qk  = (const float*)d_in[16];
  const float* sv  = (const float*)d_in[17];
  const float* svb = (const float*)d_in[18];
  const float* st  = (const float*)d_in[19];
  const float* stb = (const float*)d_in[20];
  const float* sg  = (const float*)d_in[21];
  const float* sb  = (const float*)d_in[22];
  const float* fw  = (const float*)d_in[23];
  const float* fg  = (const float*)d_in[24];
  const float* fb  = (const float*)d_in[25];

  float* ws = (float*)d_ws;
  float* H    = ws + 0;          // 2,097,152
  float* QXb  = ws + 2097152;    //   524,288
  float* XVb  = ws + 2621440;    // 2,097,152 (ends 4,718,592)
  float* RMP  = ws + 4718592;    //   131,072
  float* RSP  = ws + 4849664;    //   131,072
  float* RMX  = ws + 4980736;    //    16,384
  float* RSM  = ws + 4997120;    //    16,384 (ends 5,013,504)
  // phase-1 overlay on [2,097,152 .. 4,915,200) — dead before SA phase:
  float* XX   = ws + 2146304;
  int*   IDX  = (int*)(ws + 2162688);
  float* X1T  = ws + 2818048;
  float* X2T  = ws + 3866624;    // ends 4,915,200
  float* C0   = ws + 5013504;
  float* W1T = C0 + 0;
  float* W2T = C0 + 384;
  float* W3T = C0 + 4480;
  float* W4T = C0 + 12672;
  float* FWT = C0 + 16768;       // C0 ends 5,161,344
  float* PP  = ws + 5161344;     // 4,194,304 (PV partials: 1024 slots x 4096)
  float* CSP = ws + 9355648;     //    32,768 — total 9,388,416 floats = 35.8 MiB
  float* ACC = (float*)d_out;

  k_xx1<<<64,256,0,stream>>>(X, XX);
  k_prep_wt<<<578,256,0,stream>>>(w1,w2,w3,w4,fw, W1T,W2T,W3T,W4T,FWT);
  k_knn1<<<4096,256,0,stream>>>(X, XX, IDX);
  k_ec1<<<16384,64,0,stream>>>(X, IDX, W1T, W2T, g1,b1,g2,b2_, X1T);
  k_xx2<<<64,256,0,stream>>>(X1T, XX);
  k_tr<<<256,256,0,stream>>>(X1T, H);                  // X1 -> channel-major (H ch 0..63), BEFORE knn2
  k_knn2<<<2048,256,0,stream>>>(H, XX, IDX);           // v3: 2 q/wave, shared loads (verified 262us)
  k_ec2<<<16384,64,0,stream>>>(X1T, IDX, W3T, W4T, g3,b3,g4,b4, X2T);
  k_tr<<<256,256,0,stream>>>(X2T, H + 64*Nn);

  for (int l=0;l<4;++l){
    k_sa_a<<<512,256,0,stream>>>(H, qk + l*4096, sv + l*16384, svb + l*128, QXb, XVb);
    k_sa_b<<<512,256,0,stream>>>(QXb, RMP, RSP);
    k_sa_b2<<<64,256,0,stream>>>(RMP, RSP, RMX, RSM);
    k_sa_cm<<<1024,256,0,stream>>>(QXb, XVb, RMX, RSM, PP, CSP);
    k_sa_cc<<<512,256,0,stream>>>(H, PP, CSP,
                                  st + l*16384, stb + l*128, sg + l*128, sb + l*128, H);
    k_fuse_part<<<512,256,0,stream>>>(H, FWT, ACC, l, (l==0)?1:0, (l==3)?1:0, fg, fb);
  }
}

// Round 13
// 2428.594 us; speedup vs baseline: 1.2230x; 1.0133x over previous
//
#include <hip/hip_runtime.h>

#define Bb 8
#define Nn 2048
#define Kk 40
#define HS (128*Nn)   // h stride per batch (channel-major [b,128,2048])

// monotone float->uint transform: a > b  <=>  f2o(a) > f2o(b)
__device__ __forceinline__ unsigned f2o(float f){
  unsigned u = __float_as_uint(f);
  return (u & 0x80000000u) ? ~u : (u | 0x80000000u);
}

// Wave-cooperative exact top-40 of 2048, grouped rescan (4 groups of 8 slots).
// Lane owns m = slot*64+lane. Per round only the winner lane rescans its group;
// selection order identical to a full linear scan (value desc, index asc).
__device__ __forceinline__ void wave_top40(float* d, int lane, int* op){
  float gv[4]; int gs[4];
  #pragma unroll
  for (int g=0; g<4; ++g){
    float bv = d[g*8]; int bs = g*8;
    #pragma unroll
    for (int j=1;j<8;++j){
      float v = d[g*8+j];
      if (v > bv){ bv = v; bs = g*8+j; }
    }
    gv[g]=bv; gs[g]=bs;
  }
  for (int t=0; t<Kk; ++t){
    float bv = gv[0]; int bs = gs[0];
    if (gv[1] > bv){ bv=gv[1]; bs=gs[1]; }
    if (gv[2] > bv){ bv=gv[2]; bs=gs[2]; }
    if (gv[3] > bv){ bv=gv[3]; bs=gs[3]; }
    int bm = bs*64 + lane;
    unsigned long long key = ((unsigned long long)f2o(bv) << 32) | (unsigned)(~bm);
    #pragma unroll
    for (int s=32;s>0;s>>=1){
      unsigned long long o = __shfl_xor(key, s, 64);
      if (o > key) key = o;
    }
    int wm = (int)(~(unsigned)key);
    if (lane == 0) op[t] = wm;
    bool mine = ((wm & 63) == lane);
    int wsl = wm >> 6;
    if (mine){
      int G = wsl >> 3;
      #pragma unroll
      for (int g=0; g<4; ++g){
        if (g == G){
          float nv = -__builtin_inff(); int ns = g*8;
          #pragma unroll
          for (int j=0;j<8;++j){
            float v = d[g*8+j];
            if (g*8+j == wsl) v = -__builtin_inff();
            d[g*8+j] = v;
            if (v > nv){ nv=v; ns=g*8+j; }
          }
          gv[g]=nv; gs[g]=ns;
        }
      }
    }
  }
}

// Dual-query variant of the coalesced-ownership top40 (m = (s>>2)*256+lane*4+(s&3)).
// Interleaves the two independent 6-step shuffle-max chains per round to double
// ILP on the serial critical path. Each query's op sequence (reduce order,
// tie-break, rescan) is IDENTICAL to wave_top40_g -> selection bit-exact.
__device__ __forceinline__ void wave_top40_g2(float* d0, float* d1, int lane,
                                              int* op0, int* op1){
  float gv0[4], gv1[4]; int gs0[4], gs1[4];
  #pragma unroll
  for (int g=0; g<4; ++g){
    float bv0 = d0[g*8]; int bs0 = g*8;
    float bv1 = d1[g*8]; int bs1 = g*8;
    #pragma unroll
    for (int j=1;j<8;++j){
      float v0 = d0[g*8+j];
      if (v0 > bv0){ bv0 = v0; bs0 = g*8+j; }
      float v1 = d1[g*8+j];
      if (v1 > bv1){ bv1 = v1; bs1 = g*8+j; }
    }
    gv0[g]=bv0; gs0[g]=bs0;
    gv1[g]=bv1; gs1[g]=bs1;
  }
  for (int t=0; t<Kk; ++t){
    float bv0 = gv0[0]; int bs0 = gs0[0];
    if (gv0[1] > bv0){ bv0=gv0[1]; bs0=gs0[1]; }
    if (gv0[2] > bv0){ bv0=gv0[2]; bs0=gs0[2]; }
    if (gv0[3] > bv0){ bv0=gv0[3]; bs0=gs0[3]; }
    float bv1 = gv1[0]; int bs1 = gs1[0];
    if (gv1[1] > bv1){ bv1=gv1[1]; bs1=gs1[1]; }
    if (gv1[2] > bv1){ bv1=gv1[2]; bs1=gs1[2]; }
    if (gv1[3] > bv1){ bv1=gv1[3]; bs1=gs1[3]; }
    int bm0 = ((bs0>>2)<<8) + lane*4 + (bs0&3);
    int bm1 = ((bs1>>2)<<8) + lane*4 + (bs1&3);
    unsigned long long key0 = ((unsigned long long)f2o(bv0) << 32) | (unsigned)(~bm0);
    unsigned long long key1 = ((unsigned long long)f2o(bv1) << 32) | (unsigned)(~bm1);
    #pragma unroll
    for (int s=32;s>0;s>>=1){
      unsigned long long o0 = __shfl_xor(key0, s, 64);
      unsigned long long o1 = __shfl_xor(key1, s, 64);
      if (o0 > key0) key0 = o0;
      if (o1 > key1) key1 = o1;
    }
    int wm0 = (int)(~(unsigned)key0);
    int wm1 = (int)(~(unsigned)key1);
    if (lane == 0){ op0[t] = wm0; op1[t] = wm1; }
    {
      bool mine = (((wm0>>2) & 63) == lane);
      int wsl = ((wm0>>8)<<2) | (wm0 & 3);
      if (mine){
        int G = wsl >> 3;
        #pragma unroll
        for (int g=0; g<4; ++g){
          if (g == G){
            float nv = -__builtin_inff(); int ns = g*8;
            #pragma unroll
            for (int j=0;j<8;++j){
              float v = d0[g*8+j];
              if (g*8+j == wsl) v = -__builtin_inff();
              d0[g*8+j] = v;
              if (v > nv){ nv=v; ns=g*8+j; }
            }
            gv0[g]=nv; gs0[g]=ns;
          }
        }
      }
    }
    {
      bool mine = (((wm1>>2) & 63) == lane);
      int wsl = ((wm1>>8)<<2) | (wm1 & 3);
      if (mine){
        int G = wsl >> 3;
        #pragma unroll
        for (int g=0; g<4; ++g){
          if (g == G){
            float nv = -__builtin_inff(); int ns = g*8;
            #pragma unroll
            for (int j=0;j<8;++j){
              float v = d1[g*8+j];
              if (g*8+j == wsl) v = -__builtin_inff();
              d1[g*8+j] = v;
              if (v > nv){ nv=v; ns=g*8+j; }
            }
            gv1[g]=nv; gs1[g]=ns;
          }
        }
      }
    }
  }
}

// ---------------- prep ----------------
__global__ __launch_bounds__(256) void k_xx1(const float* __restrict__ x, float* __restrict__ XX){
  int e = blockIdx.x*256 + threadIdx.x;
  if (e >= Bb*Nn) return;
  float p0 = x[e*3+0], p1 = x[e*3+1], p2 = x[e*3+2];
  XX[e] = __fadd_rn(__fadd_rn(__fmul_rn(p0,p0), __fmul_rn(p1,p1)), __fmul_rn(p2,p2));
}

__global__ __launch_bounds__(256) void k_prep_wt(const float* __restrict__ w1, const float* __restrict__ w2,
                                                 const float* __restrict__ w3, const float* __restrict__ w4,
                                                 const float* __restrict__ fw,
                                                 float* __restrict__ W1T, float* __restrict__ W2T,
                                                 float* __restrict__ W3T, float* __restrict__ W4T,
                                                 float* __restrict__ FWT){
  int e = blockIdx.x*256 + threadIdx.x;
  if (e < 384)   { int i=e/64,  c=e%64;  W1T[e] = w1[c*6+i];    return; } e -= 384;
  if (e < 4096)  { int i=e/64,  c=e%64;  W2T[e] = w2[c*64+i];   return; } e -= 4096;
  if (e < 8192)  { int i=e/64,  c=e%64;  W3T[e] = w3[c*128+i];  return; } e -= 8192;
  if (e < 4096)  { int i=e/64,  c=e%64;  W4T[e] = w4[c*64+i];   return; } e -= 4096;
  if (e < 131072){ int i=e/256, o=e%256; FWT[e] = fw[o*512+i];  return; }
}

// ---------------- knn on 3-D points: 1 wave / query, LDS-staged cloud ----------------
__global__ __launch_bounds__(256) void k_knn1(const float* __restrict__ P, const float* __restrict__ XX,
                                              int* __restrict__ IDX){
  int blk = blockIdx.x;
  int b = blk >> 9;
  int w = threadIdx.x >> 6, lane = threadIdx.x & 63;
  int n = (blk & 511)*4 + w;
  const float* Pb = P + b*Nn*3;
  const float* xb = XX + b*Nn;
  __shared__ float Pl[Nn*3];
  __shared__ float Xl[Nn];
  for (int e = threadIdx.x; e < Nn*3; e += 256) Pl[e] = Pb[e];
  for (int e = threadIdx.x; e < Nn; e += 256) Xl[e] = xb[e];
  __syncthreads();
  float c0 = Pl[n*3+0], c1 = Pl[n*3+1], c2 = Pl[n*3+2];
  float xn = Xl[n];
  float d[32];
  #pragma unroll
  for (int j=0;j<32;++j){
    int m = j*64 + lane;
    float a0 = Pl[m*3+0], a1 = Pl[m*3+1], a2 = Pl[m*3+2];
    float in_ = __fadd_rn(__fadd_rn(__fmul_rn(c0,a0), __fmul_rn(c1,a1)), __fmul_rn(c2,a2));
    d[j] = __fsub_rn(__fsub_rn(__fmul_rn(2.0f,in_), xn), Xl[m]);
  }
  wave_top40(d, lane, IDX + (b*Nn+n)*Kk);
}

// ---------------- edge conv 1+2 + maxpool (bit-exact _rn path) ----------------
__global__ __launch_bounds__(64) void k_ec1(const float* __restrict__ P, const int* __restrict__ IDX,
                                            const float* __restrict__ W1T, const float* __restrict__ W2T,
                                            const float* __restrict__ g1, const float* __restrict__ b1,
                                            const float* __restrict__ g2, const float* __restrict__ b2,
                                            float* __restrict__ X1T){
  int e = blockIdx.x;           // global point row 0..16383
  int b = e >> 11;
  int lane = threadIdx.x;
  __shared__ float dC[Kk*4];
  __shared__ __align__(16) float y1L[64*44];
  float c0 = P[e*3+0], c1 = P[e*3+1], c2 = P[e*3+2];
  if (lane < Kk) {
    int idx = IDX[e*Kk + lane] & (Nn-1);
    const float* pn = P + (b*Nn + idx)*3;
    dC[lane*4+0] = __fsub_rn(pn[0], c0);
    dC[lane*4+1] = __fsub_rn(pn[1], c1);
    dC[lane*4+2] = __fsub_rn(pn[2], c2);
  }
  __syncthreads();
  float w10 = W1T[0*64+lane], w11 = W1T[1*64+lane], w12 = W1T[2*64+lane];
  float w13 = W1T[3*64+lane], w14 = W1T[4*64+lane], w15 = W1T[5*64+lane];
  float p3 = __fmul_rn(w13,c0), p4 = __fmul_rn(w14,c1), p5 = __fmul_rn(w15,c2);
  float s1 = __fdiv_rn(g1[lane], __fsqrt_rn(1.0f + 1e-5f));
  float o1 = b1[lane];
  for (int k=0;k<Kk;++k){
    float t = __fmul_rn(w10, dC[k*4+0]);
    t = __fadd_rn(t, __fmul_rn(w11, dC[k*4+1]));
    t = __fadd_rn(t, __fmul_rn(w12, dC[k*4+2]));
    t = __fadd_rn(t, p3); t = __fadd_rn(t, p4); t = __fadd_rn(t, p5);
    float y = __fadd_rn(__fmul_rn(t, s1), o1);
    y = (y >= 0.0f) ? y : __fmul_rn(0.2f, y);
    y1L[lane*44+k] = y;
  }
  __syncthreads();
  float4 q[10];
  #pragma unroll
  for (int k4=0;k4<10;++k4) q[k4] = make_float4(0.f,0.f,0.f,0.f);
  for (int i=0;i<64;++i){
    float w = W2T[i*64+lane];
    const float4* yp = (const float4*)&y1L[i*44];
    #pragma unroll
    for (int k4=0;k4<10;++k4){
      float4 yv = yp[k4];
      q[k4].x = __fadd_rn(q[k4].x, __fmul_rn(w, yv.x));
      q[k4].y = __fadd_rn(q[k4].y, __fmul_rn(w, yv.y));
      q[k4].z = __fadd_rn(q[k4].z, __fmul_rn(w, yv.z));
      q[k4].w = __fadd_rn(q[k4].w, __fmul_rn(w, yv.w));
    }
  }
  float s2 = __fdiv_rn(g2[lane], __fsqrt_rn(1.0f + 1e-5f));
  float o2 = b2[lane];
  float mx = -__builtin_inff();
  #pragma unroll
  for (int k4=0;k4<10;++k4){
    float vs[4] = {q[k4].x, q[k4].y, q[k4].z, q[k4].w};
    #pragma unroll
    for (int j=0;j<4;++j){
      float y = __fadd_rn(__fmul_rn(vs[j], s2), o2);
      y = (y >= 0.0f) ? y : __fmul_rn(0.2f, y);
      mx = fmaxf(mx, y);
    }
  }
  X1T[e*64 + lane] = mx;
}

__global__ __launch_bounds__(256) void k_xx2(const float* __restrict__ X1T, float* __restrict__ XX2){
  int e = blockIdx.x*256 + threadIdx.x;
  const float* r = X1T + e*64;
  float a = 0.f;
  for (int c=0;c<64;++c) a = __fadd_rn(a, __fmul_rn(r[c], r[c]));
  XX2[e] = a;
}

// ---------------- knn on 64-D features ----------------
// v5: v3's verified 2-queries/wave structure (grid 2048; 262us) + interleaved
// dual-query top40 (wave_top40_g2) to break the serial reduce/rescan chain.
// MAC phase, accumulation order, and ownership map unchanged -> d arrays
// bit-identical; per-query selection sequence unchanged -> IDX bit-exact.
__global__ __launch_bounds__(256) void k_knn2(const float* __restrict__ X1C, const float* __restrict__ XX2,
                                              int* __restrict__ IDX){
  int blk = blockIdx.x;
  int b = blk >> 8;                 // 256 blocks per batch
  int n0 = (blk & 255) << 3;        // 8 queries per block
  int w = threadIdx.x >> 6, lane = threadIdx.x & 63;
  __shared__ float qL[8*64];        // [q][c] query features (2 KB)
  for (int e=threadIdx.x; e<512; e+=256){
    int q = e >> 6, c = e & 63;
    qL[e] = X1C[b*HS + c*Nn + n0 + q];
  }
  __syncthreads();
  float4 a0[8], a1[8];
  #pragma unroll
  for (int j=0;j<8;++j){
    a0[j] = make_float4(0.f,0.f,0.f,0.f);
    a1[j] = make_float4(0.f,0.f,0.f,0.f);
  }
  for (int c=0;c<64;++c){
    const float4* row = (const float4*)(X1C + b*HS + c*Nn);
    float q0 = qL[(w*2+0)*64 + c];
    float q1 = qL[(w*2+1)*64 + c];
    #pragma unroll
    for (int j=0;j<8;++j){
      float4 v = row[j*64 + lane];
      a0[j].x = __fadd_rn(a0[j].x, __fmul_rn(q0, v.x));
      a0[j].y = __fadd_rn(a0[j].y, __fmul_rn(q0, v.y));
      a0[j].z = __fadd_rn(a0[j].z, __fmul_rn(q0, v.z));
      a0[j].w = __fadd_rn(a0[j].w, __fmul_rn(q0, v.w));
      a1[j].x = __fadd_rn(a1[j].x, __fmul_rn(q1, v.x));
      a1[j].y = __fadd_rn(a1[j].y, __fmul_rn(q1, v.y));
      a1[j].z = __fadd_rn(a1[j].z, __fmul_rn(q1, v.z));
      a1[j].w = __fadd_rn(a1[j].w, __fmul_rn(q1, v.w));
    }
  }
  const float* xb = XX2 + b*Nn;
  const float4* xb4 = (const float4*)xb;
  int na = n0 + w*2 + 0;
  int nb = n0 + w*2 + 1;
  float xna = xb[na];
  float xnb = xb[nb];
  float d0[32], d1[32];
  #pragma unroll
  for (int j=0;j<8;++j){
    float4 xm = xb4[j*64 + lane];
    d0[j*4+0] = __fsub_rn(__fsub_rn(__fmul_rn(2.0f, a0[j].x), xna), xm.x);
    d0[j*4+1] = __fsub_rn(__fsub_rn(__fmul_rn(2.0f, a0[j].y), xna), xm.y);
    d0[j*4+2] = __fsub_rn(__fsub_rn(__fmul_rn(2.0f, a0[j].z), xna), xm.z);
    d0[j*4+3] = __fsub_rn(__fsub_rn(__fmul_rn(2.0f, a0[j].w), xna), xm.w);
    d1[j*4+0] = __fsub_rn(__fsub_rn(__fmul_rn(2.0f, a1[j].x), xnb), xm.x);
    d1[j*4+1] = __fsub_rn(__fsub_rn(__fmul_rn(2.0f, a1[j].y), xnb), xm.y);
    d1[j*4+2] = __fsub_rn(__fsub_rn(__fmul_rn(2.0f, a1[j].z), xnb), xm.z);
    d1[j*4+3] = __fsub_rn(__fsub_rn(__fmul_rn(2.0f, a1[j].w), xnb), xm.w);
  }
  wave_top40_g2(d0, d1, lane, IDX + (b*Nn + na)*Kk, IDX + (b*Nn + nb)*Kk);
}

// ---------------- edge conv 3+4 + maxpool (fma ok) ----------------
__global__ __launch_bounds__(64) void k_ec2(const float* __restrict__ X1T, const int* __restrict__ IDX,
                                            const float* __restrict__ W3T, const float* __restrict__ W4T,
                                            const float* __restrict__ g3, const float* __restrict__ b3,
                                            const float* __restrict__ g4, const float* __restrict__ b4,
                                            float* __restrict__ X2T){
  int e = blockIdx.x; int b = e >> 11; int lane = threadIdx.x;
  __shared__ __align__(16) float dL[64*44];
  __shared__ float ctrL[64];
  float ctr = X1T[e*64 + lane];
  ctrL[lane] = ctr;
  __syncthreads();
  for (int k=0;k<Kk;++k){
    int idx = IDX[e*Kk + k] & (Nn-1);
    dL[lane*44 + k] = X1T[(b*Nn+idx)*64 + lane] - ctr;
  }
  __syncthreads();
  float base = 0.f;
  for (int i=0;i<64;++i) base = fmaf(W3T[(64+i)*64 + lane], ctrL[i], base);
  float4 q[10];
  #pragma unroll
  for (int k4=0;k4<10;++k4) q[k4] = make_float4(base,base,base,base);
  for (int i=0;i<64;++i){
    float w = W3T[i*64 + lane];
    const float4* dp = (const float4*)&dL[i*44];
    #pragma unroll
    for (int k4=0;k4<10;++k4){
      float4 d = dp[k4];
      q[k4].x = fmaf(w, d.x, q[k4].x);
      q[k4].y = fmaf(w, d.y, q[k4].y);
      q[k4].z = fmaf(w, d.z, q[k4].z);
      q[k4].w = fmaf(w, d.w, q[k4].w);
    }
  }
  float s3 = g3[lane] / sqrtf(1.0f+1e-5f);
  float o3 = b3[lane];
  __syncthreads();
  #pragma unroll
  for (int k4=0;k4<10;++k4){
    float4 y;
    y.x = q[k4].x*s3 + o3; y.x = (y.x>=0.f)?y.x:0.2f*y.x;
    y.y = q[k4].y*s3 + o3; y.y = (y.y>=0.f)?y.y:0.2f*y.y;
    y.z = q[k4].z*s3 + o3; y.z = (y.z>=0.f)?y.z:0.2f*y.z;
    y.w = q[k4].w*s3 + o3; y.w = (y.w>=0.f)?y.w:0.2f*y.w;
    *(float4*)&dL[lane*44 + k4*4] = y;
  }
  __syncthreads();
  float4 p[10];
  #pragma unroll
  for (int k4=0;k4<10;++k4) p[k4] = make_float4(0.f,0.f,0.f,0.f);
  for (int i=0;i<64;++i){
    float w = W4T[i*64 + lane];
    const float4* yp = (const float4*)&dL[i*44];
    #pragma unroll
    for (int k4=0;k4<10;++k4){
      float4 yv = yp[k4];
      p[k4].x = fmaf(w, yv.x, p[k4].x);
      p[k4].y = fmaf(w, yv.y, p[k4].y);
      p[k4].z = fmaf(w, yv.z, p[k4].z);
      p[k4].w = fmaf(w, yv.w, p[k4].w);
    }
  }
  float s4 = g4[lane] / sqrtf(1.0f+1e-5f);
  float o4 = b4[lane];
  float mx = -__builtin_inff();
  #pragma unroll
  for (int k4=0;k4<10;++k4){
    float vs[4] = {p[k4].x, p[k4].y, p[k4].z, p[k4].w};
    #pragma unroll
    for (int j=0;j<4;++j){
      float y = vs[j]*s4 + o4;
      y = (y>=0.f)?y:0.2f*y;
      mx = fmaxf(mx, y);
    }
  }
  X2T[e*64 + lane] = mx;
}

// (b,n,64) -> (b,c,n); dst pre-offset by channel base; dst batch stride = HS
__global__ __launch_bounds__(256) void k_tr(const float* __restrict__ src, float* __restrict__ dst){
  int b = blockIdx.x >> 5; int n0 = (blockIdx.x & 31) << 6;
  __shared__ float t[64*65];
  for (int e=threadIdx.x; e<4096; e+=256){
    int r = e >> 6, c = e & 63;
    t[r*65+c] = src[(b*Nn + n0 + r)*64 + c];
  }
  __syncthreads();
  for (int e=threadIdx.x; e<4096; e+=256){
    int c = e >> 6, r = e & 63;
    dst[b*HS + c*Nn + n0 + r] = t[r*65+c];
  }
}

// ---------------- SA layer ----------------
// grid 512 = b(8) x nt(32) x part(2); unified rows: r<32 -> QX row r, else XV row r-32.
// v2: xl staging via float4 (8 b128 loads + 8 b128 LDS writes per thread).
__global__ __launch_bounds__(256) void k_sa_a(const float* __restrict__ IN,
                                              const float* __restrict__ QKw, const float* __restrict__ Vw,
                                              const float* __restrict__ Vb,
                                              float* __restrict__ QX, float* __restrict__ XV){
  int blk = blockIdx.x;
  int part = blk & 1; int nt = (blk >> 1) & 31; int b = blk >> 6;
  int n0 = nt << 6;
  int w = threadIdx.x >> 6, lane = threadIdx.x & 63;
  __shared__ __align__(16) float xl[128*64];
  for (int e=threadIdx.x; e<2048; e+=256){
    int c = e >> 4, j4 = (e & 15) << 2;
    *(float4*)&xl[(c<<6) + j4] = *(const float4*)&IN[b*HS + c*Nn + n0 + j4];
  }
  __syncthreads();
  for (int i=0;i<20;++i){
    int r = part*80 + w*20 + i;
    const float4* wp4;
    if (r < 32) wp4 = (const float4*)(QKw + r*128);
    else        wp4 = (const float4*)(Vw + (r-32)*128);
    float a = 0.f;
    #pragma unroll
    for (int c4=0;c4<32;++c4){
      float4 wv = wp4[c4];
      a = fmaf(wv.x, xl[(c4*4+0)*64 + lane], a);
      a = fmaf(wv.y, xl[(c4*4+1)*64 + lane], a);
      a = fmaf(wv.z, xl[(c4*4+2)*64 + lane], a);
      a = fmaf(wv.w, xl[(c4*4+3)*64 + lane], a);
    }
    if (r < 32) QX[(b*32+r)*Nn + n0 + lane] = a;
    else { int o = r-32; XV[(b*128+o)*Nn + n0 + lane] = a + Vb[o]; }
  }
}

// m-split x8: grid 512 = b(8) x nc(8) x mc(8)
// v3: qt staged via float4 + b128 LDS writes; inner loop broadcast float4.
__global__ __launch_bounds__(256) void k_sa_b(const float* __restrict__ QX,
                                              float* __restrict__ RMP, float* __restrict__ RSP){
  int blk = blockIdx.x;
  int b = blk >> 6, sub = blk & 63;
  int ncn = sub >> 3, mcn = sub & 7;
  int n = ncn*256 + threadIdx.x;
  float q[32];
  #pragma unroll
  for (int o=0;o<32;++o) q[o] = QX[(b*32+o)*Nn + n];
  __shared__ __align__(16) float qt[32*128];
  float mr = -__builtin_inff(), lr = 0.f;
  int m0 = mcn*256;
  for (int t=0;t<2;++t){
    for (int e=threadIdx.x; e<1024; e+=256){
      int o = e >> 5, mm4 = (e & 31) << 2;
      *(float4*)&qt[(o<<7) + mm4] = *(const float4*)&QX[(b*32+o)*Nn + m0 + t*128 + mm4];
    }
    __syncthreads();
    for (int mm=0;mm<128;mm+=4){
      float e0=0.f, e1=0.f, e2=0.f, e3=0.f;
      #pragma unroll
      for (int o=0;o<32;++o){
        float qo=q[o];
        float4 qv = *(const float4*)&qt[o*128+mm];
        e0 = fmaf(qo, qv.x, e0);
        e1 = fmaf(qo, qv.y, e1);
        e2 = fmaf(qo, qv.z, e2);
        e3 = fmaf(qo, qv.w, e3);
      }
      if (e0 > mr){ lr = lr*expf(mr-e0) + 1.f; mr = e0; } else lr += expf(e0-mr);
      if (e1 > mr){ lr = lr*expf(mr-e1) + 1.f; mr = e1; } else lr += expf(e1-mr);
      if (e2 > mr){ lr = lr*expf(mr-e2) + 1.f; mr = e2; } else lr += expf(e2-mr);
      if (e3 > mr){ lr = lr*expf(mr-e3) + 1.f; mr = e3; } else lr += expf(e3-mr);
    }
    __syncthreads();
  }
  RMP[(b*Nn+n)*8 + mcn] = mr;
  RSP[(b*Nn+n)*8 + mcn] = lr;
}

__global__ __launch_bounds__(256) void k_sa_b2(const float* __restrict__ RMP, const float* __restrict__ RSP,
                                               float* __restrict__ RMX, float* __restrict__ RSM){
  int e = blockIdx.x*256 + threadIdx.x;
  float M = -__builtin_inff();
  #pragma unroll
  for (int i=0;i<8;++i) M = fmaxf(M, RMP[e*8+i]);
  float l = 0.f;
  #pragma unroll
  for (int i=0;i<8;++i) l += RSP[e*8+i]*expf(RMP[e*8+i]-M);
  RMX[e] = M; RSM[e] = l;
}

// LDS map (floats): QM[32o][32m]=1024 @0, QN[32o][32n]=1024 @1024,
// XVt[32n][132]=4224 @2048, SL[32n][32m]=1024 @6272, MX@7296, RL@7328.
#define SM_QM 0
#define SM_QN 1024
#define SM_XV 2048
#define SM_SL 6272
#define SM_MX 7296
#define SM_RL 7328

// main: grid 1024 = b(8) x mt(64) x part(2). v3: async-STAGE split (T14) --
// iter t+1's QN/XV/MX/RL are prefetched into REGISTERS right after the S-write
// (in flight across the barrier, hidden under csr+PV), and written to LDS at
// loop top. Same 3 barriers, same values to same slots, same order -> bit-exact.
__global__ __launch_bounds__(256) void k_sa_cm(const float* __restrict__ QX, const float* __restrict__ XV,
                                               const float* __restrict__ RMAX, const float* __restrict__ RSUM,
                                               float* __restrict__ PP, float* __restrict__ CSP){
  int blk = blockIdx.x;
  int part = blk & 1, mt = (blk >> 1) & 63, b = blk >> 7;
  int m0 = mt << 5;
  int tid = threadIdx.x;
  int nnp = tid >> 4, mmp = tid & 15;      // 2x2 S-microtile owner
  int tc = tid >> 3, tm8 = tid & 7;        // PV owner: c=tc*4+ci, m=tm8*4+mi
  __shared__ __align__(16) float sm[7360];
  {
    int o = tid >> 3, mm4 = (tid & 7) << 2;
    *(float4*)&sm[SM_QM + (o<<5) + mm4] = *(const float4*)&QX[(b*32+o)*Nn + m0 + mm4];
  }
  float acc[4][4];
  #pragma unroll
  for (int ci=0;ci<4;++ci){
    #pragma unroll
    for (int mi=0;mi<4;++mi) acc[ci][mi] = 0.f;
  }
  float csr = 0.f;
  int it0 = part*32;
  // prefetch state (registers)
  int o_q = tid >> 3, nn4_q = (tid & 7) << 2;   // QN coords (1 float4/thread)
  float4 rQN;
  float4 rXV[4];
  float rMX = 0.f, rRS = 0.f;
  {
    int nb = it0*32;
    rQN = *(const float4*)&QX[(b*32+o_q)*Nn + nb + nn4_q];
    #pragma unroll
    for (int u=0;u<4;++u){
      int e = tid + u*256;
      int c = e >> 3, nn4 = (e & 7) << 2;
      rXV[u] = *(const float4*)&XV[(b*128+c)*Nn + nb + nn4];
    }
    if (tid < 32){ rMX = RMAX[b*Nn + nb + tid]; rRS = RSUM[b*Nn + nb + tid]; }
  }
  for (int it=it0; it<it0+32; ++it){
    __syncthreads();
    // write prefetched staging to LDS (same slots/order as before)
    *(float4*)&sm[SM_QN + (o_q<<5) + nn4_q] = rQN;
    #pragma unroll
    for (int u=0;u<4;++u){
      int e = tid + u*256;
      int c = e >> 3, nn4 = (e & 7) << 2;
      sm[SM_XV + (nn4+0)*132 + c] = rXV[u].x;
      sm[SM_XV + (nn4+1)*132 + c] = rXV[u].y;
      sm[SM_XV + (nn4+2)*132 + c] = rXV[u].z;
      sm[SM_XV + (nn4+3)*132 + c] = rXV[u].w;
    }
    if (tid < 32){ sm[SM_MX+tid] = rMX; sm[SM_RL+tid] = 1.0f / rRS; }
    __syncthreads();
    float e00=0.f, e01=0.f, e10=0.f, e11=0.f;
    #pragma unroll
    for (int o=0;o<32;++o){
      float2 qn = *(const float2*)&sm[SM_QN + o*32 + nnp*2];
      float2 qm = *(const float2*)&sm[SM_QM + o*32 + mmp*2];
      e00 = fmaf(qn.x, qm.x, e00);
      e01 = fmaf(qn.x, qm.y, e01);
      e10 = fmaf(qn.y, qm.x, e10);
      e11 = fmaf(qn.y, qm.y, e11);
    }
    float mx0 = sm[SM_MX + nnp*2],   rl0 = sm[SM_RL + nnp*2];
    float mx1 = sm[SM_MX + nnp*2+1], rl1 = sm[SM_RL + nnp*2+1];
    float2 s0; s0.x = expf(e00-mx0)*rl0; s0.y = expf(e01-mx0)*rl0;
    float2 s1; s1.x = expf(e10-mx1)*rl1; s1.y = expf(e11-mx1)*rl1;
    *(float2*)&sm[SM_SL + (nnp*2  )*32 + mmp*2] = s0;
    *(float2*)&sm[SM_SL + (nnp*2+1)*32 + mmp*2] = s1;
    // issue next iter's global loads now; latency hides under csr+PV below
    if (it+1 < it0+32){
      int nb2 = (it+1)*32;
      rQN = *(const float4*)&QX[(b*32+o_q)*Nn + nb2 + nn4_q];
      #pragma unroll
      for (int u=0;u<4;++u){
        int e = tid + u*256;
        int c = e >> 3, nn4 = (e & 7) << 2;
        rXV[u] = *(const float4*)&XV[(b*128+c)*Nn + nb2 + nn4];
      }
      if (tid < 32){ rMX = RMAX[b*Nn + nb2 + tid]; rRS = RSUM[b*Nn + nb2 + tid]; }
    }
    __syncthreads();
    if (tid < 32){
      #pragma unroll
      for (int nn=0;nn<32;++nn) csr += sm[SM_SL + nn*32 + tid];
    }
    #pragma unroll 8
    for (int nn=0;nn<32;++nn){
      float4 xv4 = *(const float4*)&sm[SM_XV + nn*132 + tc*4];
      float4 s4  = *(const float4*)&sm[SM_SL + nn*32  + tm8*4];
      acc[0][0] = fmaf(xv4.x, s4.x, acc[0][0]);
      acc[0][1] = fmaf(xv4.x, s4.y, acc[0][1]);
      acc[0][2] = fmaf(xv4.x, s4.z, acc[0][2]);
      acc[0][3] = fmaf(xv4.x, s4.w, acc[0][3]);
      acc[1][0] = fmaf(xv4.y, s4.x, acc[1][0]);
      acc[1][1] = fmaf(xv4.y, s4.y, acc[1][1]);
      acc[1][2] = fmaf(xv4.y, s4.z, acc[1][2]);
      acc[1][3] = fmaf(xv4.y, s4.w, acc[1][3]);
      acc[2][0] = fmaf(xv4.z, s4.x, acc[2][0]);
      acc[2][1] = fmaf(xv4.z, s4.y, acc[2][1]);
      acc[2][2] = fmaf(xv4.z, s4.z, acc[2][2]);
      acc[2][3] = fmaf(xv4.z, s4.w, acc[2][3]);
      acc[3][0] = fmaf(xv4.w, s4.x, acc[3][0]);
      acc[3][1] = fmaf(xv4.w, s4.y, acc[3][1]);
      acc[3][2] = fmaf(xv4.w, s4.z, acc[3][2]);
      acc[3][3] = fmaf(xv4.w, s4.w, acc[3][3]);
    }
  }
  int slot = (b*64 + mt)*2 + part;
  #pragma unroll
  for (int ci=0;ci<4;++ci){
    int c = tc*4 + ci;
    *(float4*)&PP[slot*4096 + c*32 + tm8*4] =
      make_float4(acc[ci][0], acc[ci][1], acc[ci][2], acc[ci][3]);
  }
  if (tid < 32) CSP[slot*32 + tid] = csr;
}

// combine + transform epilogue: grid 512 = b(8) x mt(64). In-place on h.
// v2: IN read in the residual-build phase via float4.
__global__ __launch_bounds__(256) void k_sa_cc(const float* IN,
                                               const float* __restrict__ PP, const float* __restrict__ CSP,
                                               const float* __restrict__ Tw, const float* __restrict__ Tb,
                                               const float* __restrict__ Gs, const float* __restrict__ Bs,
                                               float* OUT){
  int blk = blockIdx.x;
  int mt = blk & 63, b = blk >> 6;
  int m0 = mt << 5;
  int tid = threadIdx.x;
  int tc = tid >> 3, tm8 = tid & 7;
  __shared__ __align__(16) float sm[4128];   // DL[128][32] @0, CS[32] @4096
  int s0 = (b*64 + mt)*2, s1 = s0 + 1;
  if (tid < 32) sm[4096 + tid] = CSP[s0*32 + tid] + CSP[s1*32 + tid];
  __syncthreads();
  #pragma unroll
  for (int ci=0;ci<4;++ci){
    int c = tc*4 + ci;
    float4 p0 = *(const float4*)&PP[s0*4096 + c*32 + tm8*4];
    float4 p1 = *(const float4*)&PP[s1*4096 + c*32 + tm8*4];
    float4 inv = *(const float4*)&IN[b*HS + c*Nn + m0 + tm8*4];
    float am[4] = {p0.x+p1.x, p0.y+p1.y, p0.z+p1.z, p0.w+p1.w};
    float ivs[4] = {inv.x, inv.y, inv.z, inv.w};
    #pragma unroll
    for (int mi=0;mi<4;++mi){
      int ml = tm8*4 + mi;
      float cs = sm[4096 + ml];
      float xr = am[mi] / (1e-9f + cs);
      sm[c*32 + ml] = ivs[mi] - xr;
    }
  }
  __syncthreads();
  int hw = tid >> 5, m = tid & 31;
  float sroot = sqrtf(1.0f + 1e-5f);
  for (int oo=0; oo<16; ++oo){
    int o = oo*8 + hw;
    const float4* twp = (const float4*)(Tw + o*128);
    float a = 0.f;
    #pragma unroll
    for (int c4=0;c4<32;++c4){
      float4 wv = twp[c4];
      a = fmaf(wv.x, sm[(c4*4+0)*32 + m], a);
      a = fmaf(wv.y, sm[(c4*4+1)*32 + m], a);
      a = fmaf(wv.z, sm[(c4*4+2)*32 + m], a);
      a = fmaf(wv.w, sm[(c4*4+3)*32 + m], a);
    }
    a += Tb[o];
    float y = a * (Gs[o] / sroot) + Bs[o];
    y = fmaxf(y, 0.f);
    OUT[b*HS + o*Nn + m0 + m] = IN[b*HS + o*Nn + m0 + m] + y;
  }
}

// ---------------- progressive fuse: ACC += FW[:, l*128:(l+1)*128] * h_l ----------------
// grid 512 = b(8) x nt(32) x half(2); wave w covers o = hf*128 + w*32 + [0,32).
// fin: apply final BN + leaky-ReLU on the last layer's write (replaces k_fin).
// v2: xt staging via float4.
__global__ __launch_bounds__(256) void k_fuse_part(const float* __restrict__ Hc, const float* __restrict__ FWT,
                                                   float* __restrict__ ACC, int l, int init, int fin,
                                                   const float* __restrict__ FGF, const float* __restrict__ FBF){
  int blk = blockIdx.x;
  int hf = blk & 1; int nt = (blk >> 1) & 31; int b = blk >> 6;
  int n0 = nt << 6;
  int w = threadIdx.x >> 6, lane = threadIdx.x & 63;
  __shared__ __align__(16) float xt[128*64];
  for (int e=threadIdx.x; e<2048; e+=256){
    int c = e >> 4, j4 = (e & 15) << 2;
    *(float4*)&xt[(c<<6) + j4] = *(const float4*)&Hc[(b*128 + c)*Nn + n0 + j4];
  }
  __syncthreads();
  float4 a[8];
  #pragma unroll
  for (int j=0;j<8;++j) a[j] = make_float4(0.f,0.f,0.f,0.f);
  int ob = hf*128 + w*32;
  for (int c=0;c<128;++c){
    float xv = xt[c*64 + lane];
    const float4* wr = (const float4*)(FWT + (l*128+c)*256 + ob);
    #pragma unroll
    for (int j4=0;j4<8;++j4){
      float4 wv = wr[j4];
      a[j4].x = fmaf(wv.x, xv, a[j4].x);
      a[j4].y = fmaf(wv.y, xv, a[j4].y);
      a[j4].z = fmaf(wv.z, xv, a[j4].z);
      a[j4].w = fmaf(wv.w, xv, a[j4].w);
    }
  }
  float sroot = sqrtf(1.0f + 1e-5f);
  #pragma unroll
  for (int j4=0;j4<8;++j4){
    float vs[4] = {a[j4].x, a[j4].y, a[j4].z, a[j4].w};
    #pragma unroll
    for (int qq=0;qq<4;++qq){
      int o = ob + j4*4 + qq;
      int idx = (b*256 + o)*Nn + n0 + lane;
      float v = init ? vs[qq] : (ACC[idx] + vs[qq]);
      if (fin){
        float y = v * (FGF[o] / sroot) + FBF[o];
        y = (y >= 0.f) ? y : 0.2f*y;
        ACC[idx] = y;
      } else {
        ACC[idx] = v;
      }
    }
  }
}

extern "C" void kernel_launch(void* const* d_in, const int* in_sizes, int n_in,
                              void* d_out, int out_size, void* d_ws, size_t ws_size,
                              hipStream_t stream) {
  const float* X   = (const float*)d_in[0];
  const float* w1  = (const float*)d_in[1];
  const float* g1  = (const float*)d_in[2];
  const float* b1  = (const float*)d_in[3];
  const float* w2  = (const float*)d_in[4];
  const float* g2  = (const float*)d_in[5];
  const float* b2_ = (const float*)d_in[6];
  const float* w3  = (const float*)d_in[7];
  const float* g3  = (const float*)d_in[8];
  const float* b3  = (const float*)d_in[9];
  const float* w4  = (const float*)d_in[10];
  const float* g4  = (const float*)d_in[11];
  const float* b4  = (const float*)d_in[12];
  // d_in[13..15] = w5/g5/b5 : unused by reference
  const float* qk  = (const float*)d_in[16];
  const float* sv  = (const float*)d_in[17];
  const float* svb = (const float*)d_in[18];
  const float* st  = (const float*)d_in[19];
  const float* stb = (const float*)d_in[20];
  const float* sg  = (const float*)d_in[21];
  const float* sb  = (const float*)d_in[22];
  const float* fw  = (const float*)d_in[23];
  const float* fg  = (const float*)d_in[24];
  const float* fb  = (const float*)d_in[25];

  float* ws = (float*)d_ws;
  float* H    = ws + 0;          // 2,097,152
  float* QXb  = ws + 2097152;    //   524,288
  float* XVb  = ws + 2621440;    // 2,097,152 (ends 4,718,592)
  float* RMP  = ws + 4718592;    //   131,072
  float* RSP  = ws + 4849664;    //   131,072
  float* RMX  = ws + 4980736;    //    16,384
  float* RSM  = ws + 4997120;    //    16,384 (ends 5,013,504)
  // phase-1 overlay on [2,097,152 .. 4,915,200) — dead before SA phase:
  float* XX   = ws + 2146304;
  int*   IDX  = (int*)(ws + 2162688);
  float* X1T  = ws + 2818048;
  float* X2T  = ws + 3866624;    // ends 4,915,200
  float* C0   = ws + 5013504;
  float* W1T = C0 + 0;
  float* W2T = C0 + 384;
  float* W3T = C0 + 4480;
  float* W4T = C0 + 12672;
  float* FWT = C0 + 16768;       // C0 ends 5,161,344
  float* PP  = ws + 5161344;     // 4,194,304 (PV partials: 1024 slots x 4096)
  float* CSP = ws + 9355648;     //    32,768 — total 9,388,416 floats = 35.8 MiB
  float* ACC = (float*)d_out;

  k_xx1<<<64,256,0,stream>>>(X, XX);
  k_prep_wt<<<578,256,0,stream>>>(w1,w2,w3,w4,fw, W1T,W2T,W3T,W4T,FWT);
  k_knn1<<<4096,256,0,stream>>>(X, XX, IDX);
  k_ec1<<<16384,64,0,stream>>>(X, IDX, W1T, W2T, g1,b1,g2,b2_, X1T);
  k_xx2<<<64,256,0,stream>>>(X1T, XX);
  k_tr<<<256,256,0,stream>>>(X1T, H);                  // X1 -> channel-major (H ch 0..63), BEFORE knn2
  k_knn2<<<2048,256,0,stream>>>(H, XX, IDX);           // v5: dual-interleaved top40
  k_ec2<<<16384,64,0,stream>>>(X1T, IDX, W3T, W4T, g3,b3,g4,b4, X2T);
  k_tr<<<256,256,0,stream>>>(X2T, H + 64*Nn);

  for (int l=0;l<4;++l){
    k_sa_a<<<512,256,0,stream>>>(H, qk + l*4096, sv + l*16384, svb + l*128, QXb, XVb);
    k_sa_b<<<512,256,0,stream>>>(QXb, RMP, RSP);
    k_sa_b2<<<64,256,0,stream>>>(RMP, RSP, RMX, RSM);
    k_sa_cm<<<1024,256,0,stream>>>(QXb, XVb, RMX, RSM, PP, CSP);
    k_sa_cc<<<512,256,0,stream>>>(H, PP, CSP,
                                  st + l*16384, stb + l*128, sg + l*128, sb + l*128, H);
    k_fuse_part<<<512,256,0,stream>>>(H, FWT, ACC, l, (l==0)?1:0, (l==3)?1:0, fg, fb);
  }
}